// Round 7
// baseline (270.646 us; speedup 1.0000x reference)
//
#include <hip/hip_runtime.h>
#include <hip/hip_bf16.h>

// MultiScaleRetention forward, MI355X gfx950 — Round 7.
// R6 passed (264.8 µs); retention = 97.5 µs, latency-bound w/ triangular tail
// (Occupancy 11.5%). This round changes ONLY retention: triangular pairing —
// block bx handles q-tiles bx AND 31-bx of one (b,h), staging each KV tile
// once. Uniform 33 compute-units/block, grid 16x16=256, LDS 64KB (2 blk/CU).
// All other kernels byte-identical to R6.

#define B_ 2
#define T_ 2048
#define E_ 1024
#define V_ 2048
#define H_ 8
#define KD_ 128
#define HD_ 256
#define M_ 4096  // B_*T_

typedef __attribute__((ext_vector_type(8))) short bf16x8;
typedef __attribute__((ext_vector_type(4))) float f32x4;

__device__ __forceinline__ float u2f(unsigned short u) {
    return __uint_as_float(((unsigned)u) << 16);
}
__device__ __forceinline__ unsigned short f2bu(float f) {
    unsigned x = __float_as_uint(f);
    return (unsigned short)((x + 0x7fffu + ((x >> 16) & 1u)) >> 16);  // RNE
}

typedef const __attribute__((address_space(1))) void gas_t;
typedef __attribute__((address_space(3))) void las_t;
__device__ __forceinline__ void gl_lds16(const void* g, void* l) {
    __builtin_amdgcn_global_load_lds((gas_t*)g, (las_t*)l, 16, 0, 0);
}

__device__ __forceinline__ void stc(float* p, float f) { *p = f; }
__device__ __forceinline__ void stc(unsigned short* p, float f) { *p = f2bu(f); }

// ---------------------------------------------------------------------------
// x fp32 -> bf16 flat convert (8 elems/thread).  [R4 verbatim]
// ---------------------------------------------------------------------------
__global__ __launch_bounds__(256) void conv_x_kernel(
    const float* __restrict__ x, unsigned short* __restrict__ xb)
{
    const size_t i = ((size_t)blockIdx.x * 256 + threadIdx.x) * 8;
    float4 a = *(const float4*)(x + i);
    float4 c = *(const float4*)(x + i + 4);
    *(ushort4*)(xb + i)     = make_ushort4(f2bu(a.x), f2bu(a.y), f2bu(a.z), f2bu(a.w));
    *(ushort4*)(xb + i + 4) = make_ushort4(f2bu(c.x), f2bu(c.y), f2bu(c.z), f2bu(c.w));
}

// ---------------------------------------------------------------------------
// W [K][N] fp32 -> Wt [N][K] bf16 (64x64 LDS tile transpose).  [R4 verbatim]
// ---------------------------------------------------------------------------
__global__ __launch_bounds__(256) void transW_kernel(
    const float* __restrict__ W, unsigned short* __restrict__ Wt, int K, int N)
{
    __shared__ float tl[64][65];
    const int tid = threadIdx.x;
    const int n0 = blockIdx.x * 64, k0 = blockIdx.y * 64;
    #pragma unroll
    for (int i = 0; i < 4; ++i) {
        int kr = i * 16 + (tid >> 4);
        int nc = (tid & 15) * 4;
        float4 v = *(const float4*)(W + (size_t)(k0 + kr) * N + n0 + nc);
        tl[kr][nc] = v.x; tl[kr][nc + 1] = v.y; tl[kr][nc + 2] = v.z; tl[kr][nc + 3] = v.w;
    }
    __syncthreads();
    #pragma unroll
    for (int i = 0; i < 4; ++i) {
        int nr = i * 16 + (tid >> 4);
        int kc = (tid & 15) * 4;
        ushort4 u = make_ushort4(f2bu(tl[kc + 0][nr]), f2bu(tl[kc + 1][nr]),
                                 f2bu(tl[kc + 2][nr]), f2bu(tl[kc + 3][nr]));
        *(ushort4*)(Wt + (size_t)(n0 + nr) * K + k0 + kc) = u;
    }
}

// ---------------------------------------------------------------------------
// V [b*T + t][2048] bf16 -> Vt [b*2048 + c][T] bf16.  [R4 verbatim]
// ---------------------------------------------------------------------------
__global__ __launch_bounds__(256) void transV_kernel(
    const unsigned short* __restrict__ vb, unsigned short* __restrict__ vt)
{
    __shared__ unsigned short tl[64][68];
    const int tid = threadIdx.x;
    const int t0 = blockIdx.x * 64, c0 = blockIdx.y * 64, b = blockIdx.z;
    #pragma unroll
    for (int i = 0; i < 4; ++i) {
        int tr = i * 16 + (tid >> 4);
        int cc = (tid & 15) * 4;
        ushort4 v = *(const ushort4*)(vb + (size_t)(b * T_ + t0 + tr) * V_ + c0 + cc);
        tl[tr][cc] = v.x; tl[tr][cc + 1] = v.y; tl[tr][cc + 2] = v.z; tl[tr][cc + 3] = v.w;
    }
    __syncthreads();
    #pragma unroll
    for (int i = 0; i < 4; ++i) {
        int cr = i * 16 + (tid >> 4);
        int tc = (tid & 15) * 4;
        ushort4 u = make_ushort4(tl[tc + 0][cr], tl[tc + 1][cr], tl[tc + 2][cr], tl[tc + 3][cr]);
        *(ushort4*)(vt + (size_t)(b * V_ + c0 + cr) * T_ + t0 + tc) = u;
    }
}

// ---------------------------------------------------------------------------
// MFMA GEMM: C[M,N] = A[M,K] @ Bt[N,K]^T. 128x128 tile, BK=64.  [R4 verbatim]
// ---------------------------------------------------------------------------
template <typename CT>
__global__ __launch_bounds__(256) void gemm_mfma_kernel(
    const unsigned short* __restrict__ A,
    const unsigned short* __restrict__ Bt,
    CT* __restrict__ C,
    int N, int K)
{
    __shared__ __align__(16) char Asm[128 * 64 * 2];
    __shared__ __align__(16) char Bsm[128 * 64 * 2];
    const int tid = threadIdx.x;
    const int l = tid & 63;
    const int w = tid >> 6;
    const int wr = w >> 1, wc = w & 1;
    const int rowBase = blockIdx.y * 128;
    const int colBase = blockIdx.x * 128;
    const int srow = tid >> 3;
    const int scolb = (tid & 7) * 16;

    f32x4 acc[4][4] = {};

    for (int k0 = 0; k0 < K; k0 += 64) {
        __syncthreads();
        #pragma unroll
        for (int i = 0; i < 4; ++i) {
            int r = i * 32 + srow;
            int cb = scolb ^ ((r & 7) << 4);
            gl_lds16((const char*)(A  + (size_t)(rowBase + r) * K + k0) + cb,
                     Asm + i * 4096 + w * 1024);
            gl_lds16((const char*)(Bt + (size_t)(colBase + r) * K + k0) + cb,
                     Bsm + i * 4096 + w * 1024);
        }
        __syncthreads();
        #pragma unroll
        for (int kk = 0; kk < 2; ++kk) {
            const int cb = kk * 64 + (l >> 4) * 16;
            bf16x8 a[4], b[4];
            #pragma unroll
            for (int m = 0; m < 4; ++m) {
                int r = wr * 64 + m * 16 + (l & 15);
                a[m] = *(const bf16x8*)(Asm + r * 128 + (cb ^ ((r & 7) << 4)));
            }
            #pragma unroll
            for (int n = 0; n < 4; ++n) {
                int r = wc * 64 + n * 16 + (l & 15);
                b[n] = *(const bf16x8*)(Bsm + r * 128 + (cb ^ ((r & 7) << 4)));
            }
            #pragma unroll
            for (int m = 0; m < 4; ++m)
                #pragma unroll
                for (int n = 0; n < 4; ++n)
                    acc[m][n] = __builtin_amdgcn_mfma_f32_16x16x32_bf16(a[m], b[n], acc[m][n], 0, 0, 0);
        }
    }
    #pragma unroll
    for (int m = 0; m < 4; ++m)
        #pragma unroll
        for (int n = 0; n < 4; ++n)
            #pragma unroll
            for (int r = 0; r < 4; ++r) {
                int row = rowBase + wr * 64 + m * 16 + (l >> 4) * 4 + r;
                int col = colBase + wc * 64 + n * 16 + (l & 15);
                float f = acc[m][n][r];
                if (!isfinite(f)) f = 0.f;  // tripwire
                stc(C + (size_t)row * N + col, f);
            }
}

// ---------------------------------------------------------------------------
// Fused qkv GEMM (R6-proven): R4 body, epilogue selects among q/k/v.
// ---------------------------------------------------------------------------
__global__ __launch_bounds__(256) void gemm_qkv3_kernel(
    const unsigned short* __restrict__ A,
    const unsigned short* __restrict__ Bt,
    unsigned short* __restrict__ qb,
    unsigned short* __restrict__ kb,
    unsigned short* __restrict__ vb)
{
    const int K = E_;
    __shared__ __align__(16) char Asm[128 * 64 * 2];
    __shared__ __align__(16) char Bsm[128 * 64 * 2];
    const int tid = threadIdx.x;
    const int l = tid & 63;
    const int w = tid >> 6;
    const int wr = w >> 1, wc = w & 1;
    const int rowBase = blockIdx.y * 128;
    const int colBase = blockIdx.x * 128;
    const int srow = tid >> 3;
    const int scolb = (tid & 7) * 16;

    f32x4 acc[4][4] = {};

    for (int k0 = 0; k0 < K; k0 += 64) {
        __syncthreads();
        #pragma unroll
        for (int i = 0; i < 4; ++i) {
            int r = i * 32 + srow;
            int cb = scolb ^ ((r & 7) << 4);
            gl_lds16((const char*)(A  + (size_t)(rowBase + r) * K + k0) + cb,
                     Asm + i * 4096 + w * 1024);
            gl_lds16((const char*)(Bt + (size_t)(colBase + r) * K + k0) + cb,
                     Bsm + i * 4096 + w * 1024);
        }
        __syncthreads();
        #pragma unroll
        for (int kk = 0; kk < 2; ++kk) {
            const int cb = kk * 64 + (l >> 4) * 16;
            bf16x8 a[4], b[4];
            #pragma unroll
            for (int m = 0; m < 4; ++m) {
                int r = wr * 64 + m * 16 + (l & 15);
                a[m] = *(const bf16x8*)(Asm + r * 128 + (cb ^ ((r & 7) << 4)));
            }
            #pragma unroll
            for (int n = 0; n < 4; ++n) {
                int r = wc * 64 + n * 16 + (l & 15);
                b[n] = *(const bf16x8*)(Bsm + r * 128 + (cb ^ ((r & 7) << 4)));
            }
            #pragma unroll
            for (int m = 0; m < 4; ++m)
                #pragma unroll
                for (int n = 0; n < 4; ++n)
                    acc[m][n] = __builtin_amdgcn_mfma_f32_16x16x32_bf16(a[m], b[n], acc[m][n], 0, 0, 0);
        }
    }

    const int colW = colBase + wc * 64;
    unsigned short* dst;
    int cofs, stride;
    if (colW < 1024)      { dst = qb; cofs = 0;    stride = E_; }
    else if (colW < 2048) { dst = kb; cofs = 1024; stride = E_; }
    else                  { dst = vb; cofs = 2048; stride = V_; }
    #pragma unroll
    for (int m = 0; m < 4; ++m)
        #pragma unroll
        for (int n = 0; n < 4; ++n)
            #pragma unroll
            for (int r = 0; r < 4; ++r) {
                int row = rowBase + wr * 64 + m * 16 + (l >> 4) * 4 + r;
                int col = colW + n * 16 + (l & 15);
                float f = acc[m][n][r];
                if (!isfinite(f)) f = 0.f;  // tripwire
                dst[(size_t)row * stride + (col - cofs)] = f2bu(f);
            }
}

// ---------------------------------------------------------------------------
// theta_shift in place on bf16 [M_, E_].  [R4 verbatim]
// ---------------------------------------------------------------------------
__global__ __launch_bounds__(256) void theta_shift_kernel(
    unsigned short* __restrict__ qk,
    const float* __restrict__ sinp, const float* __restrict__ cosp, float scale)
{
    const int i = blockIdx.x * 256 + threadIdx.x;
    const int pe = i & (E_ / 2 - 1);
    const int bt = i >> 9;
    const int t = bt & (T_ - 1);
    const int e0 = pe << 1;
    const int d0 = e0 & (KD_ - 1);
    const size_t base = (size_t)bt * E_ + e0;
    const float q0 = u2f(qk[base]);
    const float q1 = u2f(qk[base + 1]);
    const int sb = t * KD_ + d0;
    const float s0 = sinp[sb], s1 = sinp[sb + 1];
    const float c0 = cosp[sb], c1 = cosp[sb + 1];
    qk[base]     = f2bu((q0 * c0 - q1 * s0) * scale);
    qk[base + 1] = f2bu((q1 * c1 + q0 * s1) * scale);
}

// ---------------------------------------------------------------------------
// Paired MFMA retention: block bx handles q-tiles A=bx and B=31-bx of (b,h).
// KV tile staged once per t; B computed always, A when t<=bx. Uniform work.
// ---------------------------------------------------------------------------
#define RET_PART(QF, S0, PS, OACC, RS)                                         \
    {                                                                          \
        f32x4 sacc[4] = {};                                                    \
        _Pragma("unroll")                                                      \
        for (int kk = 0; kk < 4; ++kk) {                                       \
            const int cb = kk * 64 + (l >> 4) * 16;                            \
            _Pragma("unroll")                                                  \
            for (int n = 0; n < 4; ++n) {                                      \
                int r = n * 16 + (l & 15);                                     \
                bf16x8 kf = *(const bf16x8*)(Ks + r * 256 + (cb ^ ((r & 7) << 4))); \
                sacc[n] = __builtin_amdgcn_mfma_f32_16x16x32_bf16(QF[kk], kf, sacc[n], 0, 0, 0); \
            }                                                                  \
        }                                                                      \
        float rsp[4] = {0.f, 0.f, 0.f, 0.f};                                   \
        _Pragma("unroll")                                                      \
        for (int n = 0; n < 4; ++n)                                            \
            _Pragma("unroll")                                                  \
            for (int r = 0; r < 4; ++r) {                                      \
                int qrow = w * 16 + (l >> 4) * 4 + r;                          \
                int tcol = n * 16 + (l & 15);                                  \
                int d = ((S0) + qrow) - (t0 + tcol);                           \
                float pm = (d >= 0) ? sacc[n][r] * __expf((float)d * ld) : 0.f;\
                rsp[r] += pm;                                                  \
                *(unsigned short*)(PS + qrow * 128 + ((tcol * 2) ^ ((qrow & 7) << 4))) = f2bu(pm); \
            }                                                                  \
        _Pragma("unroll")                                                      \
        for (int r = 0; r < 4; ++r) {                                          \
            float vv = rsp[r];                                                 \
            vv += __shfl_xor(vv, 1, 16);                                       \
            vv += __shfl_xor(vv, 2, 16);                                       \
            vv += __shfl_xor(vv, 4, 16);                                       \
            vv += __shfl_xor(vv, 8, 16);                                       \
            RS[r] += vv;                                                       \
        }                                                                      \
        _Pragma("unroll")                                                      \
        for (int kk = 0; kk < 2; ++kk) {                                       \
            const int cb = kk * 64 + (l >> 4) * 16;                            \
            int pr = w * 16 + (l & 15);                                        \
            bf16x8 pf = *(const bf16x8*)(PS + pr * 128 + (cb ^ ((pr & 7) << 4))); \
            _Pragma("unroll")                                                  \
            for (int n2 = 0; n2 < 16; ++n2) {                                  \
                int r = n2 * 16 + (l & 15);                                    \
                bf16x8 vf = *(const bf16x8*)(Vs + r * 128 + (cb ^ ((r & 7) << 4))); \
                OACC[n2] = __builtin_amdgcn_mfma_f32_16x16x32_bf16(pf, vf, OACC[n2], 0, 0, 0); \
            }                                                                  \
        }                                                                      \
    }

__global__ __launch_bounds__(256) void retention_mfma_kernel(
    const unsigned short* __restrict__ qb,
    const unsigned short* __restrict__ kb,
    const unsigned short* __restrict__ vt,
    unsigned short* __restrict__ ao)
{
    __shared__ __align__(16) char Ks[64 * 128 * 2];    // 16 KB
    __shared__ __align__(16) char Vs[256 * 64 * 2];    // 32 KB
    __shared__ __align__(16) char PsA[64 * 64 * 2];    //  8 KB
    __shared__ __align__(16) char PsB[64 * 64 * 2];    //  8 KB
    const int tid = threadIdx.x;
    const int l = tid & 63;
    const int w = tid >> 6;
    const int bh = blockIdx.y;
    const int b = bh >> 3, h = bh & 7;
    const int bx = blockIdx.x;             // 0..15
    const int s0A = bx * 64;
    const int s0B = (31 - bx) * 64;
    const float ld = logf(1.f - exp2f(-5.f - (float)h));

    bf16x8 qfA[4], qfB[4];
    {
        const char* qpA = (const char*)(qb + (size_t)(b * T_ + s0A + w * 16 + (l & 15)) * E_ + h * KD_);
        const char* qpB = (const char*)(qb + (size_t)(b * T_ + s0B + w * 16 + (l & 15)) * E_ + h * KD_);
        #pragma unroll
        for (int kk = 0; kk < 4; ++kk) {
            qfA[kk] = *(const bf16x8*)(qpA + kk * 64 + (l >> 4) * 16);
            qfB[kk] = *(const bf16x8*)(qpB + kk * 64 + (l >> 4) * 16);
        }
    }

    f32x4 oaccA[16] = {}, oaccB[16] = {};
    float rsA[4] = {0.f, 0.f, 0.f, 0.f}, rsB[4] = {0.f, 0.f, 0.f, 0.f};

    const int nt = 32 - bx;   // B needs tiles 0..31-bx
    for (int t = 0; t < nt; ++t) {
        const int t0 = t * 64;
        __syncthreads();
        #pragma unroll
        for (int i = 0; i < 4; ++i) {  // K: 64 rows x 256 B
            int r = i * 16 + (tid >> 4);
            int cb = ((tid & 15) * 16) ^ ((r & 7) << 4);
            gl_lds16((const char*)(kb + (size_t)(b * T_ + t0 + r) * E_ + h * KD_) + cb,
                     Ks + i * 4096 + w * 1024);
        }
        #pragma unroll
        for (int i = 0; i < 8; ++i) {  // Vt: 256 rows x 128 B
            int r = i * 32 + (tid >> 3);
            int cb = ((tid & 7) * 16) ^ ((r & 7) << 4);
            gl_lds16((const char*)(vt + (size_t)((b * H_ + h) * HD_ + r) * T_ + t0) + cb,
                     Vs + i * 4096 + w * 1024);
        }
        __syncthreads();

        RET_PART(qfB, s0B, PsB, oaccB, rsB)
        if (t <= bx) {
            RET_PART(qfA, s0A, PsA, oaccA, rsA)
        }
    }

    float invA[4], invB[4];
    #pragma unroll
    for (int r = 0; r < 4; ++r) {
        invA[r] = 1.f / fmaxf(fabsf(rsA[r]), 1.f);
        invB[r] = 1.f / fmaxf(fabsf(rsB[r]), 1.f);
    }
    #pragma unroll
    for (int n2 = 0; n2 < 16; ++n2)
        #pragma unroll
        for (int r = 0; r < 4; ++r) {
            int rr = w * 16 + (l >> 4) * 4 + r;
            int col = h * HD_ + n2 * 16 + (l & 15);
            float fA = oaccA[n2][r] * invA[r];
            float fB = oaccB[n2][r] * invB[r];
            if (!isfinite(fA)) fA = 0.f;
            if (!isfinite(fB)) fB = 0.f;
            ao[(size_t)(b * T_ + s0A + rr) * V_ + col] = f2bu(fA);
            ao[(size_t)(b * T_ + s0B + rr) * V_ + col] = f2bu(fB);
        }
}

// ---------------------------------------------------------------------------
// Per-(b,t,h): ao = silu(g) * ao * rsqrt(mean(ao^2) + eps).  [R4 verbatim]
// ---------------------------------------------------------------------------
__global__ __launch_bounds__(256) void rms_silu_kernel(
    unsigned short* __restrict__ ao, const unsigned short* __restrict__ g)
{
    __shared__ float part[4];
    const int tid = threadIdx.x;
    const size_t base = (size_t)blockIdx.x * HD_;
    const float f = u2f(ao[base + tid]);
    float sq = f * f;
    #pragma unroll
    for (int off = 32; off > 0; off >>= 1) sq += __shfl_down(sq, off, 64);
    if ((tid & 63) == 0) part[tid >> 6] = sq;
    __syncthreads();
    const float tot = part[0] + part[1] + part[2] + part[3];
    const float scale = rsqrtf(tot * (1.0f / HD_) + 1e-6f);
    const float gv = u2f(g[base + tid]);
    ao[base + tid] = f2bu(f * scale * gv / (1.f + __expf(-gv)));
}

extern "C" void kernel_launch(void* const* d_in, const int* in_sizes, int n_in,
                              void* d_out, int out_size, void* d_ws, size_t ws_size,
                              hipStream_t stream)
{
    const float* x    = (const float*)d_in[0];
    const float* sinp = (const float*)d_in[1];
    const float* cosp = (const float*)d_in[2];
    // d_in[3] = mask: decay computed analytically in-kernel
    const float* Wq   = (const float*)d_in[4];
    const float* Wk   = (const float*)d_in[5];
    const float* Wv   = (const float*)d_in[6];
    const float* Wg   = (const float*)d_in[7];
    const float* Wo   = (const float*)d_in[8];
    float* out = (float*)d_out;

    // d_out doubles as scratch (R4-proven): xb [0,8.39M) | qb [8.39M,16.78M).
    unsigned short* xb = (unsigned short*)d_out;
    unsigned short* qb = xb + (size_t)M_ * E_;

    // ws layout (R6-identical, 41.94 MB peak):
    char* ws = (char*)d_ws;
    unsigned short* kb  = (unsigned short*)ws;
    unsigned short* wt  = (unsigned short*)(ws + 8388608);
    unsigned short* vt  = (unsigned short*)(ws + 8388608);
    unsigned short* gb  = (unsigned short*)(ws + 8388608);
    unsigned short* vb  = (unsigned short*)(ws + 25165824);
    unsigned short* aob = (unsigned short*)(ws + 25165824);
    unsigned short* wgt = (unsigned short*)ws;
    unsigned short* wot = (unsigned short*)ws;

    dim3 blk(256);
    conv_x_kernel<<<M_ * E_ / 8 / 256, blk, 0, stream>>>(x, xb);

    transW_kernel<<<dim3(16, 16), blk, 0, stream>>>(Wq, wt, E_, E_);
    transW_kernel<<<dim3(16, 16), blk, 0, stream>>>(Wk, wt + (size_t)1024 * E_, E_, E_);
    transW_kernel<<<dim3(32, 16), blk, 0, stream>>>(Wv, wt + (size_t)2048 * E_, E_, V_);

    gemm_qkv3_kernel<<<dim3(32, 32), blk, 0, stream>>>(xb, wt, qb, kb, vb);

    theta_shift_kernel<<<M_ * E_ / 2 / 256, blk, 0, stream>>>(qb, sinp, cosp, 1.0f);
    theta_shift_kernel<<<M_ * E_ / 2 / 256, blk, 0, stream>>>(kb, sinp, cosp, 0.088388347648318447f);

    transV_kernel<<<dim3(32, 32, B_), blk, 0, stream>>>(vb, vt);  // kills wt

    retention_mfma_kernel<<<dim3(16, 16), blk, 0, stream>>>(qb, kb, vt, aob);

    transW_kernel<<<dim3(32, 16), blk, 0, stream>>>(Wg, wgt, E_, V_);
    gemm_mfma_kernel<unsigned short><<<dim3(16, 32), blk, 0, stream>>>(xb, wgt, gb, V_, E_);

    rms_silu_kernel<<<B_ * T_ * H_, blk, 0, stream>>>(aob, gb);

    transW_kernel<<<dim3(16, 32), blk, 0, stream>>>(Wo, wot, V_, E_);
    gemm_mfma_kernel<float><<<dim3(8, 32), blk, 0, stream>>>(aob, wot, out, E_, V_);
}

// Round 8
// 265.997 us; speedup vs baseline: 1.0175x; 1.0175x over previous
//
#include <hip/hip_runtime.h>
#include <hip/hip_bf16.h>

// MultiScaleRetention forward, MI355X gfx950 — Round 8.
// R7 pairing regressed (1 blk/CU, worse L2 sharing). This round: retention
// rebuilt as 2-phase double-buffered pipeline (T3/T4 minimum recipe):
// STAGE(t+1) issued BEFORE compute(t); counted s_waitcnt vmcnt(12) (never 0
// mid-loop); raw s_barrier; LDS 104KB (dbuf K+V). Unpaired 512-block grid,
// XCD-swizzled so each bh's blocks share one XCD L2. All other kernels R6.

#define B_ 2
#define T_ 2048
#define E_ 1024
#define V_ 2048
#define H_ 8
#define KD_ 128
#define HD_ 256
#define M_ 4096  // B_*T_

typedef __attribute__((ext_vector_type(8))) short bf16x8;
typedef __attribute__((ext_vector_type(4))) float f32x4;

__device__ __forceinline__ float u2f(unsigned short u) {
    return __uint_as_float(((unsigned)u) << 16);
}
__device__ __forceinline__ unsigned short f2bu(float f) {
    unsigned x = __float_as_uint(f);
    return (unsigned short)((x + 0x7fffu + ((x >> 16) & 1u)) >> 16);  // RNE
}

typedef const __attribute__((address_space(1))) void gas_t;
typedef __attribute__((address_space(3))) void las_t;
__device__ __forceinline__ void gl_lds16(const void* g, void* l) {
    __builtin_amdgcn_global_load_lds((gas_t*)g, (las_t*)l, 16, 0, 0);
}

__device__ __forceinline__ void stc(float* p, float f) { *p = f; }
__device__ __forceinline__ void stc(unsigned short* p, float f) { *p = f2bu(f); }

// ---------------------------------------------------------------------------
// x fp32 -> bf16 flat convert (8 elems/thread).  [R4 verbatim]
// ---------------------------------------------------------------------------
__global__ __launch_bounds__(256) void conv_x_kernel(
    const float* __restrict__ x, unsigned short* __restrict__ xb)
{
    const size_t i = ((size_t)blockIdx.x * 256 + threadIdx.x) * 8;
    float4 a = *(const float4*)(x + i);
    float4 c = *(const float4*)(x + i + 4);
    *(ushort4*)(xb + i)     = make_ushort4(f2bu(a.x), f2bu(a.y), f2bu(a.z), f2bu(a.w));
    *(ushort4*)(xb + i + 4) = make_ushort4(f2bu(c.x), f2bu(c.y), f2bu(c.z), f2bu(c.w));
}

// ---------------------------------------------------------------------------
// W [K][N] fp32 -> Wt [N][K] bf16 (64x64 LDS tile transpose).  [R4 verbatim]
// ---------------------------------------------------------------------------
__global__ __launch_bounds__(256) void transW_kernel(
    const float* __restrict__ W, unsigned short* __restrict__ Wt, int K, int N)
{
    __shared__ float tl[64][65];
    const int tid = threadIdx.x;
    const int n0 = blockIdx.x * 64, k0 = blockIdx.y * 64;
    #pragma unroll
    for (int i = 0; i < 4; ++i) {
        int kr = i * 16 + (tid >> 4);
        int nc = (tid & 15) * 4;
        float4 v = *(const float4*)(W + (size_t)(k0 + kr) * N + n0 + nc);
        tl[kr][nc] = v.x; tl[kr][nc + 1] = v.y; tl[kr][nc + 2] = v.z; tl[kr][nc + 3] = v.w;
    }
    __syncthreads();
    #pragma unroll
    for (int i = 0; i < 4; ++i) {
        int nr = i * 16 + (tid >> 4);
        int kc = (tid & 15) * 4;
        ushort4 u = make_ushort4(f2bu(tl[kc + 0][nr]), f2bu(tl[kc + 1][nr]),
                                 f2bu(tl[kc + 2][nr]), f2bu(tl[kc + 3][nr]));
        *(ushort4*)(Wt + (size_t)(n0 + nr) * K + k0 + kc) = u;
    }
}

// ---------------------------------------------------------------------------
// V [b*T + t][2048] bf16 -> Vt [b*2048 + c][T] bf16.  [R4 verbatim]
// ---------------------------------------------------------------------------
__global__ __launch_bounds__(256) void transV_kernel(
    const unsigned short* __restrict__ vb, unsigned short* __restrict__ vt)
{
    __shared__ unsigned short tl[64][68];
    const int tid = threadIdx.x;
    const int t0 = blockIdx.x * 64, c0 = blockIdx.y * 64, b = blockIdx.z;
    #pragma unroll
    for (int i = 0; i < 4; ++i) {
        int tr = i * 16 + (tid >> 4);
        int cc = (tid & 15) * 4;
        ushort4 v = *(const ushort4*)(vb + (size_t)(b * T_ + t0 + tr) * V_ + c0 + cc);
        tl[tr][cc] = v.x; tl[tr][cc + 1] = v.y; tl[tr][cc + 2] = v.z; tl[tr][cc + 3] = v.w;
    }
    __syncthreads();
    #pragma unroll
    for (int i = 0; i < 4; ++i) {
        int cr = i * 16 + (tid >> 4);
        int tc = (tid & 15) * 4;
        ushort4 u = make_ushort4(tl[tc + 0][cr], tl[tc + 1][cr], tl[tc + 2][cr], tl[tc + 3][cr]);
        *(ushort4*)(vt + (size_t)(b * V_ + c0 + cr) * T_ + t0 + tc) = u;
    }
}

// ---------------------------------------------------------------------------
// MFMA GEMM: C[M,N] = A[M,K] @ Bt[N,K]^T. 128x128 tile, BK=64.  [R4 verbatim]
// ---------------------------------------------------------------------------
template <typename CT>
__global__ __launch_bounds__(256) void gemm_mfma_kernel(
    const unsigned short* __restrict__ A,
    const unsigned short* __restrict__ Bt,
    CT* __restrict__ C,
    int N, int K)
{
    __shared__ __align__(16) char Asm[128 * 64 * 2];
    __shared__ __align__(16) char Bsm[128 * 64 * 2];
    const int tid = threadIdx.x;
    const int l = tid & 63;
    const int w = tid >> 6;
    const int wr = w >> 1, wc = w & 1;
    const int rowBase = blockIdx.y * 128;
    const int colBase = blockIdx.x * 128;
    const int srow = tid >> 3;
    const int scolb = (tid & 7) * 16;

    f32x4 acc[4][4] = {};

    for (int k0 = 0; k0 < K; k0 += 64) {
        __syncthreads();
        #pragma unroll
        for (int i = 0; i < 4; ++i) {
            int r = i * 32 + srow;
            int cb = scolb ^ ((r & 7) << 4);
            gl_lds16((const char*)(A  + (size_t)(rowBase + r) * K + k0) + cb,
                     Asm + i * 4096 + w * 1024);
            gl_lds16((const char*)(Bt + (size_t)(colBase + r) * K + k0) + cb,
                     Bsm + i * 4096 + w * 1024);
        }
        __syncthreads();
        #pragma unroll
        for (int kk = 0; kk < 2; ++kk) {
            const int cb = kk * 64 + (l >> 4) * 16;
            bf16x8 a[4], b[4];
            #pragma unroll
            for (int m = 0; m < 4; ++m) {
                int r = wr * 64 + m * 16 + (l & 15);
                a[m] = *(const bf16x8*)(Asm + r * 128 + (cb ^ ((r & 7) << 4)));
            }
            #pragma unroll
            for (int n = 0; n < 4; ++n) {
                int r = wc * 64 + n * 16 + (l & 15);
                b[n] = *(const bf16x8*)(Bsm + r * 128 + (cb ^ ((r & 7) << 4)));
            }
            #pragma unroll
            for (int m = 0; m < 4; ++m)
                #pragma unroll
                for (int n = 0; n < 4; ++n)
                    acc[m][n] = __builtin_amdgcn_mfma_f32_16x16x32_bf16(a[m], b[n], acc[m][n], 0, 0, 0);
        }
    }
    #pragma unroll
    for (int m = 0; m < 4; ++m)
        #pragma unroll
        for (int n = 0; n < 4; ++n)
            #pragma unroll
            for (int r = 0; r < 4; ++r) {
                int row = rowBase + wr * 64 + m * 16 + (l >> 4) * 4 + r;
                int col = colBase + wc * 64 + n * 16 + (l & 15);
                float f = acc[m][n][r];
                if (!isfinite(f)) f = 0.f;  // tripwire
                stc(C + (size_t)row * N + col, f);
            }
}

// ---------------------------------------------------------------------------
// Fused qkv GEMM (R6-proven): R4 body, epilogue selects among q/k/v.
// ---------------------------------------------------------------------------
__global__ __launch_bounds__(256) void gemm_qkv3_kernel(
    const unsigned short* __restrict__ A,
    const unsigned short* __restrict__ Bt,
    unsigned short* __restrict__ qb,
    unsigned short* __restrict__ kb,
    unsigned short* __restrict__ vb)
{
    const int K = E_;
    __shared__ __align__(16) char Asm[128 * 64 * 2];
    __shared__ __align__(16) char Bsm[128 * 64 * 2];
    const int tid = threadIdx.x;
    const int l = tid & 63;
    const int w = tid >> 6;
    const int wr = w >> 1, wc = w & 1;
    const int rowBase = blockIdx.y * 128;
    const int colBase = blockIdx.x * 128;
    const int srow = tid >> 3;
    const int scolb = (tid & 7) * 16;

    f32x4 acc[4][4] = {};

    for (int k0 = 0; k0 < K; k0 += 64) {
        __syncthreads();
        #pragma unroll
        for (int i = 0; i < 4; ++i) {
            int r = i * 32 + srow;
            int cb = scolb ^ ((r & 7) << 4);
            gl_lds16((const char*)(A  + (size_t)(rowBase + r) * K + k0) + cb,
                     Asm + i * 4096 + w * 1024);
            gl_lds16((const char*)(Bt + (size_t)(colBase + r) * K + k0) + cb,
                     Bsm + i * 4096 + w * 1024);
        }
        __syncthreads();
        #pragma unroll
        for (int kk = 0; kk < 2; ++kk) {
            const int cb = kk * 64 + (l >> 4) * 16;
            bf16x8 a[4], b[4];
            #pragma unroll
            for (int m = 0; m < 4; ++m) {
                int r = wr * 64 + m * 16 + (l & 15);
                a[m] = *(const bf16x8*)(Asm + r * 128 + (cb ^ ((r & 7) << 4)));
            }
            #pragma unroll
            for (int n = 0; n < 4; ++n) {
                int r = wc * 64 + n * 16 + (l & 15);
                b[n] = *(const bf16x8*)(Bsm + r * 128 + (cb ^ ((r & 7) << 4)));
            }
            #pragma unroll
            for (int m = 0; m < 4; ++m)
                #pragma unroll
                for (int n = 0; n < 4; ++n)
                    acc[m][n] = __builtin_amdgcn_mfma_f32_16x16x32_bf16(a[m], b[n], acc[m][n], 0, 0, 0);
        }
    }

    const int colW = colBase + wc * 64;
    unsigned short* dst;
    int cofs, stride;
    if (colW < 1024)      { dst = qb; cofs = 0;    stride = E_; }
    else if (colW < 2048) { dst = kb; cofs = 1024; stride = E_; }
    else                  { dst = vb; cofs = 2048; stride = V_; }
    #pragma unroll
    for (int m = 0; m < 4; ++m)
        #pragma unroll
        for (int n = 0; n < 4; ++n)
            #pragma unroll
            for (int r = 0; r < 4; ++r) {
                int row = rowBase + wr * 64 + m * 16 + (l >> 4) * 4 + r;
                int col = colW + n * 16 + (l & 15);
                float f = acc[m][n][r];
                if (!isfinite(f)) f = 0.f;  // tripwire
                dst[(size_t)row * stride + (col - cofs)] = f2bu(f);
            }
}

// ---------------------------------------------------------------------------
// theta_shift in place on bf16 [M_, E_].  [R4 verbatim]
// ---------------------------------------------------------------------------
__global__ __launch_bounds__(256) void theta_shift_kernel(
    unsigned short* __restrict__ qk,
    const float* __restrict__ sinp, const float* __restrict__ cosp, float scale)
{
    const int i = blockIdx.x * 256 + threadIdx.x;
    const int pe = i & (E_ / 2 - 1);
    const int bt = i >> 9;
    const int t = bt & (T_ - 1);
    const int e0 = pe << 1;
    const int d0 = e0 & (KD_ - 1);
    const size_t base = (size_t)bt * E_ + e0;
    const float q0 = u2f(qk[base]);
    const float q1 = u2f(qk[base + 1]);
    const int sb = t * KD_ + d0;
    const float s0 = sinp[sb], s1 = sinp[sb + 1];
    const float c0 = cosp[sb], c1 = cosp[sb + 1];
    qk[base]     = f2bu((q0 * c0 - q1 * s0) * scale);
    qk[base + 1] = f2bu((q1 * c1 + q0 * s1) * scale);
}

// ---------------------------------------------------------------------------
// Retention, 2-phase double-buffered pipeline. Block = 64 q-rows of one
// (b,h); KVBLK=64 tiles streamed with STAGE(t+1) || COMPUTE(t), counted
// vmcnt(12), raw s_barrier. Grid 512 flat, XCD-swizzled (same-bh -> one XCD).
// ---------------------------------------------------------------------------
#define STAGE_KV(BUF, T0)                                                      \
    {                                                                          \
        _Pragma("unroll")                                                      \
        for (int i = 0; i < 4; ++i) {                                          \
            int r = i * 16 + (tid >> 4);                                       \
            int cb = ((tid & 15) * 16) ^ ((r & 7) << 4);                       \
            gl_lds16((const char*)(kb + (size_t)(b * T_ + (T0) + r) * E_ + h * KD_) + cb, \
                     Ks[BUF] + i * 4096 + w * 1024);                           \
        }                                                                      \
        _Pragma("unroll")                                                      \
        for (int i = 0; i < 8; ++i) {                                          \
            int r = i * 32 + (tid >> 3);                                       \
            int cb = ((tid & 7) * 16) ^ ((r & 7) << 4);                        \
            gl_lds16((const char*)(vt + (size_t)((b * H_ + h) * HD_ + r) * T_ + (T0)) + cb, \
                     Vs[BUF] + i * 4096 + w * 1024);                           \
        }                                                                      \
    }

__global__ __launch_bounds__(256) void retention_mfma_kernel(
    const unsigned short* __restrict__ qb,
    const unsigned short* __restrict__ kb,
    const unsigned short* __restrict__ vt,
    unsigned short* __restrict__ ao)
{
    __shared__ __align__(16) char Ks[2][64 * 128 * 2];   // 2 x 16 KB
    __shared__ __align__(16) char Vs[2][256 * 64 * 2];   // 2 x 32 KB
    __shared__ __align__(16) char Ps[64 * 64 * 2];       //     8 KB
    const int tid = threadIdx.x;
    const int l = tid & 63;
    const int w = tid >> 6;
    // XCD swizzle: hardware round-robins blockIdx over 8 XCDs; remap so each
    // XCD owns 2 bh values (3 MB K/V slice, L2-resident). Bijective on [0,512).
    const int orig = (int)blockIdx.x;
    const int work = (orig & 7) * 64 + (orig >> 3);
    const int bh = work >> 5;            // 0..15
    const int qt = 31 - (work & 31);     // longest-first within bh
    const int b = bh >> 3, h = bh & 7;
    const int s0 = qt * 64;
    const float ld = logf(1.f - exp2f(-5.f - (float)h));

    bf16x8 qf[4];
    {
        const char* qp = (const char*)(qb + (size_t)(b * T_ + s0 + w * 16 + (l & 15)) * E_ + h * KD_);
        #pragma unroll
        for (int kk = 0; kk < 4; ++kk)
            qf[kk] = *(const bf16x8*)(qp + kk * 64 + (l >> 4) * 16);
    }

    f32x4 oacc[16] = {};
    float rs[4] = {0.f, 0.f, 0.f, 0.f};

    const int nt = qt + 1;
    STAGE_KV(0, 0)                         // prologue: tile 0 -> buf 0

    for (int t = 0; t < nt; ++t) {
        const int cur = t & 1;
        if (t + 1 < nt) {
            STAGE_KV(1 - cur, (t + 1) * 64)
            asm volatile("s_waitcnt vmcnt(12)" ::: "memory");  // drain tile t only
        } else {
            asm volatile("s_waitcnt vmcnt(0)" ::: "memory");
        }
        __builtin_amdgcn_s_barrier();      // buf[cur] fully staged, all waves
        __builtin_amdgcn_sched_barrier(0);
        const int t0 = t * 64;

        // QK^T: wave's 16 q-rows x 64 t-cols
        f32x4 sacc[4] = {};
        #pragma unroll
        for (int kk = 0; kk < 4; ++kk) {
            const int cb = kk * 64 + (l >> 4) * 16;
            #pragma unroll
            for (int n = 0; n < 4; ++n) {
                int r = n * 16 + (l & 15);
                bf16x8 kf = *(const bf16x8*)(Ks[cur] + r * 256 + (cb ^ ((r & 7) << 4)));
                sacc[n] = __builtin_amdgcn_mfma_f32_16x16x32_bf16(qf[kk], kf, sacc[n], 0, 0, 0);
            }
        }
        // decay mask + rowsum partials + P write (wave-private rows)
        float rsp[4] = {0.f, 0.f, 0.f, 0.f};
        #pragma unroll
        for (int n = 0; n < 4; ++n)
            #pragma unroll
            for (int r = 0; r < 4; ++r) {
                int qrow = w * 16 + (l >> 4) * 4 + r;
                int tcol = n * 16 + (l & 15);
                int d = (s0 + qrow) - (t0 + tcol);
                float pm = (d >= 0) ? sacc[n][r] * __expf((float)d * ld) : 0.f;
                rsp[r] += pm;
                *(unsigned short*)(Ps + qrow * 128 + ((tcol * 2) ^ ((qrow & 7) << 4))) = f2bu(pm);
            }
        #pragma unroll
        for (int r = 0; r < 4; ++r) {
            float vv = rsp[r];
            vv += __shfl_xor(vv, 1, 16);
            vv += __shfl_xor(vv, 2, 16);
            vv += __shfl_xor(vv, 4, 16);
            vv += __shfl_xor(vv, 8, 16);
            rs[r] += vv;
        }
        // PV: O[16 q-rows][256] += P[16][64] @ V[64][256]
        #pragma unroll
        for (int kk = 0; kk < 2; ++kk) {
            const int cb = kk * 64 + (l >> 4) * 16;
            int pr = w * 16 + (l & 15);
            bf16x8 pf = *(const bf16x8*)(Ps + pr * 128 + (cb ^ ((pr & 7) << 4)));
            #pragma unroll
            for (int n2 = 0; n2 < 16; ++n2) {
                int r = n2 * 16 + (l & 15);
                bf16x8 vf = *(const bf16x8*)(Vs[cur] + r * 128 + (cb ^ ((r & 7) << 4)));
                oacc[n2] = __builtin_amdgcn_mfma_f32_16x16x32_bf16(pf, vf, oacc[n2], 0, 0, 0);
            }
        }
        __builtin_amdgcn_s_barrier();      // all waves done reading buf[cur]
        __builtin_amdgcn_sched_barrier(0); // keep next STAGE below the barrier
    }

    float inv[4];
    #pragma unroll
    for (int r = 0; r < 4; ++r) inv[r] = 1.f / fmaxf(fabsf(rs[r]), 1.f);
    #pragma unroll
    for (int n2 = 0; n2 < 16; ++n2)
        #pragma unroll
        for (int r = 0; r < 4; ++r) {
            int row = s0 + w * 16 + (l >> 4) * 4 + r;
            int col = h * HD_ + n2 * 16 + (l & 15);
            float f = oacc[n2][r] * inv[r];
            if (!isfinite(f)) f = 0.f;
            ao[(size_t)(b * T_ + row) * V_ + col] = f2bu(f);
        }
}

// ---------------------------------------------------------------------------
// Per-(b,t,h): ao = silu(g) * ao * rsqrt(mean(ao^2) + eps).  [R4 verbatim]
// ---------------------------------------------------------------------------
__global__ __launch_bounds__(256) void rms_silu_kernel(
    unsigned short* __restrict__ ao, const unsigned short* __restrict__ g)
{
    __shared__ float part[4];
    const int tid = threadIdx.x;
    const size_t base = (size_t)blockIdx.x * HD_;
    const float f = u2f(ao[base + tid]);
    float sq = f * f;
    #pragma unroll
    for (int off = 32; off > 0; off >>= 1) sq += __shfl_down(sq, off, 64);
    if ((tid & 63) == 0) part[tid >> 6] = sq;
    __syncthreads();
    const float tot = part[0] + part[1] + part[2] + part[3];
    const float scale = rsqrtf(tot * (1.0f / HD_) + 1e-6f);
    const float gv = u2f(g[base + tid]);
    ao[base + tid] = f2bu(f * scale * gv / (1.f + __expf(-gv)));
}

extern "C" void kernel_launch(void* const* d_in, const int* in_sizes, int n_in,
                              void* d_out, int out_size, void* d_ws, size_t ws_size,
                              hipStream_t stream)
{
    const float* x    = (const float*)d_in[0];
    const float* sinp = (const float*)d_in[1];
    const float* cosp = (const float*)d_in[2];
    // d_in[3] = mask: decay computed analytically in-kernel
    const float* Wq   = (const float*)d_in[4];
    const float* Wk   = (const float*)d_in[5];
    const float* Wv   = (const float*)d_in[6];
    const float* Wg   = (const float*)d_in[7];
    const float* Wo   = (const float*)d_in[8];
    float* out = (float*)d_out;

    // d_out doubles as scratch (R4-proven): xb [0,8.39M) | qb [8.39M,16.78M).
    unsigned short* xb = (unsigned short*)d_out;
    unsigned short* qb = xb + (size_t)M_ * E_;

    // ws layout (R6-identical, 41.94 MB peak):
    char* ws = (char*)d_ws;
    unsigned short* kb  = (unsigned short*)ws;
    unsigned short* wt  = (unsigned short*)(ws + 8388608);
    unsigned short* vt  = (unsigned short*)(ws + 8388608);
    unsigned short* gb  = (unsigned short*)(ws + 8388608);
    unsigned short* vb  = (unsigned short*)(ws + 25165824);
    unsigned short* aob = (unsigned short*)(ws + 25165824);
    unsigned short* wgt = (unsigned short*)ws;
    unsigned short* wot = (unsigned short*)ws;

    dim3 blk(256);
    conv_x_kernel<<<M_ * E_ / 8 / 256, blk, 0, stream>>>(x, xb);

    transW_kernel<<<dim3(16, 16), blk, 0, stream>>>(Wq, wt, E_, E_);
    transW_kernel<<<dim3(16, 16), blk, 0, stream>>>(Wk, wt + (size_t)1024 * E_, E_, E_);
    transW_kernel<<<dim3(32, 16), blk, 0, stream>>>(Wv, wt + (size_t)2048 * E_, E_, V_);

    gemm_qkv3_kernel<<<dim3(32, 32), blk, 0, stream>>>(xb, wt, qb, kb, vb);

    theta_shift_kernel<<<M_ * E_ / 2 / 256, blk, 0, stream>>>(qb, sinp, cosp, 1.0f);
    theta_shift_kernel<<<M_ * E_ / 2 / 256, blk, 0, stream>>>(kb, sinp, cosp, 0.088388347648318447f);

    transV_kernel<<<dim3(32, 32, B_), blk, 0, stream>>>(vb, vt);  // kills wt

    retention_mfma_kernel<<<dim3(512), blk, 0, stream>>>(qb, kb, vt, aob);

    transW_kernel<<<dim3(32, 16), blk, 0, stream>>>(Wg, wgt, E_, V_);
    gemm_mfma_kernel<unsigned short><<<dim3(16, 32), blk, 0, stream>>>(xb, wgt, gb, V_, E_);

    rms_silu_kernel<<<B_ * T_ * H_, blk, 0, stream>>>(aob, gb);

    transW_kernel<<<dim3(16, 32), blk, 0, stream>>>(Wo, wot, V_, E_);
    gemm_mfma_kernel<float><<<dim3(8, 32), blk, 0, stream>>>(aob, wot, out, E_, V_);
}

// Round 9
// 257.778 us; speedup vs baseline: 1.0499x; 1.0319x over previous
//
#include <hip/hip_runtime.h>
#include <hip/hip_bf16.h>

// MultiScaleRetention forward, MI355X gfx950 — Round 9.
// R8: XCD swizzle cleared retention HBM (92->16.5 MB) but time unchanged ->
// retention is serial-chain-bound, deferred. GEMMs (~130 µs @ ~530 TF) are
// the biggest bucket. This round: ALL THREE GEMM bodies get the R8-proven
// double-buffer + counted-vmcnt pipeline (STAGE(k+1) before compute(k),
// vmcnt(8), raw s_barrier, sched_barrier). LDS 64 KB, 2 blocks/CU.
// Retention byte-identical to R8 (control).

#define B_ 2
#define T_ 2048
#define E_ 1024
#define V_ 2048
#define H_ 8
#define KD_ 128
#define HD_ 256
#define M_ 4096  // B_*T_

typedef __attribute__((ext_vector_type(8))) short bf16x8;
typedef __attribute__((ext_vector_type(4))) float f32x4;

__device__ __forceinline__ float u2f(unsigned short u) {
    return __uint_as_float(((unsigned)u) << 16);
}
__device__ __forceinline__ unsigned short f2bu(float f) {
    unsigned x = __float_as_uint(f);
    return (unsigned short)((x + 0x7fffu + ((x >> 16) & 1u)) >> 16);  // RNE
}

typedef const __attribute__((address_space(1))) void gas_t;
typedef __attribute__((address_space(3))) void las_t;
__device__ __forceinline__ void gl_lds16(const void* g, void* l) {
    __builtin_amdgcn_global_load_lds((gas_t*)g, (las_t*)l, 16, 0, 0);
}

__device__ __forceinline__ void stc(float* p, float f) { *p = f; }
__device__ __forceinline__ void stc(unsigned short* p, float f) { *p = f2bu(f); }

// ---------------------------------------------------------------------------
// x fp32 -> bf16 flat convert (8 elems/thread).  [R4 verbatim]
// ---------------------------------------------------------------------------
__global__ __launch_bounds__(256) void conv_x_kernel(
    const float* __restrict__ x, unsigned short* __restrict__ xb)
{
    const size_t i = ((size_t)blockIdx.x * 256 + threadIdx.x) * 8;
    float4 a = *(const float4*)(x + i);
    float4 c = *(const float4*)(x + i + 4);
    *(ushort4*)(xb + i)     = make_ushort4(f2bu(a.x), f2bu(a.y), f2bu(a.z), f2bu(a.w));
    *(ushort4*)(xb + i + 4) = make_ushort4(f2bu(c.x), f2bu(c.y), f2bu(c.z), f2bu(c.w));
}

// ---------------------------------------------------------------------------
// W [K][N] fp32 -> Wt [N][K] bf16 (64x64 LDS tile transpose).  [R4 verbatim]
// ---------------------------------------------------------------------------
__global__ __launch_bounds__(256) void transW_kernel(
    const float* __restrict__ W, unsigned short* __restrict__ Wt, int K, int N)
{
    __shared__ float tl[64][65];
    const int tid = threadIdx.x;
    const int n0 = blockIdx.x * 64, k0 = blockIdx.y * 64;
    #pragma unroll
    for (int i = 0; i < 4; ++i) {
        int kr = i * 16 + (tid >> 4);
        int nc = (tid & 15) * 4;
        float4 v = *(const float4*)(W + (size_t)(k0 + kr) * N + n0 + nc);
        tl[kr][nc] = v.x; tl[kr][nc + 1] = v.y; tl[kr][nc + 2] = v.z; tl[kr][nc + 3] = v.w;
    }
    __syncthreads();
    #pragma unroll
    for (int i = 0; i < 4; ++i) {
        int nr = i * 16 + (tid >> 4);
        int kc = (tid & 15) * 4;
        ushort4 u = make_ushort4(f2bu(tl[kc + 0][nr]), f2bu(tl[kc + 1][nr]),
                                 f2bu(tl[kc + 2][nr]), f2bu(tl[kc + 3][nr]));
        *(ushort4*)(Wt + (size_t)(n0 + nr) * K + k0 + kc) = u;
    }
}

// ---------------------------------------------------------------------------
// V [b*T + t][2048] bf16 -> Vt [b*2048 + c][T] bf16.  [R4 verbatim]
// ---------------------------------------------------------------------------
__global__ __launch_bounds__(256) void transV_kernel(
    const unsigned short* __restrict__ vb, unsigned short* __restrict__ vt)
{
    __shared__ unsigned short tl[64][68];
    const int tid = threadIdx.x;
    const int t0 = blockIdx.x * 64, c0 = blockIdx.y * 64, b = blockIdx.z;
    #pragma unroll
    for (int i = 0; i < 4; ++i) {
        int tr = i * 16 + (tid >> 4);
        int cc = (tid & 15) * 4;
        ushort4 v = *(const ushort4*)(vb + (size_t)(b * T_ + t0 + tr) * V_ + c0 + cc);
        tl[tr][cc] = v.x; tl[tr][cc + 1] = v.y; tl[tr][cc + 2] = v.z; tl[tr][cc + 3] = v.w;
    }
    __syncthreads();
    #pragma unroll
    for (int i = 0; i < 4; ++i) {
        int cr = i * 16 + (tid >> 4);
        int tc = (tid & 15) * 4;
        ushort4 u = make_ushort4(tl[tc + 0][cr], tl[tc + 1][cr], tl[tc + 2][cr], tl[tc + 3][cr]);
        *(ushort4*)(vt + (size_t)(b * V_ + c0 + cr) * T_ + t0 + tc) = u;
    }
}

// ---------------------------------------------------------------------------
// GEMM stage + compute building blocks (dbuf pipeline, R8-proven sync).
// ---------------------------------------------------------------------------
#define GSTAGE(BUF, K0)                                                        \
    {                                                                          \
        _Pragma("unroll")                                                      \
        for (int i = 0; i < 4; ++i) {                                          \
            int r = i * 32 + srow;                                             \
            int cb = scolb ^ ((r & 7) << 4);                                   \
            gl_lds16((const char*)(A  + (size_t)(rowBase + r) * K + (K0)) + cb,\
                     Asm[BUF] + i * 4096 + w * 1024);                          \
            gl_lds16((const char*)(Bt + (size_t)(colBase + r) * K + (K0)) + cb,\
                     Bsm[BUF] + i * 4096 + w * 1024);                          \
        }                                                                      \
    }

#define GCOMPUTE(BUF)                                                          \
    {                                                                          \
        _Pragma("unroll")                                                      \
        for (int kk = 0; kk < 2; ++kk) {                                       \
            const int cb = kk * 64 + (l >> 4) * 16;                            \
            bf16x8 a[4], b[4];                                                 \
            _Pragma("unroll")                                                  \
            for (int m = 0; m < 4; ++m) {                                      \
                int r = wr * 64 + m * 16 + (l & 15);                           \
                a[m] = *(const bf16x8*)(Asm[BUF] + r * 128 + (cb ^ ((r & 7) << 4))); \
            }                                                                  \
            _Pragma("unroll")                                                  \
            for (int n = 0; n < 4; ++n) {                                      \
                int r = wc * 64 + n * 16 + (l & 15);                           \
                b[n] = *(const bf16x8*)(Bsm[BUF] + r * 128 + (cb ^ ((r & 7) << 4))); \
            }                                                                  \
            _Pragma("unroll")                                                  \
            for (int m = 0; m < 4; ++m)                                        \
                _Pragma("unroll")                                              \
                for (int n = 0; n < 4; ++n)                                    \
                    acc[m][n] = __builtin_amdgcn_mfma_f32_16x16x32_bf16(a[m], b[n], acc[m][n], 0, 0, 0); \
        }                                                                      \
    }

#define GEMM_PIPELINE_LOOP                                                     \
    GSTAGE(0, 0)                                                               \
    const int nk = K / 64;                                                     \
    for (int kt = 0; kt < nk; ++kt) {                                          \
        const int cur = kt & 1;                                                \
        if (kt + 1 < nk) {                                                     \
            GSTAGE(1 - cur, (kt + 1) * 64)                                     \
            asm volatile("s_waitcnt vmcnt(8)" ::: "memory");                   \
        } else {                                                               \
            asm volatile("s_waitcnt vmcnt(0)" ::: "memory");                   \
        }                                                                      \
        __builtin_amdgcn_s_barrier();                                          \
        __builtin_amdgcn_sched_barrier(0);                                     \
        GCOMPUTE(cur)                                                          \
        __builtin_amdgcn_s_barrier();                                          \
        __builtin_amdgcn_sched_barrier(0);                                     \
    }

// ---------------------------------------------------------------------------
// MFMA GEMM (dbuf): C[M,N] = A[M,K] @ Bt[N,K]^T. 128x128 tile, BK=64.
// ---------------------------------------------------------------------------
template <typename CT>
__global__ __launch_bounds__(256) void gemm_mfma_kernel(
    const unsigned short* __restrict__ A,
    const unsigned short* __restrict__ Bt,
    CT* __restrict__ C,
    int N, int K)
{
    __shared__ __align__(16) char Asm[2][128 * 64 * 2];
    __shared__ __align__(16) char Bsm[2][128 * 64 * 2];
    const int tid = threadIdx.x;
    const int l = tid & 63;
    const int w = tid >> 6;
    const int wr = w >> 1, wc = w & 1;
    const int rowBase = blockIdx.y * 128;
    const int colBase = blockIdx.x * 128;
    const int srow = tid >> 3;
    const int scolb = (tid & 7) * 16;

    f32x4 acc[4][4] = {};

    GEMM_PIPELINE_LOOP

    #pragma unroll
    for (int m = 0; m < 4; ++m)
        #pragma unroll
        for (int n = 0; n < 4; ++n)
            #pragma unroll
            for (int r = 0; r < 4; ++r) {
                int row = rowBase + wr * 64 + m * 16 + (l >> 4) * 4 + r;
                int col = colBase + wc * 64 + n * 16 + (l & 15);
                float f = acc[m][n][r];
                if (!isfinite(f)) f = 0.f;  // tripwire
                stc(C + (size_t)row * N + col, f);
            }
}

// ---------------------------------------------------------------------------
// Fused qkv GEMM (dbuf): same body; epilogue selects among q/k/v.
// ---------------------------------------------------------------------------
__global__ __launch_bounds__(256) void gemm_qkv3_kernel(
    const unsigned short* __restrict__ A,
    const unsigned short* __restrict__ Bt,
    unsigned short* __restrict__ qb,
    unsigned short* __restrict__ kb,
    unsigned short* __restrict__ vb)
{
    const int K = E_;
    __shared__ __align__(16) char Asm[2][128 * 64 * 2];
    __shared__ __align__(16) char Bsm[2][128 * 64 * 2];
    const int tid = threadIdx.x;
    const int l = tid & 63;
    const int w = tid >> 6;
    const int wr = w >> 1, wc = w & 1;
    const int rowBase = blockIdx.y * 128;
    const int colBase = blockIdx.x * 128;
    const int srow = tid >> 3;
    const int scolb = (tid & 7) * 16;

    f32x4 acc[4][4] = {};

    GEMM_PIPELINE_LOOP

    const int colW = colBase + wc * 64;
    unsigned short* dst;
    int cofs, stride;
    if (colW < 1024)      { dst = qb; cofs = 0;    stride = E_; }
    else if (colW < 2048) { dst = kb; cofs = 1024; stride = E_; }
    else                  { dst = vb; cofs = 2048; stride = V_; }
    #pragma unroll
    for (int m = 0; m < 4; ++m)
        #pragma unroll
        for (int n = 0; n < 4; ++n)
            #pragma unroll
            for (int r = 0; r < 4; ++r) {
                int row = rowBase + wr * 64 + m * 16 + (l >> 4) * 4 + r;
                int col = colW + n * 16 + (l & 15);
                float f = acc[m][n][r];
                if (!isfinite(f)) f = 0.f;  // tripwire
                dst[(size_t)row * stride + (col - cofs)] = f2bu(f);
            }
}

// ---------------------------------------------------------------------------
// theta_shift in place on bf16 [M_, E_].  [R4 verbatim]
// ---------------------------------------------------------------------------
__global__ __launch_bounds__(256) void theta_shift_kernel(
    unsigned short* __restrict__ qk,
    const float* __restrict__ sinp, const float* __restrict__ cosp, float scale)
{
    const int i = blockIdx.x * 256 + threadIdx.x;
    const int pe = i & (E_ / 2 - 1);
    const int bt = i >> 9;
    const int t = bt & (T_ - 1);
    const int e0 = pe << 1;
    const int d0 = e0 & (KD_ - 1);
    const size_t base = (size_t)bt * E_ + e0;
    const float q0 = u2f(qk[base]);
    const float q1 = u2f(qk[base + 1]);
    const int sb = t * KD_ + d0;
    const float s0 = sinp[sb], s1 = sinp[sb + 1];
    const float c0 = cosp[sb], c1 = cosp[sb + 1];
    qk[base]     = f2bu((q0 * c0 - q1 * s0) * scale);
    qk[base + 1] = f2bu((q1 * c1 + q0 * s1) * scale);
}

// ---------------------------------------------------------------------------
// Retention, 2-phase double-buffered pipeline.  [R8 verbatim — control]
// ---------------------------------------------------------------------------
#define STAGE_KV(BUF, T0)                                                      \
    {                                                                          \
        _Pragma("unroll")                                                      \
        for (int i = 0; i < 4; ++i) {                                          \
            int r = i * 16 + (tid >> 4);                                       \
            int cb = ((tid & 15) * 16) ^ ((r & 7) << 4);                       \
            gl_lds16((const char*)(kb + (size_t)(b * T_ + (T0) + r) * E_ + h * KD_) + cb, \
                     Ks[BUF] + i * 4096 + w * 1024);                           \
        }                                                                      \
        _Pragma("unroll")                                                      \
        for (int i = 0; i < 8; ++i) {                                          \
            int r = i * 32 + (tid >> 3);                                       \
            int cb = ((tid & 7) * 16) ^ ((r & 7) << 4);                        \
            gl_lds16((const char*)(vt + (size_t)((b * H_ + h) * HD_ + r) * T_ + (T0)) + cb, \
                     Vs[BUF] + i * 4096 + w * 1024);                           \
        }                                                                      \
    }

__global__ __launch_bounds__(256) void retention_mfma_kernel(
    const unsigned short* __restrict__ qb,
    const unsigned short* __restrict__ kb,
    const unsigned short* __restrict__ vt,
    unsigned short* __restrict__ ao)
{
    __shared__ __align__(16) char Ks[2][64 * 128 * 2];   // 2 x 16 KB
    __shared__ __align__(16) char Vs[2][256 * 64 * 2];   // 2 x 32 KB
    __shared__ __align__(16) char Ps[64 * 64 * 2];       //     8 KB
    const int tid = threadIdx.x;
    const int l = tid & 63;
    const int w = tid >> 6;
    const int orig = (int)blockIdx.x;
    const int work = (orig & 7) * 64 + (orig >> 3);
    const int bh = work >> 5;            // 0..15
    const int qt = 31 - (work & 31);     // longest-first within bh
    const int b = bh >> 3, h = bh & 7;
    const int s0 = qt * 64;
    const float ld = logf(1.f - exp2f(-5.f - (float)h));

    bf16x8 qf[4];
    {
        const char* qp = (const char*)(qb + (size_t)(b * T_ + s0 + w * 16 + (l & 15)) * E_ + h * KD_);
        #pragma unroll
        for (int kk = 0; kk < 4; ++kk)
            qf[kk] = *(const bf16x8*)(qp + kk * 64 + (l >> 4) * 16);
    }

    f32x4 oacc[16] = {};
    float rs[4] = {0.f, 0.f, 0.f, 0.f};

    const int nt = qt + 1;
    STAGE_KV(0, 0)

    for (int t = 0; t < nt; ++t) {
        const int cur = t & 1;
        if (t + 1 < nt) {
            STAGE_KV(1 - cur, (t + 1) * 64)
            asm volatile("s_waitcnt vmcnt(12)" ::: "memory");
        } else {
            asm volatile("s_waitcnt vmcnt(0)" ::: "memory");
        }
        __builtin_amdgcn_s_barrier();
        __builtin_amdgcn_sched_barrier(0);
        const int t0 = t * 64;

        f32x4 sacc[4] = {};
        #pragma unroll
        for (int kk = 0; kk < 4; ++kk) {
            const int cb = kk * 64 + (l >> 4) * 16;
            #pragma unroll
            for (int n = 0; n < 4; ++n) {
                int r = n * 16 + (l & 15);
                bf16x8 kf = *(const bf16x8*)(Ks[cur] + r * 256 + (cb ^ ((r & 7) << 4)));
                sacc[n] = __builtin_amdgcn_mfma_f32_16x16x32_bf16(qf[kk], kf, sacc[n], 0, 0, 0);
            }
        }
        float rsp[4] = {0.f, 0.f, 0.f, 0.f};
        #pragma unroll
        for (int n = 0; n < 4; ++n)
            #pragma unroll
            for (int r = 0; r < 4; ++r) {
                int qrow = w * 16 + (l >> 4) * 4 + r;
                int tcol = n * 16 + (l & 15);
                int d = (s0 + qrow) - (t0 + tcol);
                float pm = (d >= 0) ? sacc[n][r] * __expf((float)d * ld) : 0.f;
                rsp[r] += pm;
                *(unsigned short*)(Ps + qrow * 128 + ((tcol * 2) ^ ((qrow & 7) << 4))) = f2bu(pm);
            }
        #pragma unroll
        for (int r = 0; r < 4; ++r) {
            float vv = rsp[r];
            vv += __shfl_xor(vv, 1, 16);
            vv += __shfl_xor(vv, 2, 16);
            vv += __shfl_xor(vv, 4, 16);
            vv += __shfl_xor(vv, 8, 16);
            rs[r] += vv;
        }
        #pragma unroll
        for (int kk = 0; kk < 2; ++kk) {
            const int cb = kk * 64 + (l >> 4) * 16;
            int pr = w * 16 + (l & 15);
            bf16x8 pf = *(const bf16x8*)(Ps + pr * 128 + (cb ^ ((pr & 7) << 4)));
            #pragma unroll
            for (int n2 = 0; n2 < 16; ++n2) {
                int r = n2 * 16 + (l & 15);
                bf16x8 vf = *(const bf16x8*)(Vs[cur] + r * 128 + (cb ^ ((r & 7) << 4)));
                oacc[n2] = __builtin_amdgcn_mfma_f32_16x16x32_bf16(pf, vf, oacc[n2], 0, 0, 0);
            }
        }
        __builtin_amdgcn_s_barrier();
        __builtin_amdgcn_sched_barrier(0);
    }

    float inv[4];
    #pragma unroll
    for (int r = 0; r < 4; ++r) inv[r] = 1.f / fmaxf(fabsf(rs[r]), 1.f);
    #pragma unroll
    for (int n2 = 0; n2 < 16; ++n2)
        #pragma unroll
        for (int r = 0; r < 4; ++r) {
            int row = s0 + w * 16 + (l >> 4) * 4 + r;
            int col = h * HD_ + n2 * 16 + (l & 15);
            float f = oacc[n2][r] * inv[r];
            if (!isfinite(f)) f = 0.f;
            ao[(size_t)(b * T_ + row) * V_ + col] = f2bu(f);
        }
}

// ---------------------------------------------------------------------------
// Per-(b,t,h): ao = silu(g) * ao * rsqrt(mean(ao^2) + eps).  [R4 verbatim]
// ---------------------------------------------------------------------------
__global__ __launch_bounds__(256) void rms_silu_kernel(
    unsigned short* __restrict__ ao, const unsigned short* __restrict__ g)
{
    __shared__ float part[4];
    const int tid = threadIdx.x;
    const size_t base = (size_t)blockIdx.x * HD_;
    const float f = u2f(ao[base + tid]);
    float sq = f * f;
    #pragma unroll
    for (int off = 32; off > 0; off >>= 1) sq += __shfl_down(sq, off, 64);
    if ((tid & 63) == 0) part[tid >> 6] = sq;
    __syncthreads();
    const float tot = part[0] + part[1] + part[2] + part[3];
    const float scale = rsqrtf(tot * (1.0f / HD_) + 1e-6f);
    const float gv = u2f(g[base + tid]);
    ao[base + tid] = f2bu(f * scale * gv / (1.f + __expf(-gv)));
}

extern "C" void kernel_launch(void* const* d_in, const int* in_sizes, int n_in,
                              void* d_out, int out_size, void* d_ws, size_t ws_size,
                              hipStream_t stream)
{
    const float* x    = (const float*)d_in[0];
    const float* sinp = (const float*)d_in[1];
    const float* cosp = (const float*)d_in[2];
    // d_in[3] = mask: decay computed analytically in-kernel
    const float* Wq   = (const float*)d_in[4];
    const float* Wk   = (const float*)d_in[5];
    const float* Wv   = (const float*)d_in[6];
    const float* Wg   = (const float*)d_in[7];
    const float* Wo   = (const float*)d_in[8];
    float* out = (float*)d_out;

    // d_out doubles as scratch (R4-proven): xb [0,8.39M) | qb [8.39M,16.78M).
    unsigned short* xb = (unsigned short*)d_out;
    unsigned short* qb = xb + (size_t)M_ * E_;

    // ws layout (R6-identical, 41.94 MB peak):
    char* ws = (char*)d_ws;
    unsigned short* kb  = (unsigned short*)ws;
    unsigned short* wt  = (unsigned short*)(ws + 8388608);
    unsigned short* vt  = (unsigned short*)(ws + 8388608);
    unsigned short* gb  = (unsigned short*)(ws + 8388608);
    unsigned short* vb  = (unsigned short*)(ws + 25165824);
    unsigned short* aob = (unsigned short*)(ws + 25165824);
    unsigned short* wgt = (unsigned short*)ws;
    unsigned short* wot = (unsigned short*)ws;

    dim3 blk(256);
    conv_x_kernel<<<M_ * E_ / 8 / 256, blk, 0, stream>>>(x, xb);

    transW_kernel<<<dim3(16, 16), blk, 0, stream>>>(Wq, wt, E_, E_);
    transW_kernel<<<dim3(16, 16), blk, 0, stream>>>(Wk, wt + (size_t)1024 * E_, E_, E_);
    transW_kernel<<<dim3(32, 16), blk, 0, stream>>>(Wv, wt + (size_t)2048 * E_, E_, V_);

    gemm_qkv3_kernel<<<dim3(32, 32), blk, 0, stream>>>(xb, wt, qb, kb, vb);

    theta_shift_kernel<<<M_ * E_ / 2 / 256, blk, 0, stream>>>(qb, sinp, cosp, 1.0f);
    theta_shift_kernel<<<M_ * E_ / 2 / 256, blk, 0, stream>>>(kb, sinp, cosp, 0.088388347648318447f);

    transV_kernel<<<dim3(32, 32, B_), blk, 0, stream>>>(vb, vt);  // kills wt

    retention_mfma_kernel<<<dim3(512), blk, 0, stream>>>(qb, kb, vt, aob);

    transW_kernel<<<dim3(32, 16), blk, 0, stream>>>(Wg, wgt, E_, V_);
    gemm_mfma_kernel<unsigned short><<<dim3(16, 32), blk, 0, stream>>>(xb, wgt, gb, V_, E_);

    rms_silu_kernel<<<B_ * T_ * H_, blk, 0, stream>>>(aob, gb);

    transW_kernel<<<dim3(16, 32), blk, 0, stream>>>(Wo, wot, V_, E_);
    gemm_mfma_kernel<float><<<dim3(8, 32), blk, 0, stream>>>(aob, wot, out, E_, V_);
}

// Round 10
// 249.943 us; speedup vs baseline: 1.0828x; 1.0313x over previous
//
#include <hip/hip_runtime.h>
#include <hip/hip_bf16.h>

// MultiScaleRetention forward, MI355X gfx950 — Round 10.
// R9: 258 µs; retention stuck at 96 µs (1 wave/SIMD, serial chain). This
// round restructures ONLY retention: 8-wave/512-thread blocks over 128 q-rows
// (halves stage traffic, 2 waves/SIMD), K/V dbuf + counted vmcnt(6) (R8-proven
// sync), and factorized decay mask (D^s * D^-t via per-thread constants —
// 16 exps/tile -> 4 muls/tile). GEMMs & glue byte-identical to R9.

#define B_ 2
#define T_ 2048
#define E_ 1024
#define V_ 2048
#define H_ 8
#define KD_ 128
#define HD_ 256
#define M_ 4096  // B_*T_

typedef __attribute__((ext_vector_type(8))) short bf16x8;
typedef __attribute__((ext_vector_type(4))) float f32x4;

__device__ __forceinline__ float u2f(unsigned short u) {
    return __uint_as_float(((unsigned)u) << 16);
}
__device__ __forceinline__ unsigned short f2bu(float f) {
    unsigned x = __float_as_uint(f);
    return (unsigned short)((x + 0x7fffu + ((x >> 16) & 1u)) >> 16);  // RNE
}

typedef const __attribute__((address_space(1))) void gas_t;
typedef __attribute__((address_space(3))) void las_t;
__device__ __forceinline__ void gl_lds16(const void* g, void* l) {
    __builtin_amdgcn_global_load_lds((gas_t*)g, (las_t*)l, 16, 0, 0);
}

__device__ __forceinline__ void stc(float* p, float f) { *p = f; }
__device__ __forceinline__ void stc(unsigned short* p, float f) { *p = f2bu(f); }

// ---------------------------------------------------------------------------
// x fp32 -> bf16 flat convert (8 elems/thread).  [R4 verbatim]
// ---------------------------------------------------------------------------
__global__ __launch_bounds__(256) void conv_x_kernel(
    const float* __restrict__ x, unsigned short* __restrict__ xb)
{
    const size_t i = ((size_t)blockIdx.x * 256 + threadIdx.x) * 8;
    float4 a = *(const float4*)(x + i);
    float4 c = *(const float4*)(x + i + 4);
    *(ushort4*)(xb + i)     = make_ushort4(f2bu(a.x), f2bu(a.y), f2bu(a.z), f2bu(a.w));
    *(ushort4*)(xb + i + 4) = make_ushort4(f2bu(c.x), f2bu(c.y), f2bu(c.z), f2bu(c.w));
}

// ---------------------------------------------------------------------------
// W [K][N] fp32 -> Wt [N][K] bf16 (64x64 LDS tile transpose).  [R4 verbatim]
// ---------------------------------------------------------------------------
__global__ __launch_bounds__(256) void transW_kernel(
    const float* __restrict__ W, unsigned short* __restrict__ Wt, int K, int N)
{
    __shared__ float tl[64][65];
    const int tid = threadIdx.x;
    const int n0 = blockIdx.x * 64, k0 = blockIdx.y * 64;
    #pragma unroll
    for (int i = 0; i < 4; ++i) {
        int kr = i * 16 + (tid >> 4);
        int nc = (tid & 15) * 4;
        float4 v = *(const float4*)(W + (size_t)(k0 + kr) * N + n0 + nc);
        tl[kr][nc] = v.x; tl[kr][nc + 1] = v.y; tl[kr][nc + 2] = v.z; tl[kr][nc + 3] = v.w;
    }
    __syncthreads();
    #pragma unroll
    for (int i = 0; i < 4; ++i) {
        int nr = i * 16 + (tid >> 4);
        int kc = (tid & 15) * 4;
        ushort4 u = make_ushort4(f2bu(tl[kc + 0][nr]), f2bu(tl[kc + 1][nr]),
                                 f2bu(tl[kc + 2][nr]), f2bu(tl[kc + 3][nr]));
        *(ushort4*)(Wt + (size_t)(n0 + nr) * K + k0 + kc) = u;
    }
}

// ---------------------------------------------------------------------------
// V [b*T + t][2048] bf16 -> Vt [b*2048 + c][T] bf16.  [R4 verbatim]
// ---------------------------------------------------------------------------
__global__ __launch_bounds__(256) void transV_kernel(
    const unsigned short* __restrict__ vb, unsigned short* __restrict__ vt)
{
    __shared__ unsigned short tl[64][68];
    const int tid = threadIdx.x;
    const int t0 = blockIdx.x * 64, c0 = blockIdx.y * 64, b = blockIdx.z;
    #pragma unroll
    for (int i = 0; i < 4; ++i) {
        int tr = i * 16 + (tid >> 4);
        int cc = (tid & 15) * 4;
        ushort4 v = *(const ushort4*)(vb + (size_t)(b * T_ + t0 + tr) * V_ + c0 + cc);
        tl[tr][cc] = v.x; tl[tr][cc + 1] = v.y; tl[tr][cc + 2] = v.z; tl[tr][cc + 3] = v.w;
    }
    __syncthreads();
    #pragma unroll
    for (int i = 0; i < 4; ++i) {
        int cr = i * 16 + (tid >> 4);
        int tc = (tid & 15) * 4;
        ushort4 u = make_ushort4(tl[tc + 0][cr], tl[tc + 1][cr], tl[tc + 2][cr], tl[tc + 3][cr]);
        *(ushort4*)(vt + (size_t)(b * V_ + c0 + cr) * T_ + t0 + tc) = u;
    }
}

// ---------------------------------------------------------------------------
// GEMM stage + compute building blocks (dbuf pipeline).  [R9 verbatim]
// ---------------------------------------------------------------------------
#define GSTAGE(BUF, K0)                                                        \
    {                                                                          \
        _Pragma("unroll")                                                      \
        for (int i = 0; i < 4; ++i) {                                          \
            int r = i * 32 + srow;                                             \
            int cb = scolb ^ ((r & 7) << 4);                                   \
            gl_lds16((const char*)(A  + (size_t)(rowBase + r) * K + (K0)) + cb,\
                     Asm[BUF] + i * 4096 + w * 1024);                          \
            gl_lds16((const char*)(Bt + (size_t)(colBase + r) * K + (K0)) + cb,\
                     Bsm[BUF] + i * 4096 + w * 1024);                          \
        }                                                                      \
    }

#define GCOMPUTE(BUF)                                                          \
    {                                                                          \
        _Pragma("unroll")                                                      \
        for (int kk = 0; kk < 2; ++kk) {                                       \
            const int cb = kk * 64 + (l >> 4) * 16;                            \
            bf16x8 a[4], b[4];                                                 \
            _Pragma("unroll")                                                  \
            for (int m = 0; m < 4; ++m) {                                      \
                int r = wr * 64 + m * 16 + (l & 15);                           \
                a[m] = *(const bf16x8*)(Asm[BUF] + r * 128 + (cb ^ ((r & 7) << 4))); \
            }                                                                  \
            _Pragma("unroll")                                                  \
            for (int n = 0; n < 4; ++n) {                                      \
                int r = wc * 64 + n * 16 + (l & 15);                           \
                b[n] = *(const bf16x8*)(Bsm[BUF] + r * 128 + (cb ^ ((r & 7) << 4))); \
            }                                                                  \
            _Pragma("unroll")                                                  \
            for (int m = 0; m < 4; ++m)                                        \
                _Pragma("unroll")                                              \
                for (int n = 0; n < 4; ++n)                                    \
                    acc[m][n] = __builtin_amdgcn_mfma_f32_16x16x32_bf16(a[m], b[n], acc[m][n], 0, 0, 0); \
        }                                                                      \
    }

#define GEMM_PIPELINE_LOOP                                                     \
    GSTAGE(0, 0)                                                               \
    const int nk = K / 64;                                                     \
    for (int kt = 0; kt < nk; ++kt) {                                          \
        const int cur = kt & 1;                                                \
        if (kt + 1 < nk) {                                                     \
            GSTAGE(1 - cur, (kt + 1) * 64)                                     \
            asm volatile("s_waitcnt vmcnt(8)" ::: "memory");                   \
        } else {                                                               \
            asm volatile("s_waitcnt vmcnt(0)" ::: "memory");                   \
        }                                                                      \
        __builtin_amdgcn_s_barrier();                                          \
        __builtin_amdgcn_sched_barrier(0);                                     \
        GCOMPUTE(cur)                                                          \
        __builtin_amdgcn_s_barrier();                                          \
        __builtin_amdgcn_sched_barrier(0);                                     \
    }

// ---------------------------------------------------------------------------
// MFMA GEMM (dbuf): C[M,N] = A[M,K] @ Bt[N,K]^T.  [R9 verbatim]
// ---------------------------------------------------------------------------
template <typename CT>
__global__ __launch_bounds__(256) void gemm_mfma_kernel(
    const unsigned short* __restrict__ A,
    const unsigned short* __restrict__ Bt,
    CT* __restrict__ C,
    int N, int K)
{
    __shared__ __align__(16) char Asm[2][128 * 64 * 2];
    __shared__ __align__(16) char Bsm[2][128 * 64 * 2];
    const int tid = threadIdx.x;
    const int l = tid & 63;
    const int w = tid >> 6;
    const int wr = w >> 1, wc = w & 1;
    const int rowBase = blockIdx.y * 128;
    const int colBase = blockIdx.x * 128;
    const int srow = tid >> 3;
    const int scolb = (tid & 7) * 16;

    f32x4 acc[4][4] = {};

    GEMM_PIPELINE_LOOP

    #pragma unroll
    for (int m = 0; m < 4; ++m)
        #pragma unroll
        for (int n = 0; n < 4; ++n)
            #pragma unroll
            for (int r = 0; r < 4; ++r) {
                int row = rowBase + wr * 64 + m * 16 + (l >> 4) * 4 + r;
                int col = colBase + wc * 64 + n * 16 + (l & 15);
                float f = acc[m][n][r];
                if (!isfinite(f)) f = 0.f;  // tripwire
                stc(C + (size_t)row * N + col, f);
            }
}

// ---------------------------------------------------------------------------
// Fused qkv GEMM (dbuf).  [R9 verbatim]
// ---------------------------------------------------------------------------
__global__ __launch_bounds__(256) void gemm_qkv3_kernel(
    const unsigned short* __restrict__ A,
    const unsigned short* __restrict__ Bt,
    unsigned short* __restrict__ qb,
    unsigned short* __restrict__ kb,
    unsigned short* __restrict__ vb)
{
    const int K = E_;
    __shared__ __align__(16) char Asm[2][128 * 64 * 2];
    __shared__ __align__(16) char Bsm[2][128 * 64 * 2];
    const int tid = threadIdx.x;
    const int l = tid & 63;
    const int w = tid >> 6;
    const int wr = w >> 1, wc = w & 1;
    const int rowBase = blockIdx.y * 128;
    const int colBase = blockIdx.x * 128;
    const int srow = tid >> 3;
    const int scolb = (tid & 7) * 16;

    f32x4 acc[4][4] = {};

    GEMM_PIPELINE_LOOP

    const int colW = colBase + wc * 64;
    unsigned short* dst;
    int cofs, stride;
    if (colW < 1024)      { dst = qb; cofs = 0;    stride = E_; }
    else if (colW < 2048) { dst = kb; cofs = 1024; stride = E_; }
    else                  { dst = vb; cofs = 2048; stride = V_; }
    #pragma unroll
    for (int m = 0; m < 4; ++m)
        #pragma unroll
        for (int n = 0; n < 4; ++n)
            #pragma unroll
            for (int r = 0; r < 4; ++r) {
                int row = rowBase + wr * 64 + m * 16 + (l >> 4) * 4 + r;
                int col = colW + n * 16 + (l & 15);
                float f = acc[m][n][r];
                if (!isfinite(f)) f = 0.f;  // tripwire
                dst[(size_t)row * stride + (col - cofs)] = f2bu(f);
            }
}

// ---------------------------------------------------------------------------
// theta_shift in place on bf16 [M_, E_].  [R4 verbatim]
// ---------------------------------------------------------------------------
__global__ __launch_bounds__(256) void theta_shift_kernel(
    unsigned short* __restrict__ qk,
    const float* __restrict__ sinp, const float* __restrict__ cosp, float scale)
{
    const int i = blockIdx.x * 256 + threadIdx.x;
    const int pe = i & (E_ / 2 - 1);
    const int bt = i >> 9;
    const int t = bt & (T_ - 1);
    const int e0 = pe << 1;
    const int d0 = e0 & (KD_ - 1);
    const size_t base = (size_t)bt * E_ + e0;
    const float q0 = u2f(qk[base]);
    const float q1 = u2f(qk[base + 1]);
    const int sb = t * KD_ + d0;
    const float s0 = sinp[sb], s1 = sinp[sb + 1];
    const float c0 = cosp[sb], c1 = cosp[sb + 1];
    qk[base]     = f2bu((q0 * c0 - q1 * s0) * scale);
    qk[base + 1] = f2bu((q1 * c1 + q0 * s1) * scale);
}

// ---------------------------------------------------------------------------
// Retention v2: 8-wave (512-thread) block over 128 q-rows of one (b,h).
// K/V double-buffered (counted vmcnt(6)); decay mask factorized D^s * D^-t.
// Grid 256 flat, XCD-swizzled (2 bh per XCD, L2-resident K/V).
// ---------------------------------------------------------------------------
#define STAGE_KV8(BUF, T0)                                                     \
    {                                                                          \
        _Pragma("unroll")                                                      \
        for (int i = 0; i < 2; ++i) {  /* K: 64 rows x 256 B */                \
            int r = i * 32 + (tid >> 4);                                       \
            int cb = ((tid & 15) * 16) ^ ((r & 7) << 4);                       \
            gl_lds16((const char*)(kb + (size_t)(b * T_ + (T0) + r) * E_ + h * KD_) + cb, \
                     Ks[BUF] + i * 8192 + w * 1024);                           \
        }                                                                      \
        _Pragma("unroll")                                                      \
        for (int i = 0; i < 4; ++i) {  /* Vt: 256 rows x 128 B */              \
            int c = i * 64 + (tid >> 3);                                       \
            int cb = ((tid & 7) * 16) ^ ((c & 7) << 4);                        \
            gl_lds16((const char*)(vt + (size_t)((b * H_ + h) * HD_ + c) * T_ + (T0)) + cb, \
                     Vs[BUF] + i * 8192 + w * 1024);                           \
        }                                                                      \
    }

__global__ __launch_bounds__(512) void retention_mfma_kernel(
    const unsigned short* __restrict__ qb,
    const unsigned short* __restrict__ kb,
    const unsigned short* __restrict__ vt,
    unsigned short* __restrict__ ao)
{
    __shared__ __align__(16) char Ks[2][64 * 128 * 2];    // 2 x 16 KB
    __shared__ __align__(16) char Vs[2][256 * 64 * 2];    // 2 x 32 KB
    __shared__ __align__(16) char Ps[128 * 64 * 2];       //     16 KB
    const int tid = threadIdx.x;    // 0..511
    const int l = tid & 63;
    const int w = tid >> 6;         // 0..7
    // XCD swizzle: orig&7 = hw XCD; each XCD owns 2 bh (3 MB K/V, L2-fits).
    const int orig = (int)blockIdx.x;          // 0..255
    const int work = (orig & 7) * 32 + (orig >> 3);
    const int bh = work >> 4;                  // 0..15
    const int chunk = 15 - (work & 15);        // longest-first
    const int b = bh >> 3, h = bh & 7;
    const int s0 = chunk * 128;
    const float ld = logf(1.f - exp2f(-5.f - (float)h));

    // factorized decay: mask(s,t) = D^s * D^-t  (D = e^ld < 1)
    float es[4], etl[4];
    #pragma unroll
    for (int r = 0; r < 4; ++r)
        es[r] = __expf((float)(s0 + w * 16 + (l >> 4) * 4 + r) * ld);
    #pragma unroll
    for (int n = 0; n < 4; ++n)
        etl[n] = __expf(-(float)(n * 16 + (l & 15)) * ld);
    const float Dm64 = __expf(-64.f * ld);
    float etb = 1.f;                           // D^-t0, updated per tile

    bf16x8 qf[4];
    {
        const char* qp = (const char*)(qb + (size_t)(b * T_ + s0 + w * 16 + (l & 15)) * E_ + h * KD_);
        #pragma unroll
        for (int kk = 0; kk < 4; ++kk)
            qf[kk] = *(const bf16x8*)(qp + kk * 64 + (l >> 4) * 16);
    }

    f32x4 oacc[16] = {};
    float rs[4] = {0.f, 0.f, 0.f, 0.f};

    const int nt = 2 * chunk + 2;              // tiles 0 .. 2*chunk+1
    STAGE_KV8(0, 0)

    for (int t = 0; t < nt; ++t) {
        const int cur = t & 1;
        if (t + 1 < nt) {
            STAGE_KV8(1 - cur, (t + 1) * 64)
            asm volatile("s_waitcnt vmcnt(6)" ::: "memory");   // tile t drained
        } else {
            asm volatile("s_waitcnt vmcnt(0)" ::: "memory");
        }
        __builtin_amdgcn_s_barrier();
        __builtin_amdgcn_sched_barrier(0);
        const int t0 = t * 64;

        // QK^T: wave's 16 q-rows x 64 t-cols
        f32x4 sacc[4] = {};
        #pragma unroll
        for (int kk = 0; kk < 4; ++kk) {
            const int cb = kk * 64 + (l >> 4) * 16;
            #pragma unroll
            for (int n = 0; n < 4; ++n) {
                int r = n * 16 + (l & 15);
                bf16x8 kf = *(const bf16x8*)(Ks[cur] + r * 256 + (cb ^ ((r & 7) << 4)));
                sacc[n] = __builtin_amdgcn_mfma_f32_16x16x32_bf16(qf[kk], kf, sacc[n], 0, 0, 0);
            }
        }
        // decay mask (factorized) + rowsum partials + P write (wave-private)
        float et[4];
        #pragma unroll
        for (int n = 0; n < 4; ++n) et[n] = etb * etl[n];
        etb *= Dm64;
        float rsp[4] = {0.f, 0.f, 0.f, 0.f};
        #pragma unroll
        for (int n = 0; n < 4; ++n)
            #pragma unroll
            for (int r = 0; r < 4; ++r) {
                int qrow = w * 16 + (l >> 4) * 4 + r;
                int tcol = n * 16 + (l & 15);
                int d = (s0 + qrow) - (t0 + tcol);
                float pm = (d >= 0) ? sacc[n][r] * (es[r] * et[n]) : 0.f;
                rsp[r] += pm;
                *(unsigned short*)(Ps + qrow * 128 + ((tcol * 2) ^ ((qrow & 7) << 4))) = f2bu(pm);
            }
        #pragma unroll
        for (int r = 0; r < 4; ++r) {
            float vv = rsp[r];
            vv += __shfl_xor(vv, 1, 16);
            vv += __shfl_xor(vv, 2, 16);
            vv += __shfl_xor(vv, 4, 16);
            vv += __shfl_xor(vv, 8, 16);
            rs[r] += vv;
        }
        // PV: O[16 q-rows][256] += P[16][64] @ V[64][256]
        #pragma unroll
        for (int kk = 0; kk < 2; ++kk) {
            const int cb = kk * 64 + (l >> 4) * 16;
            int pr = w * 16 + (l & 15);
            bf16x8 pf = *(const bf16x8*)(Ps + pr * 128 + (cb ^ ((pr & 7) << 4)));
            #pragma unroll
            for (int n2 = 0; n2 < 16; ++n2) {
                int r = n2 * 16 + (l & 15);
                bf16x8 vf = *(const bf16x8*)(Vs[cur] + r * 128 + (cb ^ ((r & 7) << 4)));
                oacc[n2] = __builtin_amdgcn_mfma_f32_16x16x32_bf16(pf, vf, oacc[n2], 0, 0, 0);
            }
        }
        __builtin_amdgcn_s_barrier();
        __builtin_amdgcn_sched_barrier(0);
    }

    float inv[4];
    #pragma unroll
    for (int r = 0; r < 4; ++r) inv[r] = 1.f / fmaxf(fabsf(rs[r]), 1.f);
    #pragma unroll
    for (int n2 = 0; n2 < 16; ++n2)
        #pragma unroll
        for (int r = 0; r < 4; ++r) {
            int row = s0 + w * 16 + (l >> 4) * 4 + r;
            int col = h * HD_ + n2 * 16 + (l & 15);
            float f = oacc[n2][r] * inv[r];
            if (!isfinite(f)) f = 0.f;
            ao[(size_t)(b * T_ + row) * V_ + col] = f2bu(f);
        }
}

// ---------------------------------------------------------------------------
// Per-(b,t,h): ao = silu(g) * ao * rsqrt(mean(ao^2) + eps).  [R4 verbatim]
// ---------------------------------------------------------------------------
__global__ __launch_bounds__(256) void rms_silu_kernel(
    unsigned short* __restrict__ ao, const unsigned short* __restrict__ g)
{
    __shared__ float part[4];
    const int tid = threadIdx.x;
    const size_t base = (size_t)blockIdx.x * HD_;
    const float f = u2f(ao[base + tid]);
    float sq = f * f;
    #pragma unroll
    for (int off = 32; off > 0; off >>= 1) sq += __shfl_down(sq, off, 64);
    if ((tid & 63) == 0) part[tid >> 6] = sq;
    __syncthreads();
    const float tot = part[0] + part[1] + part[2] + part[3];
    const float scale = rsqrtf(tot * (1.0f / HD_) + 1e-6f);
    const float gv = u2f(g[base + tid]);
    ao[base + tid] = f2bu(f * scale * gv / (1.f + __expf(-gv)));
}

extern "C" void kernel_launch(void* const* d_in, const int* in_sizes, int n_in,
                              void* d_out, int out_size, void* d_ws, size_t ws_size,
                              hipStream_t stream)
{
    const float* x    = (const float*)d_in[0];
    const float* sinp = (const float*)d_in[1];
    const float* cosp = (const float*)d_in[2];
    // d_in[3] = mask: decay computed analytically in-kernel
    const float* Wq   = (const float*)d_in[4];
    const float* Wk   = (const float*)d_in[5];
    const float* Wv   = (const float*)d_in[6];
    const float* Wg   = (const float*)d_in[7];
    const float* Wo   = (const float*)d_in[8];
    float* out = (float*)d_out;

    // d_out doubles as scratch (R4-proven): xb [0,8.39M) | qb [8.39M,16.78M).
    unsigned short* xb = (unsigned short*)d_out;
    unsigned short* qb = xb + (size_t)M_ * E_;

    // ws layout (R6-identical, 41.94 MB peak):
    char* ws = (char*)d_ws;
    unsigned short* kb  = (unsigned short*)ws;
    unsigned short* wt  = (unsigned short*)(ws + 8388608);
    unsigned short* vt  = (unsigned short*)(ws + 8388608);
    unsigned short* gb  = (unsigned short*)(ws + 8388608);
    unsigned short* vb  = (unsigned short*)(ws + 25165824);
    unsigned short* aob = (unsigned short*)(ws + 25165824);
    unsigned short* wgt = (unsigned short*)ws;
    unsigned short* wot = (unsigned short*)ws;

    dim3 blk(256);
    conv_x_kernel<<<M_ * E_ / 8 / 256, blk, 0, stream>>>(x, xb);

    transW_kernel<<<dim3(16, 16), blk, 0, stream>>>(Wq, wt, E_, E_);
    transW_kernel<<<dim3(16, 16), blk, 0, stream>>>(Wk, wt + (size_t)1024 * E_, E_, E_);
    transW_kernel<<<dim3(32, 16), blk, 0, stream>>>(Wv, wt + (size_t)2048 * E_, E_, V_);

    gemm_qkv3_kernel<<<dim3(32, 32), blk, 0, stream>>>(xb, wt, qb, kb, vb);

    theta_shift_kernel<<<M_ * E_ / 2 / 256, blk, 0, stream>>>(qb, sinp, cosp, 1.0f);
    theta_shift_kernel<<<M_ * E_ / 2 / 256, blk, 0, stream>>>(kb, sinp, cosp, 0.088388347648318447f);

    transV_kernel<<<dim3(32, 32, B_), blk, 0, stream>>>(vb, vt);  // kills wt

    retention_mfma_kernel<<<dim3(256), dim3(512), 0, stream>>>(qb, kb, vt, aob);

    transW_kernel<<<dim3(32, 16), blk, 0, stream>>>(Wg, wgt, E_, V_);
    gemm_mfma_kernel<unsigned short><<<dim3(16, 32), blk, 0, stream>>>(xb, wgt, gb, V_, E_);

    rms_silu_kernel<<<B_ * T_ * H_, blk, 0, stream>>>(aob, gb);

    transW_kernel<<<dim3(16, 32), blk, 0, stream>>>(Wo, wot, V_, E_);
    gemm_mfma_kernel<float><<<dim3(8, 32), blk, 0, stream>>>(aob, wot, out, E_, V_);
}

// Round 11
// 238.912 us; speedup vs baseline: 1.1328x; 1.0462x over previous
//
#include <hip/hip_runtime.h>
#include <hip/hip_bf16.h>

// MultiScaleRetention forward, MI355X gfx950 — Round 11.
// R10: retention 88 µs; wall = 32-tile blocks at 1 block/CU (LDS 112 KB), no
// TLP. This round: retention back to 64-row/4-wave blocks (grid 512) with LDS
// cut to 72 KB (K dbuf 32K + V single 32K + P 8K) -> 2 blocks/CU, and a
// complementarity swizzle pairing chunk (31-c) with chunk c (same bh) on each
// CU -> ~33 tiles per CU, 2-way parallel. 3-barrier tile loop with counted
// vmcnt (QK: 12, PV: 4). Factorized decay kept. All other kernels R10-verbatim.

#define B_ 2
#define T_ 2048
#define E_ 1024
#define V_ 2048
#define H_ 8
#define KD_ 128
#define HD_ 256
#define M_ 4096  // B_*T_

typedef __attribute__((ext_vector_type(8))) short bf16x8;
typedef __attribute__((ext_vector_type(4))) float f32x4;

__device__ __forceinline__ float u2f(unsigned short u) {
    return __uint_as_float(((unsigned)u) << 16);
}
__device__ __forceinline__ unsigned short f2bu(float f) {
    unsigned x = __float_as_uint(f);
    return (unsigned short)((x + 0x7fffu + ((x >> 16) & 1u)) >> 16);  // RNE
}

typedef const __attribute__((address_space(1))) void gas_t;
typedef __attribute__((address_space(3))) void las_t;
__device__ __forceinline__ void gl_lds16(const void* g, void* l) {
    __builtin_amdgcn_global_load_lds((gas_t*)g, (las_t*)l, 16, 0, 0);
}

__device__ __forceinline__ void stc(float* p, float f) { *p = f; }
__device__ __forceinline__ void stc(unsigned short* p, float f) { *p = f2bu(f); }

// ---------------------------------------------------------------------------
// x fp32 -> bf16 flat convert (8 elems/thread).  [R4 verbatim]
// ---------------------------------------------------------------------------
__global__ __launch_bounds__(256) void conv_x_kernel(
    const float* __restrict__ x, unsigned short* __restrict__ xb)
{
    const size_t i = ((size_t)blockIdx.x * 256 + threadIdx.x) * 8;
    float4 a = *(const float4*)(x + i);
    float4 c = *(const float4*)(x + i + 4);
    *(ushort4*)(xb + i)     = make_ushort4(f2bu(a.x), f2bu(a.y), f2bu(a.z), f2bu(a.w));
    *(ushort4*)(xb + i + 4) = make_ushort4(f2bu(c.x), f2bu(c.y), f2bu(c.z), f2bu(c.w));
}

// ---------------------------------------------------------------------------
// W [K][N] fp32 -> Wt [N][K] bf16 (64x64 LDS tile transpose).  [R4 verbatim]
// ---------------------------------------------------------------------------
__global__ __launch_bounds__(256) void transW_kernel(
    const float* __restrict__ W, unsigned short* __restrict__ Wt, int K, int N)
{
    __shared__ float tl[64][65];
    const int tid = threadIdx.x;
    const int n0 = blockIdx.x * 64, k0 = blockIdx.y * 64;
    #pragma unroll
    for (int i = 0; i < 4; ++i) {
        int kr = i * 16 + (tid >> 4);
        int nc = (tid & 15) * 4;
        float4 v = *(const float4*)(W + (size_t)(k0 + kr) * N + n0 + nc);
        tl[kr][nc] = v.x; tl[kr][nc + 1] = v.y; tl[kr][nc + 2] = v.z; tl[kr][nc + 3] = v.w;
    }
    __syncthreads();
    #pragma unroll
    for (int i = 0; i < 4; ++i) {
        int nr = i * 16 + (tid >> 4);
        int kc = (tid & 15) * 4;
        ushort4 u = make_ushort4(f2bu(tl[kc + 0][nr]), f2bu(tl[kc + 1][nr]),
                                 f2bu(tl[kc + 2][nr]), f2bu(tl[kc + 3][nr]));
        *(ushort4*)(Wt + (size_t)(n0 + nr) * K + k0 + kc) = u;
    }
}

// ---------------------------------------------------------------------------
// V [b*T + t][2048] bf16 -> Vt [b*2048 + c][T] bf16.  [R4 verbatim]
// ---------------------------------------------------------------------------
__global__ __launch_bounds__(256) void transV_kernel(
    const unsigned short* __restrict__ vb, unsigned short* __restrict__ vt)
{
    __shared__ unsigned short tl[64][68];
    const int tid = threadIdx.x;
    const int t0 = blockIdx.x * 64, c0 = blockIdx.y * 64, b = blockIdx.z;
    #pragma unroll
    for (int i = 0; i < 4; ++i) {
        int tr = i * 16 + (tid >> 4);
        int cc = (tid & 15) * 4;
        ushort4 v = *(const ushort4*)(vb + (size_t)(b * T_ + t0 + tr) * V_ + c0 + cc);
        tl[tr][cc] = v.x; tl[tr][cc + 1] = v.y; tl[tr][cc + 2] = v.z; tl[tr][cc + 3] = v.w;
    }
    __syncthreads();
    #pragma unroll
    for (int i = 0; i < 4; ++i) {
        int cr = i * 16 + (tid >> 4);
        int tc = (tid & 15) * 4;
        ushort4 u = make_ushort4(tl[tc + 0][cr], tl[tc + 1][cr], tl[tc + 2][cr], tl[tc + 3][cr]);
        *(ushort4*)(vt + (size_t)(b * V_ + c0 + cr) * T_ + t0 + tc) = u;
    }
}

// ---------------------------------------------------------------------------
// GEMM stage + compute building blocks (dbuf pipeline).  [R9 verbatim]
// ---------------------------------------------------------------------------
#define GSTAGE(BUF, K0)                                                        \
    {                                                                          \
        _Pragma("unroll")                                                      \
        for (int i = 0; i < 4; ++i) {                                          \
            int r = i * 32 + srow;                                             \
            int cb = scolb ^ ((r & 7) << 4);                                   \
            gl_lds16((const char*)(A  + (size_t)(rowBase + r) * K + (K0)) + cb,\
                     Asm[BUF] + i * 4096 + w * 1024);                          \
            gl_lds16((const char*)(Bt + (size_t)(colBase + r) * K + (K0)) + cb,\
                     Bsm[BUF] + i * 4096 + w * 1024);                          \
        }                                                                      \
    }

#define GCOMPUTE(BUF)                                                          \
    {                                                                          \
        _Pragma("unroll")                                                      \
        for (int kk = 0; kk < 2; ++kk) {                                       \
            const int cb = kk * 64 + (l >> 4) * 16;                            \
            bf16x8 a[4], b[4];                                                 \
            _Pragma("unroll")                                                  \
            for (int m = 0; m < 4; ++m) {                                      \
                int r = wr * 64 + m * 16 + (l & 15);                           \
                a[m] = *(const bf16x8*)(Asm[BUF] + r * 128 + (cb ^ ((r & 7) << 4))); \
            }                                                                  \
            _Pragma("unroll")                                                  \
            for (int n = 0; n < 4; ++n) {                                      \
                int r = wc * 64 + n * 16 + (l & 15);                           \
                b[n] = *(const bf16x8*)(Bsm[BUF] + r * 128 + (cb ^ ((r & 7) << 4))); \
            }                                                                  \
            _Pragma("unroll")                                                  \
            for (int m = 0; m < 4; ++m)                                        \
                _Pragma("unroll")                                              \
                for (int n = 0; n < 4; ++n)                                    \
                    acc[m][n] = __builtin_amdgcn_mfma_f32_16x16x32_bf16(a[m], b[n], acc[m][n], 0, 0, 0); \
        }                                                                      \
    }

#define GEMM_PIPELINE_LOOP                                                     \
    GSTAGE(0, 0)                                                               \
    const int nk = K / 64;                                                     \
    for (int kt = 0; kt < nk; ++kt) {                                          \
        const int cur = kt & 1;                                                \
        if (kt + 1 < nk) {                                                     \
            GSTAGE(1 - cur, (kt + 1) * 64)                                     \
            asm volatile("s_waitcnt vmcnt(8)" ::: "memory");                   \
        } else {                                                               \
            asm volatile("s_waitcnt vmcnt(0)" ::: "memory");                   \
        }                                                                      \
        __builtin_amdgcn_s_barrier();                                          \
        __builtin_amdgcn_sched_barrier(0);                                     \
        GCOMPUTE(cur)                                                          \
        __builtin_amdgcn_s_barrier();                                          \
        __builtin_amdgcn_sched_barrier(0);                                     \
    }

// ---------------------------------------------------------------------------
// MFMA GEMM (dbuf): C[M,N] = A[M,K] @ Bt[N,K]^T.  [R9 verbatim]
// ---------------------------------------------------------------------------
template <typename CT>
__global__ __launch_bounds__(256) void gemm_mfma_kernel(
    const unsigned short* __restrict__ A,
    const unsigned short* __restrict__ Bt,
    CT* __restrict__ C,
    int N, int K)
{
    __shared__ __align__(16) char Asm[2][128 * 64 * 2];
    __shared__ __align__(16) char Bsm[2][128 * 64 * 2];
    const int tid = threadIdx.x;
    const int l = tid & 63;
    const int w = tid >> 6;
    const int wr = w >> 1, wc = w & 1;
    const int rowBase = blockIdx.y * 128;
    const int colBase = blockIdx.x * 128;
    const int srow = tid >> 3;
    const int scolb = (tid & 7) * 16;

    f32x4 acc[4][4] = {};

    GEMM_PIPELINE_LOOP

    #pragma unroll
    for (int m = 0; m < 4; ++m)
        #pragma unroll
        for (int n = 0; n < 4; ++n)
            #pragma unroll
            for (int r = 0; r < 4; ++r) {
                int row = rowBase + wr * 64 + m * 16 + (l >> 4) * 4 + r;
                int col = colBase + wc * 64 + n * 16 + (l & 15);
                float f = acc[m][n][r];
                if (!isfinite(f)) f = 0.f;  // tripwire
                stc(C + (size_t)row * N + col, f);
            }
}

// ---------------------------------------------------------------------------
// Fused qkv GEMM (dbuf).  [R9 verbatim]
// ---------------------------------------------------------------------------
__global__ __launch_bounds__(256) void gemm_qkv3_kernel(
    const unsigned short* __restrict__ A,
    const unsigned short* __restrict__ Bt,
    unsigned short* __restrict__ qb,
    unsigned short* __restrict__ kb,
    unsigned short* __restrict__ vb)
{
    const int K = E_;
    __shared__ __align__(16) char Asm[2][128 * 64 * 2];
    __shared__ __align__(16) char Bsm[2][128 * 64 * 2];
    const int tid = threadIdx.x;
    const int l = tid & 63;
    const int w = tid >> 6;
    const int wr = w >> 1, wc = w & 1;
    const int rowBase = blockIdx.y * 128;
    const int colBase = blockIdx.x * 128;
    const int srow = tid >> 3;
    const int scolb = (tid & 7) * 16;

    f32x4 acc[4][4] = {};

    GEMM_PIPELINE_LOOP

    const int colW = colBase + wc * 64;
    unsigned short* dst;
    int cofs, stride;
    if (colW < 1024)      { dst = qb; cofs = 0;    stride = E_; }
    else if (colW < 2048) { dst = kb; cofs = 1024; stride = E_; }
    else                  { dst = vb; cofs = 2048; stride = V_; }
    #pragma unroll
    for (int m = 0; m < 4; ++m)
        #pragma unroll
        for (int n = 0; n < 4; ++n)
            #pragma unroll
            for (int r = 0; r < 4; ++r) {
                int row = rowBase + wr * 64 + m * 16 + (l >> 4) * 4 + r;
                int col = colW + n * 16 + (l & 15);
                float f = acc[m][n][r];
                if (!isfinite(f)) f = 0.f;  // tripwire
                dst[(size_t)row * stride + (col - cofs)] = f2bu(f);
            }
}

// ---------------------------------------------------------------------------
// theta_shift in place on bf16 [M_, E_].  [R4 verbatim]
// ---------------------------------------------------------------------------
__global__ __launch_bounds__(256) void theta_shift_kernel(
    unsigned short* __restrict__ qk,
    const float* __restrict__ sinp, const float* __restrict__ cosp, float scale)
{
    const int i = blockIdx.x * 256 + threadIdx.x;
    const int pe = i & (E_ / 2 - 1);
    const int bt = i >> 9;
    const int t = bt & (T_ - 1);
    const int e0 = pe << 1;
    const int d0 = e0 & (KD_ - 1);
    const size_t base = (size_t)bt * E_ + e0;
    const float q0 = u2f(qk[base]);
    const float q1 = u2f(qk[base + 1]);
    const int sb = t * KD_ + d0;
    const float s0 = sinp[sb], s1 = sinp[sb + 1];
    const float c0 = cosp[sb], c1 = cosp[sb + 1];
    qk[base]     = f2bu((q0 * c0 - q1 * s0) * scale);
    qk[base + 1] = f2bu((q1 * c1 + q0 * s1) * scale);
}

// ---------------------------------------------------------------------------
// Retention v3: 64-row/4-wave blocks, grid 512, 2 blocks/CU (LDS 72 KB:
// K dbuf + V single + P). Complementarity swizzle: CU pairs chunk (31-c15)
// [orig<256] with chunk c15 [orig>=256] of the same bh -> 33 tiles/CU,
// 2-way parallel. 3 barriers/tile, counted vmcnt (QK:12, PV:4).
// Factorized decay mask D^s * D^-t.
// ---------------------------------------------------------------------------
#define STAGE_K(BUF, T0)                                                       \
    {                                                                          \
        _Pragma("unroll")                                                      \
        for (int i = 0; i < 4; ++i) {                                          \
            int r = i * 16 + (tid >> 4);                                       \
            int cb = ((tid & 15) * 16) ^ ((r & 7) << 4);                       \
            gl_lds16((const char*)(kb + (size_t)(b * T_ + (T0) + r) * E_ + h * KD_) + cb, \
                     Ks[BUF] + i * 4096 + w * 1024);                           \
        }                                                                      \
    }

#define STAGE_V(T0)                                                            \
    {                                                                          \
        _Pragma("unroll")                                                      \
        for (int i = 0; i < 8; ++i) {                                          \
            int r = i * 32 + (tid >> 3);                                       \
            int cb = ((tid & 7) * 16) ^ ((r & 7) << 4);                        \
            gl_lds16((const char*)(vt + (size_t)((b * H_ + h) * HD_ + r) * T_ + (T0)) + cb, \
                     Vs + i * 4096 + w * 1024);                                \
        }                                                                      \
    }

__global__ __launch_bounds__(256) void retention_mfma_kernel(
    const unsigned short* __restrict__ qb,
    const unsigned short* __restrict__ kb,
    const unsigned short* __restrict__ vt,
    unsigned short* __restrict__ ao)
{
    __shared__ __align__(16) char Ks[2][64 * 128 * 2];   // 2 x 16 KB
    __shared__ __align__(16) char Vs[256 * 64 * 2];      //     32 KB
    __shared__ __align__(16) char Ps[64 * 64 * 2];       //      8 KB
    const int tid = threadIdx.x;
    const int l = tid & 63;
    const int w = tid >> 6;
    // Complementarity swizzle (bijective on [0,512)): orig and orig+256 land
    // on the same CU under round-robin XCD/CU dispatch; sizes sum to 33.
    const int orig = (int)blockIdx.x;
    const int xcd  = orig & 7;
    const int pos  = orig >> 3;          // 0..63
    const int slot = pos >> 5;           // 0: big half, 1: small half
    const int cu   = pos & 31;
    const int half = cu >> 4;
    const int c15  = cu & 15;
    const int bh   = xcd * 2 + half;     // 0..15, 2 bh per XCD (L2-resident K/V)
    const int chunk = slot ? c15 : (31 - c15);   // sizes pair to 33
    const int b = bh >> 3, h = bh & 7;
    const int s0 = chunk * 64;
    const float ld = logf(1.f - exp2f(-5.f - (float)h));

    // factorized decay: mask(s,t) = D^s * D^-t  (D = e^ld < 1)
    float es[4], etl[4];
    #pragma unroll
    for (int r = 0; r < 4; ++r)
        es[r] = __expf((float)(s0 + w * 16 + (l >> 4) * 4 + r) * ld);
    #pragma unroll
    for (int n = 0; n < 4; ++n)
        etl[n] = __expf(-(float)(n * 16 + (l & 15)) * ld);
    const float Dm64 = __expf(-64.f * ld);
    float etb = 1.f;

    bf16x8 qf[4];
    {
        const char* qp = (const char*)(qb + (size_t)(b * T_ + s0 + w * 16 + (l & 15)) * E_ + h * KD_);
        #pragma unroll
        for (int kk = 0; kk < 4; ++kk)
            qf[kk] = *(const bf16x8*)(qp + kk * 64 + (l >> 4) * 16);
    }

    f32x4 oacc[16] = {};
    float rs[4] = {0.f, 0.f, 0.f, 0.f};

    const int nt = chunk + 1;
    STAGE_K(0, 0)                                   // prologue: K(0), 4 loads

    for (int t = 0; t < nt; ++t) {
        const int cur = t & 1;
        const int t0 = t * 64;
        STAGE_V(t0)                                 // V(t), 8 loads
        if (t + 1 < nt) {
            STAGE_K(1 - cur, t0 + 64)               // K(t+1), 4 loads
            asm volatile("s_waitcnt vmcnt(12)" ::: "memory");  // K(t) landed
        } else {
            asm volatile("s_waitcnt vmcnt(8)" ::: "memory");   // K(t) landed
        }
        __builtin_amdgcn_s_barrier();
        __builtin_amdgcn_sched_barrier(0);

        // QK^T: wave's 16 q-rows x 64 t-cols from Ks[cur]
        f32x4 sacc[4] = {};
        #pragma unroll
        for (int kk = 0; kk < 4; ++kk) {
            const int cb = kk * 64 + (l >> 4) * 16;
            #pragma unroll
            for (int n = 0; n < 4; ++n) {
                int r = n * 16 + (l & 15);
                bf16x8 kf = *(const bf16x8*)(Ks[cur] + r * 256 + (cb ^ ((r & 7) << 4)));
                sacc[n] = __builtin_amdgcn_mfma_f32_16x16x32_bf16(qf[kk], kf, sacc[n], 0, 0, 0);
            }
        }
        // decay mask (factorized) + rowsum partials + P write (wave-private)
        float et[4];
        #pragma unroll
        for (int n = 0; n < 4; ++n) et[n] = etb * etl[n];
        etb *= Dm64;
        float rsp[4] = {0.f, 0.f, 0.f, 0.f};
        #pragma unroll
        for (int n = 0; n < 4; ++n)
            #pragma unroll
            for (int r = 0; r < 4; ++r) {
                int qrow = w * 16 + (l >> 4) * 4 + r;
                int tcol = n * 16 + (l & 15);
                int d = (s0 + qrow) - (t0 + tcol);
                float pm = (d >= 0) ? sacc[n][r] * (es[r] * et[n]) : 0.f;
                rsp[r] += pm;
                *(unsigned short*)(Ps + qrow * 128 + ((tcol * 2) ^ ((qrow & 7) << 4))) = f2bu(pm);
            }
        #pragma unroll
        for (int r = 0; r < 4; ++r) {
            float vv = rsp[r];
            vv += __shfl_xor(vv, 1, 16);
            vv += __shfl_xor(vv, 2, 16);
            vv += __shfl_xor(vv, 4, 16);
            vv += __shfl_xor(vv, 8, 16);
            rs[r] += vv;
        }
        // V(t) must be fully in LDS (all waves) before PV
        if (t + 1 < nt) {
            asm volatile("s_waitcnt vmcnt(4)" ::: "memory");   // leave K(t+1)
        } else {
            asm volatile("s_waitcnt vmcnt(0)" ::: "memory");
        }
        __builtin_amdgcn_s_barrier();
        __builtin_amdgcn_sched_barrier(0);
        // PV: O[16 q-rows][256] += P[16][64] @ V[64][256]
        #pragma unroll
        for (int kk = 0; kk < 2; ++kk) {
            const int cb = kk * 64 + (l >> 4) * 16;
            int pr = w * 16 + (l & 15);
            bf16x8 pf = *(const bf16x8*)(Ps + pr * 128 + (cb ^ ((pr & 7) << 4)));
            #pragma unroll
            for (int n2 = 0; n2 < 16; ++n2) {
                int r = n2 * 16 + (l & 15);
                bf16x8 vf = *(const bf16x8*)(Vs + r * 128 + (cb ^ ((r & 7) << 4)));
                oacc[n2] = __builtin_amdgcn_mfma_f32_16x16x32_bf16(pf, vf, oacc[n2], 0, 0, 0);
            }
        }
        __builtin_amdgcn_s_barrier();       // all waves done with Vs before restage
        __builtin_amdgcn_sched_barrier(0);
    }

    float inv[4];
    #pragma unroll
    for (int r = 0; r < 4; ++r) inv[r] = 1.f / fmaxf(fabsf(rs[r]), 1.f);
    #pragma unroll
    for (int n2 = 0; n2 < 16; ++n2)
        #pragma unroll
        for (int r = 0; r < 4; ++r) {
            int row = s0 + w * 16 + (l >> 4) * 4 + r;
            int col = h * HD_ + n2 * 16 + (l & 15);
            float f = oacc[n2][r] * inv[r];
            if (!isfinite(f)) f = 0.f;
            ao[(size_t)(b * T_ + row) * V_ + col] = f2bu(f);
        }
}

// ---------------------------------------------------------------------------
// Per-(b,t,h): ao = silu(g) * ao * rsqrt(mean(ao^2) + eps).  [R4 verbatim]
// ---------------------------------------------------------------------------
__global__ __launch_bounds__(256) void rms_silu_kernel(
    unsigned short* __restrict__ ao, const unsigned short* __restrict__ g)
{
    __shared__ float part[4];
    const int tid = threadIdx.x;
    const size_t base = (size_t)blockIdx.x * HD_;
    const float f = u2f(ao[base + tid]);
    float sq = f * f;
    #pragma unroll
    for (int off = 32; off > 0; off >>= 1) sq += __shfl_down(sq, off, 64);
    if ((tid & 63) == 0) part[tid >> 6] = sq;
    __syncthreads();
    const float tot = part[0] + part[1] + part[2] + part[3];
    const float scale = rsqrtf(tot * (1.0f / HD_) + 1e-6f);
    const float gv = u2f(g[base + tid]);
    ao[base + tid] = f2bu(f * scale * gv / (1.f + __expf(-gv)));
}

extern "C" void kernel_launch(void* const* d_in, const int* in_sizes, int n_in,
                              void* d_out, int out_size, void* d_ws, size_t ws_size,
                              hipStream_t stream)
{
    const float* x    = (const float*)d_in[0];
    const float* sinp = (const float*)d_in[1];
    const float* cosp = (const float*)d_in[2];
    // d_in[3] = mask: decay computed analytically in-kernel
    const float* Wq   = (const float*)d_in[4];
    const float* Wk   = (const float*)d_in[5];
    const float* Wv   = (const float*)d_in[6];
    const float* Wg   = (const float*)d_in[7];
    const float* Wo   = (const float*)d_in[8];
    float* out = (float*)d_out;

    // d_out doubles as scratch (R4-proven): xb [0,8.39M) | qb [8.39M,16.78M).
    unsigned short* xb = (unsigned short*)d_out;
    unsigned short* qb = xb + (size_t)M_ * E_;

    // ws layout (R6-identical, 41.94 MB peak):
    char* ws = (char*)d_ws;
    unsigned short* kb  = (unsigned short*)ws;
    unsigned short* wt  = (unsigned short*)(ws + 8388608);
    unsigned short* vt  = (unsigned short*)(ws + 8388608);
    unsigned short* gb  = (unsigned short*)(ws + 8388608);
    unsigned short* vb  = (unsigned short*)(ws + 25165824);
    unsigned short* aob = (unsigned short*)(ws + 25165824);
    unsigned short* wgt = (unsigned short*)ws;
    unsigned short* wot = (unsigned short*)ws;

    dim3 blk(256);
    conv_x_kernel<<<M_ * E_ / 8 / 256, blk, 0, stream>>>(x, xb);

    transW_kernel<<<dim3(16, 16), blk, 0, stream>>>(Wq, wt, E_, E_);
    transW_kernel<<<dim3(16, 16), blk, 0, stream>>>(Wk, wt + (size_t)1024 * E_, E_, E_);
    transW_kernel<<<dim3(32, 16), blk, 0, stream>>>(Wv, wt + (size_t)2048 * E_, E_, V_);

    gemm_qkv3_kernel<<<dim3(32, 32), blk, 0, stream>>>(xb, wt, qb, kb, vb);

    theta_shift_kernel<<<M_ * E_ / 2 / 256, blk, 0, stream>>>(qb, sinp, cosp, 1.0f);
    theta_shift_kernel<<<M_ * E_ / 2 / 256, blk, 0, stream>>>(kb, sinp, cosp, 0.088388347648318447f);

    transV_kernel<<<dim3(32, 32, B_), blk, 0, stream>>>(vb, vt);  // kills wt

    retention_mfma_kernel<<<dim3(512), blk, 0, stream>>>(qb, kb, vt, aob);

    transW_kernel<<<dim3(32, 16), blk, 0, stream>>>(Wg, wgt, E_, V_);
    gemm_mfma_kernel<unsigned short><<<dim3(16, 32), blk, 0, stream>>>(xb, wgt, gb, V_, E_);

    rms_silu_kernel<<<B_ * T_ * H_, blk, 0, stream>>>(aob, gb);

    transW_kernel<<<dim3(16, 32), blk, 0, stream>>>(Wo, wot, V_, E_);
    gemm_mfma_kernel<float><<<dim3(8, 32), blk, 0, stream>>>(aob, wot, out, E_, V_);
}

// Round 12
// 233.054 us; speedup vs baseline: 1.1613x; 1.0251x over previous
//
#include <hip/hip_runtime.h>
#include <hip/hip_bf16.h>

// MultiScaleRetention forward, MI355X gfx950 — Round 12.
// R11: 239 µs; retention 77 µs, LDS-BW-bound (each wave redundantly reads the
// whole V tile in PV: 200 KB LDS reads per block-tile). This round: PV column
// decomposition — wave w computes O[64 rows][its 64-col slice]; PV reads/wave
// 34 -> 16 (-35% total LDS traffic). Requires cross-wave P visibility
// (lgkmcnt(0) before the pre-PV barrier) and a 64-float rowsum broadcast in
// the epilogue. All other kernels byte-identical to R11.

#define B_ 2
#define T_ 2048
#define E_ 1024
#define V_ 2048
#define H_ 8
#define KD_ 128
#define HD_ 256
#define M_ 4096  // B_*T_

typedef __attribute__((ext_vector_type(8))) short bf16x8;
typedef __attribute__((ext_vector_type(4))) float f32x4;

__device__ __forceinline__ float u2f(unsigned short u) {
    return __uint_as_float(((unsigned)u) << 16);
}
__device__ __forceinline__ unsigned short f2bu(float f) {
    unsigned x = __float_as_uint(f);
    return (unsigned short)((x + 0x7fffu + ((x >> 16) & 1u)) >> 16);  // RNE
}

typedef const __attribute__((address_space(1))) void gas_t;
typedef __attribute__((address_space(3))) void las_t;
__device__ __forceinline__ void gl_lds16(const void* g, void* l) {
    __builtin_amdgcn_global_load_lds((gas_t*)g, (las_t*)l, 16, 0, 0);
}

__device__ __forceinline__ void stc(float* p, float f) { *p = f; }
__device__ __forceinline__ void stc(unsigned short* p, float f) { *p = f2bu(f); }

// ---------------------------------------------------------------------------
// x fp32 -> bf16 flat convert (8 elems/thread).  [R4 verbatim]
// ---------------------------------------------------------------------------
__global__ __launch_bounds__(256) void conv_x_kernel(
    const float* __restrict__ x, unsigned short* __restrict__ xb)
{
    const size_t i = ((size_t)blockIdx.x * 256 + threadIdx.x) * 8;
    float4 a = *(const float4*)(x + i);
    float4 c = *(const float4*)(x + i + 4);
    *(ushort4*)(xb + i)     = make_ushort4(f2bu(a.x), f2bu(a.y), f2bu(a.z), f2bu(a.w));
    *(ushort4*)(xb + i + 4) = make_ushort4(f2bu(c.x), f2bu(c.y), f2bu(c.z), f2bu(c.w));
}

// ---------------------------------------------------------------------------
// W [K][N] fp32 -> Wt [N][K] bf16 (64x64 LDS tile transpose).  [R4 verbatim]
// ---------------------------------------------------------------------------
__global__ __launch_bounds__(256) void transW_kernel(
    const float* __restrict__ W, unsigned short* __restrict__ Wt, int K, int N)
{
    __shared__ float tl[64][65];
    const int tid = threadIdx.x;
    const int n0 = blockIdx.x * 64, k0 = blockIdx.y * 64;
    #pragma unroll
    for (int i = 0; i < 4; ++i) {
        int kr = i * 16 + (tid >> 4);
        int nc = (tid & 15) * 4;
        float4 v = *(const float4*)(W + (size_t)(k0 + kr) * N + n0 + nc);
        tl[kr][nc] = v.x; tl[kr][nc + 1] = v.y; tl[kr][nc + 2] = v.z; tl[kr][nc + 3] = v.w;
    }
    __syncthreads();
    #pragma unroll
    for (int i = 0; i < 4; ++i) {
        int nr = i * 16 + (tid >> 4);
        int kc = (tid & 15) * 4;
        ushort4 u = make_ushort4(f2bu(tl[kc + 0][nr]), f2bu(tl[kc + 1][nr]),
                                 f2bu(tl[kc + 2][nr]), f2bu(tl[kc + 3][nr]));
        *(ushort4*)(Wt + (size_t)(n0 + nr) * K + k0 + kc) = u;
    }
}

// ---------------------------------------------------------------------------
// V [b*T + t][2048] bf16 -> Vt [b*2048 + c][T] bf16.  [R4 verbatim]
// ---------------------------------------------------------------------------
__global__ __launch_bounds__(256) void transV_kernel(
    const unsigned short* __restrict__ vb, unsigned short* __restrict__ vt)
{
    __shared__ unsigned short tl[64][68];
    const int tid = threadIdx.x;
    const int t0 = blockIdx.x * 64, c0 = blockIdx.y * 64, b = blockIdx.z;
    #pragma unroll
    for (int i = 0; i < 4; ++i) {
        int tr = i * 16 + (tid >> 4);
        int cc = (tid & 15) * 4;
        ushort4 v = *(const ushort4*)(vb + (size_t)(b * T_ + t0 + tr) * V_ + c0 + cc);
        tl[tr][cc] = v.x; tl[tr][cc + 1] = v.y; tl[tr][cc + 2] = v.z; tl[tr][cc + 3] = v.w;
    }
    __syncthreads();
    #pragma unroll
    for (int i = 0; i < 4; ++i) {
        int cr = i * 16 + (tid >> 4);
        int tc = (tid & 15) * 4;
        ushort4 u = make_ushort4(tl[tc + 0][cr], tl[tc + 1][cr], tl[tc + 2][cr], tl[tc + 3][cr]);
        *(ushort4*)(vt + (size_t)(b * V_ + c0 + cr) * T_ + t0 + tc) = u;
    }
}

// ---------------------------------------------------------------------------
// GEMM stage + compute building blocks (dbuf pipeline).  [R9 verbatim]
// ---------------------------------------------------------------------------
#define GSTAGE(BUF, K0)                                                        \
    {                                                                          \
        _Pragma("unroll")                                                      \
        for (int i = 0; i < 4; ++i) {                                          \
            int r = i * 32 + srow;                                             \
            int cb = scolb ^ ((r & 7) << 4);                                   \
            gl_lds16((const char*)(A  + (size_t)(rowBase + r) * K + (K0)) + cb,\
                     Asm[BUF] + i * 4096 + w * 1024);                          \
            gl_lds16((const char*)(Bt + (size_t)(colBase + r) * K + (K0)) + cb,\
                     Bsm[BUF] + i * 4096 + w * 1024);                          \
        }                                                                      \
    }

#define GCOMPUTE(BUF)                                                          \
    {                                                                          \
        _Pragma("unroll")                                                      \
        for (int kk = 0; kk < 2; ++kk) {                                       \
            const int cb = kk * 64 + (l >> 4) * 16;                            \
            bf16x8 a[4], b[4];                                                 \
            _Pragma("unroll")                                                  \
            for (int m = 0; m < 4; ++m) {                                      \
                int r = wr * 64 + m * 16 + (l & 15);                           \
                a[m] = *(const bf16x8*)(Asm[BUF] + r * 128 + (cb ^ ((r & 7) << 4))); \
            }                                                                  \
            _Pragma("unroll")                                                  \
            for (int n = 0; n < 4; ++n) {                                      \
                int r = wc * 64 + n * 16 + (l & 15);                           \
                b[n] = *(const bf16x8*)(Bsm[BUF] + r * 128 + (cb ^ ((r & 7) << 4))); \
            }                                                                  \
            _Pragma("unroll")                                                  \
            for (int m = 0; m < 4; ++m)                                        \
                _Pragma("unroll")                                              \
                for (int n = 0; n < 4; ++n)                                    \
                    acc[m][n] = __builtin_amdgcn_mfma_f32_16x16x32_bf16(a[m], b[n], acc[m][n], 0, 0, 0); \
        }                                                                      \
    }

#define GEMM_PIPELINE_LOOP                                                     \
    GSTAGE(0, 0)                                                               \
    const int nk = K / 64;                                                     \
    for (int kt = 0; kt < nk; ++kt) {                                          \
        const int cur = kt & 1;                                                \
        if (kt + 1 < nk) {                                                     \
            GSTAGE(1 - cur, (kt + 1) * 64)                                     \
            asm volatile("s_waitcnt vmcnt(8)" ::: "memory");                   \
        } else {                                                               \
            asm volatile("s_waitcnt vmcnt(0)" ::: "memory");                   \
        }                                                                      \
        __builtin_amdgcn_s_barrier();                                          \
        __builtin_amdgcn_sched_barrier(0);                                     \
        GCOMPUTE(cur)                                                          \
        __builtin_amdgcn_s_barrier();                                          \
        __builtin_amdgcn_sched_barrier(0);                                     \
    }

// ---------------------------------------------------------------------------
// MFMA GEMM (dbuf): C[M,N] = A[M,K] @ Bt[N,K]^T.  [R9 verbatim]
// ---------------------------------------------------------------------------
template <typename CT>
__global__ __launch_bounds__(256) void gemm_mfma_kernel(
    const unsigned short* __restrict__ A,
    const unsigned short* __restrict__ Bt,
    CT* __restrict__ C,
    int N, int K)
{
    __shared__ __align__(16) char Asm[2][128 * 64 * 2];
    __shared__ __align__(16) char Bsm[2][128 * 64 * 2];
    const int tid = threadIdx.x;
    const int l = tid & 63;
    const int w = tid >> 6;
    const int wr = w >> 1, wc = w & 1;
    const int rowBase = blockIdx.y * 128;
    const int colBase = blockIdx.x * 128;
    const int srow = tid >> 3;
    const int scolb = (tid & 7) * 16;

    f32x4 acc[4][4] = {};

    GEMM_PIPELINE_LOOP

    #pragma unroll
    for (int m = 0; m < 4; ++m)
        #pragma unroll
        for (int n = 0; n < 4; ++n)
            #pragma unroll
            for (int r = 0; r < 4; ++r) {
                int row = rowBase + wr * 64 + m * 16 + (l >> 4) * 4 + r;
                int col = colBase + wc * 64 + n * 16 + (l & 15);
                float f = acc[m][n][r];
                if (!isfinite(f)) f = 0.f;  // tripwire
                stc(C + (size_t)row * N + col, f);
            }
}

// ---------------------------------------------------------------------------
// Fused qkv GEMM (dbuf).  [R9 verbatim]
// ---------------------------------------------------------------------------
__global__ __launch_bounds__(256) void gemm_qkv3_kernel(
    const unsigned short* __restrict__ A,
    const unsigned short* __restrict__ Bt,
    unsigned short* __restrict__ qb,
    unsigned short* __restrict__ kb,
    unsigned short* __restrict__ vb)
{
    const int K = E_;
    __shared__ __align__(16) char Asm[2][128 * 64 * 2];
    __shared__ __align__(16) char Bsm[2][128 * 64 * 2];
    const int tid = threadIdx.x;
    const int l = tid & 63;
    const int w = tid >> 6;
    const int wr = w >> 1, wc = w & 1;
    const int rowBase = blockIdx.y * 128;
    const int colBase = blockIdx.x * 128;
    const int srow = tid >> 3;
    const int scolb = (tid & 7) * 16;

    f32x4 acc[4][4] = {};

    GEMM_PIPELINE_LOOP

    const int colW = colBase + wc * 64;
    unsigned short* dst;
    int cofs, stride;
    if (colW < 1024)      { dst = qb; cofs = 0;    stride = E_; }
    else if (colW < 2048) { dst = kb; cofs = 1024; stride = E_; }
    else                  { dst = vb; cofs = 2048; stride = V_; }
    #pragma unroll
    for (int m = 0; m < 4; ++m)
        #pragma unroll
        for (int n = 0; n < 4; ++n)
            #pragma unroll
            for (int r = 0; r < 4; ++r) {
                int row = rowBase + wr * 64 + m * 16 + (l >> 4) * 4 + r;
                int col = colW + n * 16 + (l & 15);
                float f = acc[m][n][r];
                if (!isfinite(f)) f = 0.f;  // tripwire
                dst[(size_t)row * stride + (col - cofs)] = f2bu(f);
            }
}

// ---------------------------------------------------------------------------
// theta_shift in place on bf16 [M_, E_].  [R4 verbatim]
// ---------------------------------------------------------------------------
__global__ __launch_bounds__(256) void theta_shift_kernel(
    unsigned short* __restrict__ qk,
    const float* __restrict__ sinp, const float* __restrict__ cosp, float scale)
{
    const int i = blockIdx.x * 256 + threadIdx.x;
    const int pe = i & (E_ / 2 - 1);
    const int bt = i >> 9;
    const int t = bt & (T_ - 1);
    const int e0 = pe << 1;
    const int d0 = e0 & (KD_ - 1);
    const size_t base = (size_t)bt * E_ + e0;
    const float q0 = u2f(qk[base]);
    const float q1 = u2f(qk[base + 1]);
    const int sb = t * KD_ + d0;
    const float s0 = sinp[sb], s1 = sinp[sb + 1];
    const float c0 = cosp[sb], c1 = cosp[sb + 1];
    qk[base]     = f2bu((q0 * c0 - q1 * s0) * scale);
    qk[base + 1] = f2bu((q1 * c1 + q0 * s1) * scale);
}

// ---------------------------------------------------------------------------
// Retention v4: R11 structure (64-row/4-wave blocks, grid 512, 2 blocks/CU,
// complementarity swizzle, K dbuf + V single, factorized decay) with PV
// COLUMN decomposition: wave w owns O[64 rows][64-col slice w] -> PV LDS
// reads/wave 34 -> 16. Cross-wave P visibility via lgkmcnt(0) before the
// pre-PV barrier; rowsum broadcast via 64-float LDS in the epilogue.
// ---------------------------------------------------------------------------
#define STAGE_K(BUF, T0)                                                       \
    {                                                                          \
        _Pragma("unroll")                                                      \
        for (int i = 0; i < 4; ++i) {                                          \
            int r = i * 16 + (tid >> 4);                                       \
            int cb = ((tid & 15) * 16) ^ ((r & 7) << 4);                       \
            gl_lds16((const char*)(kb + (size_t)(b * T_ + (T0) + r) * E_ + h * KD_) + cb, \
                     Ks[BUF] + i * 4096 + w * 1024);                           \
        }                                                                      \
    }

#define STAGE_V(T0)                                                            \
    {                                                                          \
        _Pragma("unroll")                                                      \
        for (int i = 0; i < 8; ++i) {                                          \
            int r = i * 32 + (tid >> 3);                                       \
            int cb = ((tid & 7) * 16) ^ ((r & 7) << 4);                        \
            gl_lds16((const char*)(vt + (size_t)((b * H_ + h) * HD_ + r) * T_ + (T0)) + cb, \
                     Vs + i * 4096 + w * 1024);                                \
        }                                                                      \
    }

__global__ __launch_bounds__(256) void retention_mfma_kernel(
    const unsigned short* __restrict__ qb,
    const unsigned short* __restrict__ kb,
    const unsigned short* __restrict__ vt,
    unsigned short* __restrict__ ao)
{
    __shared__ __align__(16) char Ks[2][64 * 128 * 2];   // 2 x 16 KB
    __shared__ __align__(16) char Vs[256 * 64 * 2];      //     32 KB
    __shared__ __align__(16) char Ps[64 * 64 * 2];       //      8 KB
    __shared__ float rsum_lds[64];
    const int tid = threadIdx.x;
    const int l = tid & 63;
    const int w = tid >> 6;
    // Complementarity swizzle (bijective on [0,512)): orig and orig+256 land
    // on the same CU under round-robin dispatch; chunk sizes pair to 33.
    const int orig = (int)blockIdx.x;
    const int xcd  = orig & 7;
    const int pos  = orig >> 3;          // 0..63
    const int slot = pos >> 5;           // 0: big half, 1: small half
    const int cu   = pos & 31;
    const int half = cu >> 4;
    const int c15  = cu & 15;
    const int bh   = xcd * 2 + half;     // 2 bh per XCD (L2-resident K/V)
    const int chunk = slot ? c15 : (31 - c15);
    const int b = bh >> 3, h = bh & 7;
    const int s0 = chunk * 64;
    const float ld = logf(1.f - exp2f(-5.f - (float)h));

    // factorized decay: mask(s,t) = D^s * D^-t  (D = e^ld < 1)
    float es[4], etl[4];
    #pragma unroll
    for (int r = 0; r < 4; ++r)
        es[r] = __expf((float)(s0 + w * 16 + (l >> 4) * 4 + r) * ld);
    #pragma unroll
    for (int n = 0; n < 4; ++n)
        etl[n] = __expf(-(float)(n * 16 + (l & 15)) * ld);
    const float Dm64 = __expf(-64.f * ld);
    float etb = 1.f;

    bf16x8 qf[4];
    {
        const char* qp = (const char*)(qb + (size_t)(b * T_ + s0 + w * 16 + (l & 15)) * E_ + h * KD_);
        #pragma unroll
        for (int kk = 0; kk < 4; ++kk)
            qf[kk] = *(const bf16x8*)(qp + kk * 64 + (l >> 4) * 16);
    }

    f32x4 oacc[4][4] = {};   // [row frag m][col frag n], cols = w*64 + n*16
    float rs[4] = {0.f, 0.f, 0.f, 0.f};

    const int nt = chunk + 1;
    STAGE_K(0, 0)

    for (int t = 0; t < nt; ++t) {
        const int cur = t & 1;
        const int t0 = t * 64;
        STAGE_V(t0)                                 // V(t), 8 loads
        if (t + 1 < nt) {
            STAGE_K(1 - cur, t0 + 64)               // K(t+1), 4 loads
            asm volatile("s_waitcnt vmcnt(12)" ::: "memory");  // K(t) landed
        } else {
            asm volatile("s_waitcnt vmcnt(8)" ::: "memory");
        }
        __builtin_amdgcn_s_barrier();
        __builtin_amdgcn_sched_barrier(0);

        // QK^T: wave's 16 q-rows x 64 t-cols from Ks[cur]
        f32x4 sacc[4] = {};
        #pragma unroll
        for (int kk = 0; kk < 4; ++kk) {
            const int cb = kk * 64 + (l >> 4) * 16;
            #pragma unroll
            for (int n = 0; n < 4; ++n) {
                int r = n * 16 + (l & 15);
                bf16x8 kf = *(const bf16x8*)(Ks[cur] + r * 256 + (cb ^ ((r & 7) << 4)));
                sacc[n] = __builtin_amdgcn_mfma_f32_16x16x32_bf16(qf[kk], kf, sacc[n], 0, 0, 0);
            }
        }
        // decay mask (factorized) + rowsum partials + P write (wave band)
        float et[4];
        #pragma unroll
        for (int n = 0; n < 4; ++n) et[n] = etb * etl[n];
        etb *= Dm64;
        float rsp[4] = {0.f, 0.f, 0.f, 0.f};
        #pragma unroll
        for (int n = 0; n < 4; ++n)
            #pragma unroll
            for (int r = 0; r < 4; ++r) {
                int qrow = w * 16 + (l >> 4) * 4 + r;
                int tcol = n * 16 + (l & 15);
                int d = (s0 + qrow) - (t0 + tcol);
                float pm = (d >= 0) ? sacc[n][r] * (es[r] * et[n]) : 0.f;
                rsp[r] += pm;
                *(unsigned short*)(Ps + qrow * 128 + ((tcol * 2) ^ ((qrow & 7) << 4))) = f2bu(pm);
            }
        #pragma unroll
        for (int r = 0; r < 4; ++r) {
            float vv = rsp[r];
            vv += __shfl_xor(vv, 1, 16);
            vv += __shfl_xor(vv, 2, 16);
            vv += __shfl_xor(vv, 4, 16);
            vv += __shfl_xor(vv, 8, 16);
            rs[r] += vv;
        }
        // V(t) staged (all waves) AND all waves' P writes visible before PV.
        if (t + 1 < nt) {
            asm volatile("s_waitcnt vmcnt(4) lgkmcnt(0)" ::: "memory");
        } else {
            asm volatile("s_waitcnt vmcnt(0) lgkmcnt(0)" ::: "memory");
        }
        __builtin_amdgcn_s_barrier();
        __builtin_amdgcn_sched_barrier(0);
        // PV (column split): O[64 rows][w's 64 cols] += P[64][64] @ V[64][:]
        #pragma unroll
        for (int kk = 0; kk < 2; ++kk) {
            const int cb = kk * 64 + (l >> 4) * 16;
            bf16x8 pf[4];
            #pragma unroll
            for (int m = 0; m < 4; ++m) {
                int pr = m * 16 + (l & 15);
                pf[m] = *(const bf16x8*)(Ps + pr * 128 + (cb ^ ((pr & 7) << 4)));
            }
            #pragma unroll
            for (int n = 0; n < 4; ++n) {
                int r = w * 64 + n * 16 + (l & 15);
                bf16x8 vf = *(const bf16x8*)(Vs + r * 128 + (cb ^ ((r & 7) << 4)));
                #pragma unroll
                for (int m = 0; m < 4; ++m)
                    oacc[m][n] = __builtin_amdgcn_mfma_f32_16x16x32_bf16(pf[m], vf, oacc[m][n], 0, 0, 0);
            }
        }
        __builtin_amdgcn_s_barrier();       // all waves done with Vs/Ps before restage
        __builtin_amdgcn_sched_barrier(0);
    }

    // broadcast per-row rowsums (each wave owns rows w*16..w*16+15)
    #pragma unroll
    for (int r = 0; r < 4; ++r)
        if ((l & 15) == 0) rsum_lds[w * 16 + (l >> 4) * 4 + r] = rs[r];
    __syncthreads();

    #pragma unroll
    for (int m = 0; m < 4; ++m)
        #pragma unroll
        for (int r = 0; r < 4; ++r) {
            const int row = m * 16 + (l >> 4) * 4 + r;
            const float inv = 1.f / fmaxf(fabsf(rsum_lds[row]), 1.f);
            #pragma unroll
            for (int n = 0; n < 4; ++n) {
                int col = h * HD_ + w * 64 + n * 16 + (l & 15);
                float f = oacc[m][n][r] * inv;
                if (!isfinite(f)) f = 0.f;
                ao[(size_t)(b * T_ + s0 + row) * V_ + col] = f2bu(f);
            }
        }
}

// ---------------------------------------------------------------------------
// Per-(b,t,h): ao = silu(g) * ao * rsqrt(mean(ao^2) + eps).  [R4 verbatim]
// ---------------------------------------------------------------------------
__global__ __launch_bounds__(256) void rms_silu_kernel(
    unsigned short* __restrict__ ao, const unsigned short* __restrict__ g)
{
    __shared__ float part[4];
    const int tid = threadIdx.x;
    const size_t base = (size_t)blockIdx.x * HD_;
    const float f = u2f(ao[base + tid]);
    float sq = f * f;
    #pragma unroll
    for (int off = 32; off > 0; off >>= 1) sq += __shfl_down(sq, off, 64);
    if ((tid & 63) == 0) part[tid >> 6] = sq;
    __syncthreads();
    const float tot = part[0] + part[1] + part[2] + part[3];
    const float scale = rsqrtf(tot * (1.0f / HD_) + 1e-6f);
    const float gv = u2f(g[base + tid]);
    ao[base + tid] = f2bu(f * scale * gv / (1.f + __expf(-gv)));
}

extern "C" void kernel_launch(void* const* d_in, const int* in_sizes, int n_in,
                              void* d_out, int out_size, void* d_ws, size_t ws_size,
                              hipStream_t stream)
{
    const float* x    = (const float*)d_in[0];
    const float* sinp = (const float*)d_in[1];
    const float* cosp = (const float*)d_in[2];
    // d_in[3] = mask: decay computed analytically in-kernel
    const float* Wq   = (const float*)d_in[4];
    const float* Wk   = (const float*)d_in[5];
    const float* Wv   = (const float*)d_in[6];
    const float* Wg   = (const float*)d_in[7];
    const float* Wo   = (const float*)d_in[8];
    float* out = (float*)d_out;

    // d_out doubles as scratch (R4-proven): xb [0,8.39M) | qb [8.39M,16.78M).
    unsigned short* xb = (unsigned short*)d_out;
    unsigned short* qb = xb + (size_t)M_ * E_;

    // ws layout (R6-identical, 41.94 MB peak):
    char* ws = (char*)d_ws;
    unsigned short* kb  = (unsigned short*)ws;
    unsigned short* wt  = (unsigned short*)(ws + 8388608);
    unsigned short* vt  = (unsigned short*)(ws + 8388608);
    unsigned short* gb  = (unsigned short*)(ws + 8388608);
    unsigned short* vb  = (unsigned short*)(ws + 25165824);
    unsigned short* aob = (unsigned short*)(ws + 25165824);
    unsigned short* wgt = (unsigned short*)ws;
    unsigned short* wot = (unsigned short*)ws;

    dim3 blk(256);
    conv_x_kernel<<<M_ * E_ / 8 / 256, blk, 0, stream>>>(x, xb);

    transW_kernel<<<dim3(16, 16), blk, 0, stream>>>(Wq, wt, E_, E_);
    transW_kernel<<<dim3(16, 16), blk, 0, stream>>>(Wk, wt + (size_t)1024 * E_, E_, E_);
    transW_kernel<<<dim3(32, 16), blk, 0, stream>>>(Wv, wt + (size_t)2048 * E_, E_, V_);

    gemm_qkv3_kernel<<<dim3(32, 32), blk, 0, stream>>>(xb, wt, qb, kb, vb);

    theta_shift_kernel<<<M_ * E_ / 2 / 256, blk, 0, stream>>>(qb, sinp, cosp, 1.0f);
    theta_shift_kernel<<<M_ * E_ / 2 / 256, blk, 0, stream>>>(kb, sinp, cosp, 0.088388347648318447f);

    transV_kernel<<<dim3(32, 32, B_), blk, 0, stream>>>(vb, vt);  // kills wt

    retention_mfma_kernel<<<dim3(512), blk, 0, stream>>>(qb, kb, vt, aob);

    transW_kernel<<<dim3(32, 16), blk, 0, stream>>>(Wg, wgt, E_, V_);
    gemm_mfma_kernel<unsigned short><<<dim3(16, 32), blk, 0, stream>>>(xb, wgt, gb, V_, E_);

    rms_silu_kernel<<<B_ * T_ * H_, blk, 0, stream>>>(aob, gb);

    transW_kernel<<<dim3(16, 32), blk, 0, stream>>>(Wo, wot, V_, E_);
    gemm_mfma_kernel<float><<<dim3(8, 32), blk, 0, stream>>>(aob, wot, out, E_, V_);
}

// Round 13
// 219.795 us; speedup vs baseline: 1.2314x; 1.0603x over previous
//
#include <hip/hip_runtime.h>
#include <hip/hip_bf16.h>

// MultiScaleRetention forward, MI355X gfx950 — Round 13.
// R12 profile revealed ws_size = 512 MiB (the 0xAA poison fill writes exactly
// 536,870,912 B). This round: consolidation on proven bodies. One GEMM for
// q,k,v,g (packed Wt [6144][1024], 4-way epilogue routing, grid 48x32);
// transW x4 -> 1 dispatch (grid.z); theta x2 -> 1 (grid.y); fully DISJOINT ws
// layout (~92 MB) — all overlay hazards gone. 9 dispatches (was 14).
// Retention / rms / wo GEMM / transV byte-identical to R12 (controls).

#define B_ 2
#define T_ 2048
#define E_ 1024
#define V_ 2048
#define H_ 8
#define KD_ 128
#define HD_ 256
#define M_ 4096  // B_*T_

typedef __attribute__((ext_vector_type(8))) short bf16x8;
typedef __attribute__((ext_vector_type(4))) float f32x4;

__device__ __forceinline__ float u2f(unsigned short u) {
    return __uint_as_float(((unsigned)u) << 16);
}
__device__ __forceinline__ unsigned short f2bu(float f) {
    unsigned x = __float_as_uint(f);
    return (unsigned short)((x + 0x7fffu + ((x >> 16) & 1u)) >> 16);  // RNE
}

typedef const __attribute__((address_space(1))) void gas_t;
typedef __attribute__((address_space(3))) void las_t;
__device__ __forceinline__ void gl_lds16(const void* g, void* l) {
    __builtin_amdgcn_global_load_lds((gas_t*)g, (las_t*)l, 16, 0, 0);
}

__device__ __forceinline__ void stc(float* p, float f) { *p = f; }
__device__ __forceinline__ void stc(unsigned short* p, float f) { *p = f2bu(f); }

// ---------------------------------------------------------------------------
// x fp32 -> bf16 flat convert (8 elems/thread).  [R4 verbatim]
// ---------------------------------------------------------------------------
__global__ __launch_bounds__(256) void conv_x_kernel(
    const float* __restrict__ x, unsigned short* __restrict__ xb)
{
    const size_t i = ((size_t)blockIdx.x * 256 + threadIdx.x) * 8;
    float4 a = *(const float4*)(x + i);
    float4 c = *(const float4*)(x + i + 4);
    *(ushort4*)(xb + i)     = make_ushort4(f2bu(a.x), f2bu(a.y), f2bu(a.z), f2bu(a.w));
    *(ushort4*)(xb + i + 4) = make_ushort4(f2bu(c.x), f2bu(c.y), f2bu(c.z), f2bu(c.w));
}

// ---------------------------------------------------------------------------
// Packed weight transpose: z selects {Wq,Wk,Wv,Wg} -> Wt rows {0,1K,2K,4K}.
// W [1024][N] fp32 -> Wt rows [rofs+n][1024] bf16. grid (32,16,4).
// ---------------------------------------------------------------------------
__global__ __launch_bounds__(256) void transW4_kernel(
    const float* __restrict__ Wq, const float* __restrict__ Wk,
    const float* __restrict__ Wv, const float* __restrict__ Wg,
    unsigned short* __restrict__ Wt)
{
    const int z = blockIdx.z;
    const float* W; int N; int rofs;
    if (z == 0)      { W = Wq; N = 1024; rofs = 0; }
    else if (z == 1) { W = Wk; N = 1024; rofs = 1024; }
    else if (z == 2) { W = Wv; N = 2048; rofs = 2048; }
    else             { W = Wg; N = 2048; rofs = 4096; }
    const int n0 = blockIdx.x * 64;
    if (n0 >= N) return;
    const int k0 = blockIdx.y * 64;

    __shared__ float tl[64][65];
    const int tid = threadIdx.x;
    #pragma unroll
    for (int i = 0; i < 4; ++i) {
        int kr = i * 16 + (tid >> 4);
        int nc = (tid & 15) * 4;
        float4 v = *(const float4*)(W + (size_t)(k0 + kr) * N + n0 + nc);
        tl[kr][nc] = v.x; tl[kr][nc + 1] = v.y; tl[kr][nc + 2] = v.z; tl[kr][nc + 3] = v.w;
    }
    __syncthreads();
    #pragma unroll
    for (int i = 0; i < 4; ++i) {
        int nr = i * 16 + (tid >> 4);
        int kc = (tid & 15) * 4;
        ushort4 u = make_ushort4(f2bu(tl[kc + 0][nr]), f2bu(tl[kc + 1][nr]),
                                 f2bu(tl[kc + 2][nr]), f2bu(tl[kc + 3][nr]));
        *(ushort4*)(Wt + (size_t)(rofs + n0 + nr) * E_ + k0 + kc) = u;
    }
}

// ---------------------------------------------------------------------------
// Single-W transpose for Wo.  [R4 verbatim]
// ---------------------------------------------------------------------------
__global__ __launch_bounds__(256) void transW_kernel(
    const float* __restrict__ W, unsigned short* __restrict__ Wt, int K, int N)
{
    __shared__ float tl[64][65];
    const int tid = threadIdx.x;
    const int n0 = blockIdx.x * 64, k0 = blockIdx.y * 64;
    #pragma unroll
    for (int i = 0; i < 4; ++i) {
        int kr = i * 16 + (tid >> 4);
        int nc = (tid & 15) * 4;
        float4 v = *(const float4*)(W + (size_t)(k0 + kr) * N + n0 + nc);
        tl[kr][nc] = v.x; tl[kr][nc + 1] = v.y; tl[kr][nc + 2] = v.z; tl[kr][nc + 3] = v.w;
    }
    __syncthreads();
    #pragma unroll
    for (int i = 0; i < 4; ++i) {
        int nr = i * 16 + (tid >> 4);
        int kc = (tid & 15) * 4;
        ushort4 u = make_ushort4(f2bu(tl[kc + 0][nr]), f2bu(tl[kc + 1][nr]),
                                 f2bu(tl[kc + 2][nr]), f2bu(tl[kc + 3][nr]));
        *(ushort4*)(Wt + (size_t)(n0 + nr) * K + k0 + kc) = u;
    }
}

// ---------------------------------------------------------------------------
// V [b*T + t][2048] bf16 -> Vt [b*2048 + c][T] bf16.  [R4 verbatim]
// ---------------------------------------------------------------------------
__global__ __launch_bounds__(256) void transV_kernel(
    const unsigned short* __restrict__ vb, unsigned short* __restrict__ vt)
{
    __shared__ unsigned short tl[64][68];
    const int tid = threadIdx.x;
    const int t0 = blockIdx.x * 64, c0 = blockIdx.y * 64, b = blockIdx.z;
    #pragma unroll
    for (int i = 0; i < 4; ++i) {
        int tr = i * 16 + (tid >> 4);
        int cc = (tid & 15) * 4;
        ushort4 v = *(const ushort4*)(vb + (size_t)(b * T_ + t0 + tr) * V_ + c0 + cc);
        tl[tr][cc] = v.x; tl[tr][cc + 1] = v.y; tl[tr][cc + 2] = v.z; tl[tr][cc + 3] = v.w;
    }
    __syncthreads();
    #pragma unroll
    for (int i = 0; i < 4; ++i) {
        int cr = i * 16 + (tid >> 4);
        int tc = (tid & 15) * 4;
        ushort4 u = make_ushort4(tl[tc + 0][cr], tl[tc + 1][cr], tl[tc + 2][cr], tl[tc + 3][cr]);
        *(ushort4*)(vt + (size_t)(b * V_ + c0 + cr) * T_ + t0 + tc) = u;
    }
}

// ---------------------------------------------------------------------------
// GEMM stage + compute building blocks (dbuf pipeline).  [R9 verbatim]
// ---------------------------------------------------------------------------
#define GSTAGE(BUF, K0)                                                        \
    {                                                                          \
        _Pragma("unroll")                                                      \
        for (int i = 0; i < 4; ++i) {                                          \
            int r = i * 32 + srow;                                             \
            int cb = scolb ^ ((r & 7) << 4);                                   \
            gl_lds16((const char*)(A  + (size_t)(rowBase + r) * K + (K0)) + cb,\
                     Asm[BUF] + i * 4096 + w * 1024);                          \
            gl_lds16((const char*)(Bt + (size_t)(colBase + r) * K + (K0)) + cb,\
                     Bsm[BUF] + i * 4096 + w * 1024);                          \
        }                                                                      \
    }

#define GCOMPUTE(BUF)                                                          \
    {                                                                          \
        _Pragma("unroll")                                                      \
        for (int kk = 0; kk < 2; ++kk) {                                       \
            const int cb = kk * 64 + (l >> 4) * 16;                            \
            bf16x8 a[4], b[4];                                                 \
            _Pragma("unroll")                                                  \
            for (int m = 0; m < 4; ++m) {                                      \
                int r = wr * 64 + m * 16 + (l & 15);                           \
                a[m] = *(const bf16x8*)(Asm[BUF] + r * 128 + (cb ^ ((r & 7) << 4))); \
            }                                                                  \
            _Pragma("unroll")                                                  \
            for (int n = 0; n < 4; ++n) {                                      \
                int r = wc * 64 + n * 16 + (l & 15);                           \
                b[n] = *(const bf16x8*)(Bsm[BUF] + r * 128 + (cb ^ ((r & 7) << 4))); \
            }                                                                  \
            _Pragma("unroll")                                                  \
            for (int m = 0; m < 4; ++m)                                        \
                _Pragma("unroll")                                              \
                for (int n = 0; n < 4; ++n)                                    \
                    acc[m][n] = __builtin_amdgcn_mfma_f32_16x16x32_bf16(a[m], b[n], acc[m][n], 0, 0, 0); \
        }                                                                      \
    }

#define GEMM_PIPELINE_LOOP                                                     \
    GSTAGE(0, 0)                                                               \
    const int nk = K / 64;                                                     \
    for (int kt = 0; kt < nk; ++kt) {                                          \
        const int cur = kt & 1;                                                \
        if (kt + 1 < nk) {                                                     \
            GSTAGE(1 - cur, (kt + 1) * 64)                                     \
            asm volatile("s_waitcnt vmcnt(8)" ::: "memory");                   \
        } else {                                                               \
            asm volatile("s_waitcnt vmcnt(0)" ::: "memory");                   \
        }                                                                      \
        __builtin_amdgcn_s_barrier();                                          \
        __builtin_amdgcn_sched_barrier(0);                                     \
        GCOMPUTE(cur)                                                          \
        __builtin_amdgcn_s_barrier();                                          \
        __builtin_amdgcn_sched_barrier(0);                                     \
    }

// ---------------------------------------------------------------------------
// MFMA GEMM (dbuf): C[M,N] = A[M,K] @ Bt[N,K]^T.  [R9 verbatim] — used for Wo.
// ---------------------------------------------------------------------------
template <typename CT>
__global__ __launch_bounds__(256) void gemm_mfma_kernel(
    const unsigned short* __restrict__ A,
    const unsigned short* __restrict__ Bt,
    CT* __restrict__ C,
    int N, int K)
{
    __shared__ __align__(16) char Asm[2][128 * 64 * 2];
    __shared__ __align__(16) char Bsm[2][128 * 64 * 2];
    const int tid = threadIdx.x;
    const int l = tid & 63;
    const int w = tid >> 6;
    const int wr = w >> 1, wc = w & 1;
    const int rowBase = blockIdx.y * 128;
    const int colBase = blockIdx.x * 128;
    const int srow = tid >> 3;
    const int scolb = (tid & 7) * 16;

    f32x4 acc[4][4] = {};

    GEMM_PIPELINE_LOOP

    #pragma unroll
    for (int m = 0; m < 4; ++m)
        #pragma unroll
        for (int n = 0; n < 4; ++n)
            #pragma unroll
            for (int r = 0; r < 4; ++r) {
                int row = rowBase + wr * 64 + m * 16 + (l >> 4) * 4 + r;
                int col = colBase + wc * 64 + n * 16 + (l & 15);
                float f = acc[m][n][r];
                if (!isfinite(f)) f = 0.f;  // tripwire
                stc(C + (size_t)row * N + col, f);
            }
}

// ---------------------------------------------------------------------------
// Fused q,k,v,g GEMM (dbuf): Bt = packed [Wq;Wk;Wv;Wg]^T [6144][1024].
// Epilogue routes cols [0,1K)->q, [1K,2K)->k, [2K,4K)->v, [4K,6K)->g.
// grid (48, 32). Body = R9/R6-proven.
// ---------------------------------------------------------------------------
__global__ __launch_bounds__(256) void gemm_qkvg_kernel(
    const unsigned short* __restrict__ A,
    const unsigned short* __restrict__ Bt,
    unsigned short* __restrict__ qb,
    unsigned short* __restrict__ kb,
    unsigned short* __restrict__ vb,
    unsigned short* __restrict__ gb)
{
    const int K = E_;
    __shared__ __align__(16) char Asm[2][128 * 64 * 2];
    __shared__ __align__(16) char Bsm[2][128 * 64 * 2];
    const int tid = threadIdx.x;
    const int l = tid & 63;
    const int w = tid >> 6;
    const int wr = w >> 1, wc = w & 1;
    const int rowBase = blockIdx.y * 128;
    const int colBase = blockIdx.x * 128;
    const int srow = tid >> 3;
    const int scolb = (tid & 7) * 16;

    f32x4 acc[4][4] = {};

    GEMM_PIPELINE_LOOP

    const int colW = colBase + wc * 64;   // wave-uniform
    unsigned short* dst;
    int cofs, stride;
    if (colW < 1024)      { dst = qb; cofs = 0;    stride = E_; }
    else if (colW < 2048) { dst = kb; cofs = 1024; stride = E_; }
    else if (colW < 4096) { dst = vb; cofs = 2048; stride = V_; }
    else                  { dst = gb; cofs = 4096; stride = V_; }
    #pragma unroll
    for (int m = 0; m < 4; ++m)
        #pragma unroll
        for (int n = 0; n < 4; ++n)
            #pragma unroll
            for (int r = 0; r < 4; ++r) {
                int row = rowBase + wr * 64 + m * 16 + (l >> 4) * 4 + r;
                int col = colW + n * 16 + (l & 15);
                float f = acc[m][n][r];
                if (!isfinite(f)) f = 0.f;  // tripwire
                dst[(size_t)row * stride + (col - cofs)] = f2bu(f);
            }
}

// ---------------------------------------------------------------------------
// theta_shift for q AND k in one dispatch: grid (8192, 2); y=0 -> q (scale 1),
// y=1 -> k (scale KD^-0.5). Body = R4 verbatim.
// ---------------------------------------------------------------------------
__global__ __launch_bounds__(256) void theta2_kernel(
    unsigned short* __restrict__ qb,
    unsigned short* __restrict__ kb,
    const float* __restrict__ sinp, const float* __restrict__ cosp)
{
    unsigned short* qk = blockIdx.y ? kb : qb;
    const float scale = blockIdx.y ? 0.088388347648318447f : 1.0f;
    const int i = blockIdx.x * 256 + threadIdx.x;
    const int pe = i & (E_ / 2 - 1);
    const int bt = i >> 9;
    const int t = bt & (T_ - 1);
    const int e0 = pe << 1;
    const int d0 = e0 & (KD_ - 1);
    const size_t base = (size_t)bt * E_ + e0;
    const float q0 = u2f(qk[base]);
    const float q1 = u2f(qk[base + 1]);
    const int sb = t * KD_ + d0;
    const float s0 = sinp[sb], s1 = sinp[sb + 1];
    const float c0 = cosp[sb], c1 = cosp[sb + 1];
    qk[base]     = f2bu((q0 * c0 - q1 * s0) * scale);
    qk[base + 1] = f2bu((q1 * c1 + q0 * s1) * scale);
}

// ---------------------------------------------------------------------------
// Retention v4.  [R12 verbatim — control]
// ---------------------------------------------------------------------------
#define STAGE_K(BUF, T0)                                                       \
    {                                                                          \
        _Pragma("unroll")                                                      \
        for (int i = 0; i < 4; ++i) {                                          \
            int r = i * 16 + (tid >> 4);                                       \
            int cb = ((tid & 15) * 16) ^ ((r & 7) << 4);                       \
            gl_lds16((const char*)(kb + (size_t)(b * T_ + (T0) + r) * E_ + h * KD_) + cb, \
                     Ks[BUF] + i * 4096 + w * 1024);                           \
        }                                                                      \
    }

#define STAGE_V(T0)                                                            \
    {                                                                          \
        _Pragma("unroll")                                                      \
        for (int i = 0; i < 8; ++i) {                                          \
            int r = i * 32 + (tid >> 3);                                       \
            int cb = ((tid & 7) * 16) ^ ((r & 7) << 4);                        \
            gl_lds16((const char*)(vt + (size_t)((b * H_ + h) * HD_ + r) * T_ + (T0)) + cb, \
                     Vs + i * 4096 + w * 1024);                                \
        }                                                                      \
    }

__global__ __launch_bounds__(256) void retention_mfma_kernel(
    const unsigned short* __restrict__ qb,
    const unsigned short* __restrict__ kb,
    const unsigned short* __restrict__ vt,
    unsigned short* __restrict__ ao)
{
    __shared__ __align__(16) char Ks[2][64 * 128 * 2];   // 2 x 16 KB
    __shared__ __align__(16) char Vs[256 * 64 * 2];      //     32 KB
    __shared__ __align__(16) char Ps[64 * 64 * 2];       //      8 KB
    __shared__ float rsum_lds[64];
    const int tid = threadIdx.x;
    const int l = tid & 63;
    const int w = tid >> 6;
    const int orig = (int)blockIdx.x;
    const int xcd  = orig & 7;
    const int pos  = orig >> 3;          // 0..63
    const int slot = pos >> 5;           // 0: big half, 1: small half
    const int cu   = pos & 31;
    const int half = cu >> 4;
    const int c15  = cu & 15;
    const int bh   = xcd * 2 + half;     // 2 bh per XCD (L2-resident K/V)
    const int chunk = slot ? c15 : (31 - c15);
    const int b = bh >> 3, h = bh & 7;
    const int s0 = chunk * 64;
    const float ld = logf(1.f - exp2f(-5.f - (float)h));

    float es[4], etl[4];
    #pragma unroll
    for (int r = 0; r < 4; ++r)
        es[r] = __expf((float)(s0 + w * 16 + (l >> 4) * 4 + r) * ld);
    #pragma unroll
    for (int n = 0; n < 4; ++n)
        etl[n] = __expf(-(float)(n * 16 + (l & 15)) * ld);
    const float Dm64 = __expf(-64.f * ld);
    float etb = 1.f;

    bf16x8 qf[4];
    {
        const char* qp = (const char*)(qb + (size_t)(b * T_ + s0 + w * 16 + (l & 15)) * E_ + h * KD_);
        #pragma unroll
        for (int kk = 0; kk < 4; ++kk)
            qf[kk] = *(const bf16x8*)(qp + kk * 64 + (l >> 4) * 16);
    }

    f32x4 oacc[4][4] = {};
    float rs[4] = {0.f, 0.f, 0.f, 0.f};

    const int nt = chunk + 1;
    STAGE_K(0, 0)

    for (int t = 0; t < nt; ++t) {
        const int cur = t & 1;
        const int t0 = t * 64;
        STAGE_V(t0)
        if (t + 1 < nt) {
            STAGE_K(1 - cur, t0 + 64)
            asm volatile("s_waitcnt vmcnt(12)" ::: "memory");
        } else {
            asm volatile("s_waitcnt vmcnt(8)" ::: "memory");
        }
        __builtin_amdgcn_s_barrier();
        __builtin_amdgcn_sched_barrier(0);

        f32x4 sacc[4] = {};
        #pragma unroll
        for (int kk = 0; kk < 4; ++kk) {
            const int cb = kk * 64 + (l >> 4) * 16;
            #pragma unroll
            for (int n = 0; n < 4; ++n) {
                int r = n * 16 + (l & 15);
                bf16x8 kf = *(const bf16x8*)(Ks[cur] + r * 256 + (cb ^ ((r & 7) << 4)));
                sacc[n] = __builtin_amdgcn_mfma_f32_16x16x32_bf16(qf[kk], kf, sacc[n], 0, 0, 0);
            }
        }
        float et[4];
        #pragma unroll
        for (int n = 0; n < 4; ++n) et[n] = etb * etl[n];
        etb *= Dm64;
        float rsp[4] = {0.f, 0.f, 0.f, 0.f};
        #pragma unroll
        for (int n = 0; n < 4; ++n)
            #pragma unroll
            for (int r = 0; r < 4; ++r) {
                int qrow = w * 16 + (l >> 4) * 4 + r;
                int tcol = n * 16 + (l & 15);
                int d = (s0 + qrow) - (t0 + tcol);
                float pm = (d >= 0) ? sacc[n][r] * (es[r] * et[n]) : 0.f;
                rsp[r] += pm;
                *(unsigned short*)(Ps + qrow * 128 + ((tcol * 2) ^ ((qrow & 7) << 4))) = f2bu(pm);
            }
        #pragma unroll
        for (int r = 0; r < 4; ++r) {
            float vv = rsp[r];
            vv += __shfl_xor(vv, 1, 16);
            vv += __shfl_xor(vv, 2, 16);
            vv += __shfl_xor(vv, 4, 16);
            vv += __shfl_xor(vv, 8, 16);
            rs[r] += vv;
        }
        if (t + 1 < nt) {
            asm volatile("s_waitcnt vmcnt(4) lgkmcnt(0)" ::: "memory");
        } else {
            asm volatile("s_waitcnt vmcnt(0) lgkmcnt(0)" ::: "memory");
        }
        __builtin_amdgcn_s_barrier();
        __builtin_amdgcn_sched_barrier(0);
        #pragma unroll
        for (int kk = 0; kk < 2; ++kk) {
            const int cb = kk * 64 + (l >> 4) * 16;
            bf16x8 pf[4];
            #pragma unroll
            for (int m = 0; m < 4; ++m) {
                int pr = m * 16 + (l & 15);
                pf[m] = *(const bf16x8*)(Ps + pr * 128 + (cb ^ ((pr & 7) << 4)));
            }
            #pragma unroll
            for (int n = 0; n < 4; ++n) {
                int r = w * 64 + n * 16 + (l & 15);
                bf16x8 vf = *(const bf16x8*)(Vs + r * 128 + (cb ^ ((r & 7) << 4)));
                #pragma unroll
                for (int m = 0; m < 4; ++m)
                    oacc[m][n] = __builtin_amdgcn_mfma_f32_16x16x32_bf16(pf[m], vf, oacc[m][n], 0, 0, 0);
            }
        }
        __builtin_amdgcn_s_barrier();
        __builtin_amdgcn_sched_barrier(0);
    }

    #pragma unroll
    for (int r = 0; r < 4; ++r)
        if ((l & 15) == 0) rsum_lds[w * 16 + (l >> 4) * 4 + r] = rs[r];
    __syncthreads();

    #pragma unroll
    for (int m = 0; m < 4; ++m)
        #pragma unroll
        for (int r = 0; r < 4; ++r) {
            const int row = m * 16 + (l >> 4) * 4 + r;
            const float inv = 1.f / fmaxf(fabsf(rsum_lds[row]), 1.f);
            #pragma unroll
            for (int n = 0; n < 4; ++n) {
                int col = h * HD_ + w * 64 + n * 16 + (l & 15);
                float f = oacc[m][n][r] * inv;
                if (!isfinite(f)) f = 0.f;
                ao[(size_t)(b * T_ + s0 + row) * V_ + col] = f2bu(f);
            }
        }
}

// ---------------------------------------------------------------------------
// Per-(b,t,h): ao = silu(g) * ao * rsqrt(mean(ao^2) + eps).  [R4 verbatim]
// ---------------------------------------------------------------------------
__global__ __launch_bounds__(256) void rms_silu_kernel(
    unsigned short* __restrict__ ao, const unsigned short* __restrict__ g)
{
    __shared__ float part[4];
    const int tid = threadIdx.x;
    const size_t base = (size_t)blockIdx.x * HD_;
    const float f = u2f(ao[base + tid]);
    float sq = f * f;
    #pragma unroll
    for (int off = 32; off > 0; off >>= 1) sq += __shfl_down(sq, off, 64);
    if ((tid & 63) == 0) part[tid >> 6] = sq;
    __syncthreads();
    const float tot = part[0] + part[1] + part[2] + part[3];
    const float scale = rsqrtf(tot * (1.0f / HD_) + 1e-6f);
    const float gv = u2f(g[base + tid]);
    ao[base + tid] = f2bu(f * scale * gv / (1.f + __expf(-gv)));
}

extern "C" void kernel_launch(void* const* d_in, const int* in_sizes, int n_in,
                              void* d_out, int out_size, void* d_ws, size_t ws_size,
                              hipStream_t stream)
{
    const float* x    = (const float*)d_in[0];
    const float* sinp = (const float*)d_in[1];
    const float* cosp = (const float*)d_in[2];
    // d_in[3] = mask: decay computed analytically in-kernel
    const float* Wq   = (const float*)d_in[4];
    const float* Wk   = (const float*)d_in[5];
    const float* Wv   = (const float*)d_in[6];
    const float* Wg   = (const float*)d_in[7];
    const float* Wo   = (const float*)d_in[8];
    float* out = (float*)d_out;

    // d_out doubles as scratch (R4-proven): xb [0,8.39M) | qb [8.39M,16.78M).
    unsigned short* xb = (unsigned short*)d_out;
    unsigned short* qb = xb + (size_t)M_ * E_;

    // ws: DISJOINT layout (~92 MB of 512 MiB — ws_size proven by 0xAA fill).
    char* ws = (char*)d_ws;
    unsigned short* kb  = (unsigned short*)(ws + 0);         //  8.39 MB
    unsigned short* vb  = (unsigned short*)(ws + 8388608);   // 16.78 MB
    unsigned short* gb  = (unsigned short*)(ws + 25165824);  // 16.78 MB
    unsigned short* wt  = (unsigned short*)(ws + 41943040);  // 12.58 MB [6144][1024]
    unsigned short* vt  = (unsigned short*)(ws + 54525952);  // 16.78 MB
    unsigned short* aob = (unsigned short*)(ws + 71303168);  // 16.78 MB
    unsigned short* wot = (unsigned short*)(ws + 88080384);  //  4.19 MB

    dim3 blk(256);
    conv_x_kernel<<<M_ * E_ / 8 / 256, blk, 0, stream>>>(x, xb);

    transW4_kernel<<<dim3(32, 16, 4), blk, 0, stream>>>(Wq, Wk, Wv, Wg, wt);

    gemm_qkvg_kernel<<<dim3(48, 32), blk, 0, stream>>>(xb, wt, qb, kb, vb, gb);

    theta2_kernel<<<dim3(M_ * E_ / 2 / 256, 2), blk, 0, stream>>>(qb, kb, sinp, cosp);

    transV_kernel<<<dim3(32, 32, B_), blk, 0, stream>>>(vb, vt);

    retention_mfma_kernel<<<dim3(512), blk, 0, stream>>>(qb, kb, vt, aob);

    rms_silu_kernel<<<B_ * T_ * H_, blk, 0, stream>>>(aob, gb);

    transW_kernel<<<dim3(16, 32), blk, 0, stream>>>(Wo, wot, V_, E_);
    gemm_mfma_kernel<float><<<dim3(8, 32), blk, 0, stream>>>(aob, wot, out, E_, V_);
}

// Round 14
// 203.310 us; speedup vs baseline: 1.3312x; 1.0811x over previous
//
#include <hip/hip_runtime.h>
#include <hip/hip_bf16.h>

// MultiScaleRetention forward, MI355X gfx950 — Round 14.
// R13: 219.8 µs. This round: (1) rms_silu FUSED into retention epilogue
// (column-split layout gives each block all 256 cols of its 64 rows; per-row
// sumsq via the proven 16-lane shfl reduce + rsq_lds[4][64] cross-wave sum;
// g loaded in epilogue; o stays fp32 until the single bf16 store). (2) Wo GEMM
// retiled to 64x128 (grid 8x64=512, 2 blocks/CU, LDS 48KB, vmcnt(6) ladder).
// qkvg GEMM / theta2 / transV / transW4 / conv_x byte-identical to R13.

#define B_ 2
#define T_ 2048
#define E_ 1024
#define V_ 2048
#define H_ 8
#define KD_ 128
#define HD_ 256
#define M_ 4096  // B_*T_

typedef __attribute__((ext_vector_type(8))) short bf16x8;
typedef __attribute__((ext_vector_type(4))) float f32x4;

__device__ __forceinline__ float u2f(unsigned short u) {
    return __uint_as_float(((unsigned)u) << 16);
}
__device__ __forceinline__ unsigned short f2bu(float f) {
    unsigned x = __float_as_uint(f);
    return (unsigned short)((x + 0x7fffu + ((x >> 16) & 1u)) >> 16);  // RNE
}

typedef const __attribute__((address_space(1))) void gas_t;
typedef __attribute__((address_space(3))) void las_t;
__device__ __forceinline__ void gl_lds16(const void* g, void* l) {
    __builtin_amdgcn_global_load_lds((gas_t*)g, (las_t*)l, 16, 0, 0);
}

// ---------------------------------------------------------------------------
// x fp32 -> bf16 flat convert (8 elems/thread).  [R4 verbatim]
// ---------------------------------------------------------------------------
__global__ __launch_bounds__(256) void conv_x_kernel(
    const float* __restrict__ x, unsigned short* __restrict__ xb)
{
    const size_t i = ((size_t)blockIdx.x * 256 + threadIdx.x) * 8;
    float4 a = *(const float4*)(x + i);
    float4 c = *(const float4*)(x + i + 4);
    *(ushort4*)(xb + i)     = make_ushort4(f2bu(a.x), f2bu(a.y), f2bu(a.z), f2bu(a.w));
    *(ushort4*)(xb + i + 4) = make_ushort4(f2bu(c.x), f2bu(c.y), f2bu(c.z), f2bu(c.w));
}

// ---------------------------------------------------------------------------
// Packed weight transpose: z selects {Wq,Wk,Wv,Wg} -> Wt rows {0,1K,2K,4K}.
// [R13 verbatim]
// ---------------------------------------------------------------------------
__global__ __launch_bounds__(256) void transW4_kernel(
    const float* __restrict__ Wq, const float* __restrict__ Wk,
    const float* __restrict__ Wv, const float* __restrict__ Wg,
    unsigned short* __restrict__ Wt)
{
    const int z = blockIdx.z;
    const float* W; int N; int rofs;
    if (z == 0)      { W = Wq; N = 1024; rofs = 0; }
    else if (z == 1) { W = Wk; N = 1024; rofs = 1024; }
    else if (z == 2) { W = Wv; N = 2048; rofs = 2048; }
    else             { W = Wg; N = 2048; rofs = 4096; }
    const int n0 = blockIdx.x * 64;
    if (n0 >= N) return;
    const int k0 = blockIdx.y * 64;

    __shared__ float tl[64][65];
    const int tid = threadIdx.x;
    #pragma unroll
    for (int i = 0; i < 4; ++i) {
        int kr = i * 16 + (tid >> 4);
        int nc = (tid & 15) * 4;
        float4 v = *(const float4*)(W + (size_t)(k0 + kr) * N + n0 + nc);
        tl[kr][nc] = v.x; tl[kr][nc + 1] = v.y; tl[kr][nc + 2] = v.z; tl[kr][nc + 3] = v.w;
    }
    __syncthreads();
    #pragma unroll
    for (int i = 0; i < 4; ++i) {
        int nr = i * 16 + (tid >> 4);
        int kc = (tid & 15) * 4;
        ushort4 u = make_ushort4(f2bu(tl[kc + 0][nr]), f2bu(tl[kc + 1][nr]),
                                 f2bu(tl[kc + 2][nr]), f2bu(tl[kc + 3][nr]));
        *(ushort4*)(Wt + (size_t)(rofs + n0 + nr) * E_ + k0 + kc) = u;
    }
}

// ---------------------------------------------------------------------------
// Single-W transpose for Wo.  [R4 verbatim]
// ---------------------------------------------------------------------------
__global__ __launch_bounds__(256) void transW_kernel(
    const float* __restrict__ W, unsigned short* __restrict__ Wt, int K, int N)
{
    __shared__ float tl[64][65];
    const int tid = threadIdx.x;
    const int n0 = blockIdx.x * 64, k0 = blockIdx.y * 64;
    #pragma unroll
    for (int i = 0; i < 4; ++i) {
        int kr = i * 16 + (tid >> 4);
        int nc = (tid & 15) * 4;
        float4 v = *(const float4*)(W + (size_t)(k0 + kr) * N + n0 + nc);
        tl[kr][nc] = v.x; tl[kr][nc + 1] = v.y; tl[kr][nc + 2] = v.z; tl[kr][nc + 3] = v.w;
    }
    __syncthreads();
    #pragma unroll
    for (int i = 0; i < 4; ++i) {
        int nr = i * 16 + (tid >> 4);
        int kc = (tid & 15) * 4;
        ushort4 u = make_ushort4(f2bu(tl[kc + 0][nr]), f2bu(tl[kc + 1][nr]),
                                 f2bu(tl[kc + 2][nr]), f2bu(tl[kc + 3][nr]));
        *(ushort4*)(Wt + (size_t)(n0 + nr) * K + k0 + kc) = u;
    }
}

// ---------------------------------------------------------------------------
// V [b*T + t][2048] bf16 -> Vt [b*2048 + c][T] bf16.  [R4 verbatim]
// ---------------------------------------------------------------------------
__global__ __launch_bounds__(256) void transV_kernel(
    const unsigned short* __restrict__ vb, unsigned short* __restrict__ vt)
{
    __shared__ unsigned short tl[64][68];
    const int tid = threadIdx.x;
    const int t0 = blockIdx.x * 64, c0 = blockIdx.y * 64, b = blockIdx.z;
    #pragma unroll
    for (int i = 0; i < 4; ++i) {
        int tr = i * 16 + (tid >> 4);
        int cc = (tid & 15) * 4;
        ushort4 v = *(const ushort4*)(vb + (size_t)(b * T_ + t0 + tr) * V_ + c0 + cc);
        tl[tr][cc] = v.x; tl[tr][cc + 1] = v.y; tl[tr][cc + 2] = v.z; tl[tr][cc + 3] = v.w;
    }
    __syncthreads();
    #pragma unroll
    for (int i = 0; i < 4; ++i) {
        int cr = i * 16 + (tid >> 4);
        int tc = (tid & 15) * 4;
        ushort4 u = make_ushort4(tl[tc + 0][cr], tl[tc + 1][cr], tl[tc + 2][cr], tl[tc + 3][cr]);
        *(ushort4*)(vt + (size_t)(b * V_ + c0 + cr) * T_ + t0 + tc) = u;
    }
}

// ---------------------------------------------------------------------------
// GEMM stage + compute building blocks (dbuf pipeline).  [R9 verbatim]
// ---------------------------------------------------------------------------
#define GSTAGE(BUF, K0)                                                        \
    {                                                                          \
        _Pragma("unroll")                                                      \
        for (int i = 0; i < 4; ++i) {                                          \
            int r = i * 32 + srow;                                             \
            int cb = scolb ^ ((r & 7) << 4);                                   \
            gl_lds16((const char*)(A  + (size_t)(rowBase + r) * K + (K0)) + cb,\
                     Asm[BUF] + i * 4096 + w * 1024);                          \
            gl_lds16((const char*)(Bt + (size_t)(colBase + r) * K + (K0)) + cb,\
                     Bsm[BUF] + i * 4096 + w * 1024);                          \
        }                                                                      \
    }

#define GCOMPUTE(BUF)                                                          \
    {                                                                          \
        _Pragma("unroll")                                                      \
        for (int kk = 0; kk < 2; ++kk) {                                       \
            const int cb = kk * 64 + (l >> 4) * 16;                            \
            bf16x8 a[4], b[4];                                                 \
            _Pragma("unroll")                                                  \
            for (int m = 0; m < 4; ++m) {                                      \
                int r = wr * 64 + m * 16 + (l & 15);                           \
                a[m] = *(const bf16x8*)(Asm[BUF] + r * 128 + (cb ^ ((r & 7) << 4))); \
            }                                                                  \
            _Pragma("unroll")                                                  \
            for (int n = 0; n < 4; ++n) {                                      \
                int r = wc * 64 + n * 16 + (l & 15);                           \
                b[n] = *(const bf16x8*)(Bsm[BUF] + r * 128 + (cb ^ ((r & 7) << 4))); \
            }                                                                  \
            _Pragma("unroll")                                                  \
            for (int m = 0; m < 4; ++m)                                        \
                _Pragma("unroll")                                              \
                for (int n = 0; n < 4; ++n)                                    \
                    acc[m][n] = __builtin_amdgcn_mfma_f32_16x16x32_bf16(a[m], b[n], acc[m][n], 0, 0, 0); \
        }                                                                      \
    }

#define GEMM_PIPELINE_LOOP                                                     \
    GSTAGE(0, 0)                                                               \
    const int nk = K / 64;                                                     \
    for (int kt = 0; kt < nk; ++kt) {                                          \
        const int cur = kt & 1;                                                \
        if (kt + 1 < nk) {                                                     \
            GSTAGE(1 - cur, (kt + 1) * 64)                                     \
            asm volatile("s_waitcnt vmcnt(8)" ::: "memory");                   \
        } else {                                                               \
            asm volatile("s_waitcnt vmcnt(0)" ::: "memory");                   \
        }                                                                      \
        __builtin_amdgcn_s_barrier();                                          \
        __builtin_amdgcn_sched_barrier(0);                                     \
        GCOMPUTE(cur)                                                          \
        __builtin_amdgcn_s_barrier();                                          \
        __builtin_amdgcn_sched_barrier(0);                                     \
    }

// ---------------------------------------------------------------------------
// Fused q,k,v,g GEMM (dbuf).  [R13 verbatim]
// ---------------------------------------------------------------------------
__global__ __launch_bounds__(256) void gemm_qkvg_kernel(
    const unsigned short* __restrict__ A,
    const unsigned short* __restrict__ Bt,
    unsigned short* __restrict__ qb,
    unsigned short* __restrict__ kb,
    unsigned short* __restrict__ vb,
    unsigned short* __restrict__ gb)
{
    const int K = E_;
    __shared__ __align__(16) char Asm[2][128 * 64 * 2];
    __shared__ __align__(16) char Bsm[2][128 * 64 * 2];
    const int tid = threadIdx.x;
    const int l = tid & 63;
    const int w = tid >> 6;
    const int wr = w >> 1, wc = w & 1;
    const int rowBase = blockIdx.y * 128;
    const int colBase = blockIdx.x * 128;
    const int srow = tid >> 3;
    const int scolb = (tid & 7) * 16;

    f32x4 acc[4][4] = {};

    GEMM_PIPELINE_LOOP

    const int colW = colBase + wc * 64;   // wave-uniform
    unsigned short* dst;
    int cofs, stride;
    if (colW < 1024)      { dst = qb; cofs = 0;    stride = E_; }
    else if (colW < 2048) { dst = kb; cofs = 1024; stride = E_; }
    else if (colW < 4096) { dst = vb; cofs = 2048; stride = V_; }
    else                  { dst = gb; cofs = 4096; stride = V_; }
    #pragma unroll
    for (int m = 0; m < 4; ++m)
        #pragma unroll
        for (int n = 0; n < 4; ++n)
            #pragma unroll
            for (int r = 0; r < 4; ++r) {
                int row = rowBase + wr * 64 + m * 16 + (l >> 4) * 4 + r;
                int col = colW + n * 16 + (l & 15);
                float f = acc[m][n][r];
                if (!isfinite(f)) f = 0.f;  // tripwire
                dst[(size_t)row * stride + (col - cofs)] = f2bu(f);
            }
}

// ---------------------------------------------------------------------------
// Wo GEMM, 64x128 tile (2 blocks/CU): C[4096,1024] = A[4096,2048] @ Bt^T.
// Stage = 2 A-loads + 4 B-loads per thread -> vmcnt(6) ladder. LDS 48 KB.
// Waves 2x2 of 32x64 sub-tiles; acc[2][4].
// ---------------------------------------------------------------------------
__global__ __launch_bounds__(256) void gemm_wo_kernel(
    const unsigned short* __restrict__ A,
    const unsigned short* __restrict__ Bt,
    float* __restrict__ C)
{
    const int K = V_;   // 2048
    __shared__ __align__(16) char Asm[2][64 * 128];    // 8 KB each
    __shared__ __align__(16) char Bsm[2][128 * 128];   // 16 KB each
    const int tid = threadIdx.x;
    const int l = tid & 63;
    const int w = tid >> 6;
    const int wr = w >> 1, wc = w & 1;
    const int rowBase = blockIdx.y * 64;
    const int colBase = blockIdx.x * 128;
    const int srow = tid >> 3;
    const int scolb = (tid & 7) * 16;

    f32x4 acc[2][4] = {};

#define WSTAGE(BUF, K0)                                                        \
    {                                                                          \
        _Pragma("unroll")                                                      \
        for (int i = 0; i < 2; ++i) {                                          \
            int r = i * 32 + srow;                                             \
            int cb = scolb ^ ((r & 7) << 4);                                   \
            gl_lds16((const char*)(A + (size_t)(rowBase + r) * K + (K0)) + cb, \
                     Asm[BUF] + i * 4096 + w * 1024);                          \
        }                                                                      \
        _Pragma("unroll")                                                      \
        for (int i = 0; i < 4; ++i) {                                          \
            int r = i * 32 + srow;                                             \
            int cb = scolb ^ ((r & 7) << 4);                                   \
            gl_lds16((const char*)(Bt + (size_t)(colBase + r) * K + (K0)) + cb,\
                     Bsm[BUF] + i * 4096 + w * 1024);                          \
        }                                                                      \
    }

    WSTAGE(0, 0)
    const int nk = K / 64;   // 32
    for (int kt = 0; kt < nk; ++kt) {
        const int cur = kt & 1;
        if (kt + 1 < nk) {
            WSTAGE(1 - cur, (kt + 1) * 64)
            asm volatile("s_waitcnt vmcnt(6)" ::: "memory");
        } else {
            asm volatile("s_waitcnt vmcnt(0)" ::: "memory");
        }
        __builtin_amdgcn_s_barrier();
        __builtin_amdgcn_sched_barrier(0);
        #pragma unroll
        for (int kk = 0; kk < 2; ++kk) {
            const int cb = kk * 64 + (l >> 4) * 16;
            bf16x8 a[2], b[4];
            #pragma unroll
            for (int m = 0; m < 2; ++m) {
                int r = wr * 32 + m * 16 + (l & 15);
                a[m] = *(const bf16x8*)(Asm[cur] + r * 128 + (cb ^ ((r & 7) << 4)));
            }
            #pragma unroll
            for (int n = 0; n < 4; ++n) {
                int r = wc * 64 + n * 16 + (l & 15);
                b[n] = *(const bf16x8*)(Bsm[cur] + r * 128 + (cb ^ ((r & 7) << 4)));
            }
            #pragma unroll
            for (int m = 0; m < 2; ++m)
                #pragma unroll
                for (int n = 0; n < 4; ++n)
                    acc[m][n] = __builtin_amdgcn_mfma_f32_16x16x32_bf16(a[m], b[n], acc[m][n], 0, 0, 0);
        }
        __builtin_amdgcn_s_barrier();
        __builtin_amdgcn_sched_barrier(0);
    }
#undef WSTAGE

    #pragma unroll
    for (int m = 0; m < 2; ++m)
        #pragma unroll
        for (int n = 0; n < 4; ++n)
            #pragma unroll
            for (int r = 0; r < 4; ++r) {
                int row = rowBase + wr * 32 + m * 16 + (l >> 4) * 4 + r;
                int col = colBase + wc * 64 + n * 16 + (l & 15);
                float f = acc[m][n][r];
                if (!isfinite(f)) f = 0.f;  // tripwire
                C[(size_t)row * E_ + col] = f;
            }
}

// ---------------------------------------------------------------------------
// theta_shift for q AND k in one dispatch.  [R13 verbatim]
// ---------------------------------------------------------------------------
__global__ __launch_bounds__(256) void theta2_kernel(
    unsigned short* __restrict__ qb,
    unsigned short* __restrict__ kb,
    const float* __restrict__ sinp, const float* __restrict__ cosp)
{
    unsigned short* qk = blockIdx.y ? kb : qb;
    const float scale = blockIdx.y ? 0.088388347648318447f : 1.0f;
    const int i = blockIdx.x * 256 + threadIdx.x;
    const int pe = i & (E_ / 2 - 1);
    const int bt = i >> 9;
    const int t = bt & (T_ - 1);
    const int e0 = pe << 1;
    const int d0 = e0 & (KD_ - 1);
    const size_t base = (size_t)bt * E_ + e0;
    const float q0 = u2f(qk[base]);
    const float q1 = u2f(qk[base + 1]);
    const int sb = t * KD_ + d0;
    const float s0 = sinp[sb], s1 = sinp[sb + 1];
    const float c0 = cosp[sb], c1 = cosp[sb + 1];
    qk[base]     = f2bu((q0 * c0 - q1 * s0) * scale);
    qk[base + 1] = f2bu((q1 * c1 + q0 * s1) * scale);
}

// ---------------------------------------------------------------------------
// Retention v5 = R12 body + FUSED rms_silu epilogue.
// Tile loop / staging / decay / PV byte-identical to R12.
// Epilogue: per-row sumsq of (o*inv) via 16-lane shfl + rsq_lds[4][64] cross-
// wave sum; scale=rsqrt(mean+eps); out = o*inv*scale*silu(g), single bf16 store.
// ---------------------------------------------------------------------------
#define STAGE_K(BUF, T0)                                                       \
    {                                                                          \
        _Pragma("unroll")                                                      \
        for (int i = 0; i < 4; ++i) {                                          \
            int r = i * 16 + (tid >> 4);                                       \
            int cb = ((tid & 15) * 16) ^ ((r & 7) << 4);                       \
            gl_lds16((const char*)(kb + (size_t)(b * T_ + (T0) + r) * E_ + h * KD_) + cb, \
                     Ks[BUF] + i * 4096 + w * 1024);                           \
        }                                                                      \
    }

#define STAGE_V(T0)                                                            \
    {                                                                          \
        _Pragma("unroll")                                                      \
        for (int i = 0; i < 8; ++i) {                                          \
            int r = i * 32 + (tid >> 3);                                       \
            int cb = ((tid & 7) * 16) ^ ((r & 7) << 4);                        \
            gl_lds16((const char*)(vt + (size_t)((b * H_ + h) * HD_ + r) * T_ + (T0)) + cb, \
                     Vs + i * 4096 + w * 1024);                                \
        }                                                                      \
    }

__global__ __launch_bounds__(256) void retention_mfma_kernel(
    const unsigned short* __restrict__ qb,
    const unsigned short* __restrict__ kb,
    const unsigned short* __restrict__ vt,
    const unsigned short* __restrict__ g,
    unsigned short* __restrict__ ao)
{
    __shared__ __align__(16) char Ks[2][64 * 128 * 2];   // 2 x 16 KB
    __shared__ __align__(16) char Vs[256 * 64 * 2];      //     32 KB
    __shared__ __align__(16) char Ps[64 * 64 * 2];       //      8 KB
    __shared__ float rsum_lds[64];
    __shared__ float rsq_lds[4][64];
    const int tid = threadIdx.x;
    const int l = tid & 63;
    const int w = tid >> 6;
    const int orig = (int)blockIdx.x;
    const int xcd  = orig & 7;
    const int pos  = orig >> 3;          // 0..63
    const int slot = pos >> 5;           // 0: big half, 1: small half
    const int cu   = pos & 31;
    const int half = cu >> 4;
    const int c15  = cu & 15;
    const int bh   = xcd * 2 + half;     // 2 bh per XCD (L2-resident K/V)
    const int chunk = slot ? c15 : (31 - c15);
    const int b = bh >> 3, h = bh & 7;
    const int s0 = chunk * 64;
    const float ld = logf(1.f - exp2f(-5.f - (float)h));

    float es[4], etl[4];
    #pragma unroll
    for (int r = 0; r < 4; ++r)
        es[r] = __expf((float)(s0 + w * 16 + (l >> 4) * 4 + r) * ld);
    #pragma unroll
    for (int n = 0; n < 4; ++n)
        etl[n] = __expf(-(float)(n * 16 + (l & 15)) * ld);
    const float Dm64 = __expf(-64.f * ld);
    float etb = 1.f;

    bf16x8 qf[4];
    {
        const char* qp = (const char*)(qb + (size_t)(b * T_ + s0 + w * 16 + (l & 15)) * E_ + h * KD_);
        #pragma unroll
        for (int kk = 0; kk < 4; ++kk)
            qf[kk] = *(const bf16x8*)(qp + kk * 64 + (l >> 4) * 16);
    }

    f32x4 oacc[4][4] = {};
    float rs[4] = {0.f, 0.f, 0.f, 0.f};

    const int nt = chunk + 1;
    STAGE_K(0, 0)

    for (int t = 0; t < nt; ++t) {
        const int cur = t & 1;
        const int t0 = t * 64;
        STAGE_V(t0)
        if (t + 1 < nt) {
            STAGE_K(1 - cur, t0 + 64)
            asm volatile("s_waitcnt vmcnt(12)" ::: "memory");
        } else {
            asm volatile("s_waitcnt vmcnt(8)" ::: "memory");
        }
        __builtin_amdgcn_s_barrier();
        __builtin_amdgcn_sched_barrier(0);

        f32x4 sacc[4] = {};
        #pragma unroll
        for (int kk = 0; kk < 4; ++kk) {
            const int cb = kk * 64 + (l >> 4) * 16;
            #pragma unroll
            for (int n = 0; n < 4; ++n) {
                int r = n * 16 + (l & 15);
                bf16x8 kf = *(const bf16x8*)(Ks[cur] + r * 256 + (cb ^ ((r & 7) << 4)));
                sacc[n] = __builtin_amdgcn_mfma_f32_16x16x32_bf16(qf[kk], kf, sacc[n], 0, 0, 0);
            }
        }
        float et[4];
        #pragma unroll
        for (int n = 0; n < 4; ++n) et[n] = etb * etl[n];
        etb *= Dm64;
        float rsp[4] = {0.f, 0.f, 0.f, 0.f};
        #pragma unroll
        for (int n = 0; n < 4; ++n)
            #pragma unroll
            for (int r = 0; r < 4; ++r) {
                int qrow = w * 16 + (l >> 4) * 4 + r;
                int tcol = n * 16 + (l & 15);
                int d = (s0 + qrow) - (t0 + tcol);
                float pm = (d >= 0) ? sacc[n][r] * (es[r] * et[n]) : 0.f;
                rsp[r] += pm;
                *(unsigned short*)(Ps + qrow * 128 + ((tcol * 2) ^ ((qrow & 7) << 4))) = f2bu(pm);
            }
        #pragma unroll
        for (int r = 0; r < 4; ++r) {
            float vv = rsp[r];
            vv += __shfl_xor(vv, 1, 16);
            vv += __shfl_xor(vv, 2, 16);
            vv += __shfl_xor(vv, 4, 16);
            vv += __shfl_xor(vv, 8, 16);
            rs[r] += vv;
        }
        if (t + 1 < nt) {
            asm volatile("s_waitcnt vmcnt(4) lgkmcnt(0)" ::: "memory");
        } else {
            asm volatile("s_waitcnt vmcnt(0) lgkmcnt(0)" ::: "memory");
        }
        __builtin_amdgcn_s_barrier();
        __builtin_amdgcn_sched_barrier(0);
        #pragma unroll
        for (int kk = 0; kk < 2; ++kk) {
            const int cb = kk * 64 + (l >> 4) * 16;
            bf16x8 pf[4];
            #pragma unroll
            for (int m = 0; m < 4; ++m) {
                int pr = m * 16 + (l & 15);
                pf[m] = *(const bf16x8*)(Ps + pr * 128 + (cb ^ ((pr & 7) << 4)));
            }
            #pragma unroll
            for (int n = 0; n < 4; ++n) {
                int r = w * 64 + n * 16 + (l & 15);
                bf16x8 vf = *(const bf16x8*)(Vs + r * 128 + (cb ^ ((r & 7) << 4)));
                #pragma unroll
                for (int m = 0; m < 4; ++m)
                    oacc[m][n] = __builtin_amdgcn_mfma_f32_16x16x32_bf16(pf[m], vf, oacc[m][n], 0, 0, 0);
            }
        }
        __builtin_amdgcn_s_barrier();
        __builtin_amdgcn_sched_barrier(0);
    }

    // --- fused epilogue: retention denom -> rms -> silu(g) -> store ---
    #pragma unroll
    for (int r = 0; r < 4; ++r)
        if ((l & 15) == 0) rsum_lds[w * 16 + (l >> 4) * 4 + r] = rs[r];
    __syncthreads();

    // per-row sumsq of normalized o, this wave's 64-col slice
    #pragma unroll
    for (int m = 0; m < 4; ++m)
        #pragma unroll
        for (int r = 0; r < 4; ++r) {
            const int row = m * 16 + (l >> 4) * 4 + r;
            const float inv = 1.f / fmaxf(fabsf(rsum_lds[row]), 1.f);
            float ps = 0.f;
            #pragma unroll
            for (int n = 0; n < 4; ++n) {
                float o = oacc[m][n][r] * inv;
                ps += o * o;
            }
            ps += __shfl_xor(ps, 1, 16);
            ps += __shfl_xor(ps, 2, 16);
            ps += __shfl_xor(ps, 4, 16);
            ps += __shfl_xor(ps, 8, 16);
            if ((l & 15) == 0) rsq_lds[w][row] = ps;
        }
    __syncthreads();

    #pragma unroll
    for (int m = 0; m < 4; ++m)
        #pragma unroll
        for (int r = 0; r < 4; ++r) {
            const int row = m * 16 + (l >> 4) * 4 + r;
            const float inv = 1.f / fmaxf(fabsf(rsum_lds[row]), 1.f);
            const float tot = rsq_lds[0][row] + rsq_lds[1][row] + rsq_lds[2][row] + rsq_lds[3][row];
            const float scale = rsqrtf(tot * (1.0f / HD_) + 1e-6f) * inv;
            #pragma unroll
            for (int n = 0; n < 4; ++n) {
                const int col = h * HD_ + w * 64 + n * 16 + (l & 15);
                const float gv = u2f(g[(size_t)(b * T_ + s0 + row) * V_ + col]);
                const float silu = gv / (1.f + __expf(-gv));
                float f = oacc[m][n][r] * scale * silu;
                if (!isfinite(f)) f = 0.f;
                ao[(size_t)(b * T_ + s0 + row) * V_ + col] = f2bu(f);
            }
        }
}

extern "C" void kernel_launch(void* const* d_in, const int* in_sizes, int n_in,
                              void* d_out, int out_size, void* d_ws, size_t ws_size,
                              hipStream_t stream)
{
    const float* x    = (const float*)d_in[0];
    const float* sinp = (const float*)d_in[1];
    const float* cosp = (const float*)d_in[2];
    // d_in[3] = mask: decay computed analytically in-kernel
    const float* Wq   = (const float*)d_in[4];
    const float* Wk   = (const float*)d_in[5];
    const float* Wv   = (const float*)d_in[6];
    const float* Wg   = (const float*)d_in[7];
    const float* Wo   = (const float*)d_in[8];
    float* out = (float*)d_out;

    // d_out doubles as scratch (R4-proven): xb [0,8.39M) | qb [8.39M,16.78M).
    unsigned short* xb = (unsigned short*)d_out;
    unsigned short* qb = xb + (size_t)M_ * E_;

    // ws: DISJOINT layout (~92 MB of 512 MiB).
    char* ws = (char*)d_ws;
    unsigned short* kb  = (unsigned short*)(ws + 0);         //  8.39 MB
    unsigned short* vb  = (unsigned short*)(ws + 8388608);   // 16.78 MB
    unsigned short* gb  = (unsigned short*)(ws + 25165824);  // 16.78 MB
    unsigned short* wt  = (unsigned short*)(ws + 41943040);  // 12.58 MB [6144][1024]
    unsigned short* vt  = (unsigned short*)(ws + 54525952);  // 16.78 MB
    unsigned short* aob = (unsigned short*)(ws + 71303168);  // 16.78 MB
    unsigned short* wot = (unsigned short*)(ws + 88080384);  //  4.19 MB

    dim3 blk(256);
    conv_x_kernel<<<M_ * E_ / 8 / 256, blk, 0, stream>>>(x, xb);

    transW4_kernel<<<dim3(32, 16, 4), blk, 0, stream>>>(Wq, Wk, Wv, Wg, wt);

    gemm_qkvg_kernel<<<dim3(48, 32), blk, 0, stream>>>(xb, wt, qb, kb, vb, gb);

    theta2_kernel<<<dim3(M_ * E_ / 2 / 256, 2), blk, 0, stream>>>(qb, kb, sinp, cosp);

    transV_kernel<<<dim3(32, 32, B_), blk, 0, stream>>>(vb, vt);

    retention_mfma_kernel<<<dim3(512), blk, 0, stream>>>(qb, kb, vt, gb, aob);

    transW_kernel<<<dim3(16, 32), blk, 0, stream>>>(Wo, wot, V_, E_);
    gemm_wo_kernel<<<dim3(8, 64), blk, 0, stream>>>(aob, wot, out);
}

// Round 15
// 190.608 us; speedup vs baseline: 1.4199x; 1.0666x over previous
//
#include <hip/hip_runtime.h>
#include <hip/hip_bf16.h>

// MultiScaleRetention forward, MI355X gfx950 — Round 15.
// R14: 203.3 µs; retention 79.7 µs dominated by redundant K reads (4x/wave),
// 16 scalar P-writes and 16 shuffles per thread per tile. This round rebuilds
// retention with SWAPPED MFMA operands: S^T = mfma(K, Q) with Q in registers
// (loaded once, qf[4][4]) and waves split along t in QK (K reads 16->4);
// P stored [q][t] via 4x ds_write_b64 (t lane-local); PV as O^T = V^T @ P^T
// (pf along t, b128); rowsum 2 shuffles. Barrier/vmcnt ladder byte-identical
// to the R12-proven structure. All other kernels R14-verbatim.

#define B_ 2
#define T_ 2048
#define E_ 1024
#define V_ 2048
#define H_ 8
#define KD_ 128
#define HD_ 256
#define M_ 4096  // B_*T_

typedef __attribute__((ext_vector_type(8))) short bf16x8;
typedef __attribute__((ext_vector_type(4))) float f32x4;

__device__ __forceinline__ float u2f(unsigned short u) {
    return __uint_as_float(((unsigned)u) << 16);
}
__device__ __forceinline__ unsigned short f2bu(float f) {
    unsigned x = __float_as_uint(f);
    return (unsigned short)((x + 0x7fffu + ((x >> 16) & 1u)) >> 16);  // RNE
}

typedef const __attribute__((address_space(1))) void gas_t;
typedef __attribute__((address_space(3))) void las_t;
__device__ __forceinline__ void gl_lds16(const void* g, void* l) {
    __builtin_amdgcn_global_load_lds((gas_t*)g, (las_t*)l, 16, 0, 0);
}

// ---------------------------------------------------------------------------
// x fp32 -> bf16 flat convert (8 elems/thread).  [R4 verbatim]
// ---------------------------------------------------------------------------
__global__ __launch_bounds__(256) void conv_x_kernel(
    const float* __restrict__ x, unsigned short* __restrict__ xb)
{
    const size_t i = ((size_t)blockIdx.x * 256 + threadIdx.x) * 8;
    float4 a = *(const float4*)(x + i);
    float4 c = *(const float4*)(x + i + 4);
    *(ushort4*)(xb + i)     = make_ushort4(f2bu(a.x), f2bu(a.y), f2bu(a.z), f2bu(a.w));
    *(ushort4*)(xb + i + 4) = make_ushort4(f2bu(c.x), f2bu(c.y), f2bu(c.z), f2bu(c.w));
}

// ---------------------------------------------------------------------------
// Packed weight transpose: z selects {Wq,Wk,Wv,Wg}.  [R13 verbatim]
// ---------------------------------------------------------------------------
__global__ __launch_bounds__(256) void transW4_kernel(
    const float* __restrict__ Wq, const float* __restrict__ Wk,
    const float* __restrict__ Wv, const float* __restrict__ Wg,
    unsigned short* __restrict__ Wt)
{
    const int z = blockIdx.z;
    const float* W; int N; int rofs;
    if (z == 0)      { W = Wq; N = 1024; rofs = 0; }
    else if (z == 1) { W = Wk; N = 1024; rofs = 1024; }
    else if (z == 2) { W = Wv; N = 2048; rofs = 2048; }
    else             { W = Wg; N = 2048; rofs = 4096; }
    const int n0 = blockIdx.x * 64;
    if (n0 >= N) return;
    const int k0 = blockIdx.y * 64;

    __shared__ float tl[64][65];
    const int tid = threadIdx.x;
    #pragma unroll
    for (int i = 0; i < 4; ++i) {
        int kr = i * 16 + (tid >> 4);
        int nc = (tid & 15) * 4;
        float4 v = *(const float4*)(W + (size_t)(k0 + kr) * N + n0 + nc);
        tl[kr][nc] = v.x; tl[kr][nc + 1] = v.y; tl[kr][nc + 2] = v.z; tl[kr][nc + 3] = v.w;
    }
    __syncthreads();
    #pragma unroll
    for (int i = 0; i < 4; ++i) {
        int nr = i * 16 + (tid >> 4);
        int kc = (tid & 15) * 4;
        ushort4 u = make_ushort4(f2bu(tl[kc + 0][nr]), f2bu(tl[kc + 1][nr]),
                                 f2bu(tl[kc + 2][nr]), f2bu(tl[kc + 3][nr]));
        *(ushort4*)(Wt + (size_t)(rofs + n0 + nr) * E_ + k0 + kc) = u;
    }
}

// ---------------------------------------------------------------------------
// Single-W transpose for Wo.  [R4 verbatim]
// ---------------------------------------------------------------------------
__global__ __launch_bounds__(256) void transW_kernel(
    const float* __restrict__ W, unsigned short* __restrict__ Wt, int K, int N)
{
    __shared__ float tl[64][65];
    const int tid = threadIdx.x;
    const int n0 = blockIdx.x * 64, k0 = blockIdx.y * 64;
    #pragma unroll
    for (int i = 0; i < 4; ++i) {
        int kr = i * 16 + (tid >> 4);
        int nc = (tid & 15) * 4;
        float4 v = *(const float4*)(W + (size_t)(k0 + kr) * N + n0 + nc);
        tl[kr][nc] = v.x; tl[kr][nc + 1] = v.y; tl[kr][nc + 2] = v.z; tl[kr][nc + 3] = v.w;
    }
    __syncthreads();
    #pragma unroll
    for (int i = 0; i < 4; ++i) {
        int nr = i * 16 + (tid >> 4);
        int kc = (tid & 15) * 4;
        ushort4 u = make_ushort4(f2bu(tl[kc + 0][nr]), f2bu(tl[kc + 1][nr]),
                                 f2bu(tl[kc + 2][nr]), f2bu(tl[kc + 3][nr]));
        *(ushort4*)(Wt + (size_t)(n0 + nr) * K + k0 + kc) = u;
    }
}

// ---------------------------------------------------------------------------
// V [b*T + t][2048] bf16 -> Vt [b*2048 + c][T] bf16.  [R4 verbatim]
// ---------------------------------------------------------------------------
__global__ __launch_bounds__(256) void transV_kernel(
    const unsigned short* __restrict__ vb, unsigned short* __restrict__ vt)
{
    __shared__ unsigned short tl[64][68];
    const int tid = threadIdx.x;
    const int t0 = blockIdx.x * 64, c0 = blockIdx.y * 64, b = blockIdx.z;
    #pragma unroll
    for (int i = 0; i < 4; ++i) {
        int tr = i * 16 + (tid >> 4);
        int cc = (tid & 15) * 4;
        ushort4 v = *(const ushort4*)(vb + (size_t)(b * T_ + t0 + tr) * V_ + c0 + cc);
        tl[tr][cc] = v.x; tl[tr][cc + 1] = v.y; tl[tr][cc + 2] = v.z; tl[tr][cc + 3] = v.w;
    }
    __syncthreads();
    #pragma unroll
    for (int i = 0; i < 4; ++i) {
        int cr = i * 16 + (tid >> 4);
        int tc = (tid & 15) * 4;
        ushort4 u = make_ushort4(tl[tc + 0][cr], tl[tc + 1][cr], tl[tc + 2][cr], tl[tc + 3][cr]);
        *(ushort4*)(vt + (size_t)(b * V_ + c0 + cr) * T_ + t0 + tc) = u;
    }
}

// ---------------------------------------------------------------------------
// GEMM stage + compute building blocks (dbuf pipeline).  [R9 verbatim]
// ---------------------------------------------------------------------------
#define GSTAGE(BUF, K0)                                                        \
    {                                                                          \
        _Pragma("unroll")                                                      \
        for (int i = 0; i < 4; ++i) {                                          \
            int r = i * 32 + srow;                                             \
            int cb = scolb ^ ((r & 7) << 4);                                   \
            gl_lds16((const char*)(A  + (size_t)(rowBase + r) * K + (K0)) + cb,\
                     Asm[BUF] + i * 4096 + w * 1024);                          \
            gl_lds16((const char*)(Bt + (size_t)(colBase + r) * K + (K0)) + cb,\
                     Bsm[BUF] + i * 4096 + w * 1024);                          \
        }                                                                      \
    }

#define GCOMPUTE(BUF)                                                          \
    {                                                                          \
        _Pragma("unroll")                                                      \
        for (int kk = 0; kk < 2; ++kk) {                                       \
            const int cb = kk * 64 + (l >> 4) * 16;                            \
            bf16x8 a[4], b[4];                                                 \
            _Pragma("unroll")                                                  \
            for (int m = 0; m < 4; ++m) {                                      \
                int r = wr * 64 + m * 16 + (l & 15);                           \
                a[m] = *(const bf16x8*)(Asm[BUF] + r * 128 + (cb ^ ((r & 7) << 4))); \
            }                                                                  \
            _Pragma("unroll")                                                  \
            for (int n = 0; n < 4; ++n) {                                      \
                int r = wc * 64 + n * 16 + (l & 15);                           \
                b[n] = *(const bf16x8*)(Bsm[BUF] + r * 128 + (cb ^ ((r & 7) << 4))); \
            }                                                                  \
            _Pragma("unroll")                                                  \
            for (int m = 0; m < 4; ++m)                                        \
                _Pragma("unroll")                                              \
                for (int n = 0; n < 4; ++n)                                    \
                    acc[m][n] = __builtin_amdgcn_mfma_f32_16x16x32_bf16(a[m], b[n], acc[m][n], 0, 0, 0); \
        }                                                                      \
    }

#define GEMM_PIPELINE_LOOP                                                     \
    GSTAGE(0, 0)                                                               \
    const int nk = K / 64;                                                     \
    for (int kt = 0; kt < nk; ++kt) {                                          \
        const int cur = kt & 1;                                                \
        if (kt + 1 < nk) {                                                     \
            GSTAGE(1 - cur, (kt + 1) * 64)                                     \
            asm volatile("s_waitcnt vmcnt(8)" ::: "memory");                   \
        } else {                                                               \
            asm volatile("s_waitcnt vmcnt(0)" ::: "memory");                   \
        }                                                                      \
        __builtin_amdgcn_s_barrier();                                          \
        __builtin_amdgcn_sched_barrier(0);                                     \
        GCOMPUTE(cur)                                                          \
        __builtin_amdgcn_s_barrier();                                          \
        __builtin_amdgcn_sched_barrier(0);                                     \
    }

// ---------------------------------------------------------------------------
// Fused q,k,v,g GEMM (dbuf).  [R13 verbatim]
// ---------------------------------------------------------------------------
__global__ __launch_bounds__(256) void gemm_qkvg_kernel(
    const unsigned short* __restrict__ A,
    const unsigned short* __restrict__ Bt,
    unsigned short* __restrict__ qb,
    unsigned short* __restrict__ kb,
    unsigned short* __restrict__ vb,
    unsigned short* __restrict__ gb)
{
    const int K = E_;
    __shared__ __align__(16) char Asm[2][128 * 64 * 2];
    __shared__ __align__(16) char Bsm[2][128 * 64 * 2];
    const int tid = threadIdx.x;
    const int l = tid & 63;
    const int w = tid >> 6;
    const int wr = w >> 1, wc = w & 1;
    const int rowBase = blockIdx.y * 128;
    const int colBase = blockIdx.x * 128;
    const int srow = tid >> 3;
    const int scolb = (tid & 7) * 16;

    f32x4 acc[4][4] = {};

    GEMM_PIPELINE_LOOP

    const int colW = colBase + wc * 64;   // wave-uniform
    unsigned short* dst;
    int cofs, stride;
    if (colW < 1024)      { dst = qb; cofs = 0;    stride = E_; }
    else if (colW < 2048) { dst = kb; cofs = 1024; stride = E_; }
    else if (colW < 4096) { dst = vb; cofs = 2048; stride = V_; }
    else                  { dst = gb; cofs = 4096; stride = V_; }
    #pragma unroll
    for (int m = 0; m < 4; ++m)
        #pragma unroll
        for (int n = 0; n < 4; ++n)
            #pragma unroll
            for (int r = 0; r < 4; ++r) {
                int row = rowBase + wr * 64 + m * 16 + (l >> 4) * 4 + r;
                int col = colW + n * 16 + (l & 15);
                float f = acc[m][n][r];
                if (!isfinite(f)) f = 0.f;  // tripwire
                dst[(size_t)row * stride + (col - cofs)] = f2bu(f);
            }
}

// ---------------------------------------------------------------------------
// Wo GEMM, 64x128 tile.  [R14 verbatim]
// ---------------------------------------------------------------------------
__global__ __launch_bounds__(256) void gemm_wo_kernel(
    const unsigned short* __restrict__ A,
    const unsigned short* __restrict__ Bt,
    float* __restrict__ C)
{
    const int K = V_;   // 2048
    __shared__ __align__(16) char Asm[2][64 * 128];    // 8 KB each
    __shared__ __align__(16) char Bsm[2][128 * 128];   // 16 KB each
    const int tid = threadIdx.x;
    const int l = tid & 63;
    const int w = tid >> 6;
    const int wr = w >> 1, wc = w & 1;
    const int rowBase = blockIdx.y * 64;
    const int colBase = blockIdx.x * 128;
    const int srow = tid >> 3;
    const int scolb = (tid & 7) * 16;

    f32x4 acc[2][4] = {};

#define WSTAGE(BUF, K0)                                                        \
    {                                                                          \
        _Pragma("unroll")                                                      \
        for (int i = 0; i < 2; ++i) {                                          \
            int r = i * 32 + srow;                                             \
            int cb = scolb ^ ((r & 7) << 4);                                   \
            gl_lds16((const char*)(A + (size_t)(rowBase + r) * K + (K0)) + cb, \
                     Asm[BUF] + i * 4096 + w * 1024);                          \
        }                                                                      \
        _Pragma("unroll")                                                      \
        for (int i = 0; i < 4; ++i) {                                          \
            int r = i * 32 + srow;                                             \
            int cb = scolb ^ ((r & 7) << 4);                                   \
            gl_lds16((const char*)(Bt + (size_t)(colBase + r) * K + (K0)) + cb,\
                     Bsm[BUF] + i * 4096 + w * 1024);                          \
        }                                                                      \
    }

    WSTAGE(0, 0)
    const int nk = K / 64;   // 32
    for (int kt = 0; kt < nk; ++kt) {
        const int cur = kt & 1;
        if (kt + 1 < nk) {
            WSTAGE(1 - cur, (kt + 1) * 64)
            asm volatile("s_waitcnt vmcnt(6)" ::: "memory");
        } else {
            asm volatile("s_waitcnt vmcnt(0)" ::: "memory");
        }
        __builtin_amdgcn_s_barrier();
        __builtin_amdgcn_sched_barrier(0);
        #pragma unroll
        for (int kk = 0; kk < 2; ++kk) {
            const int cb = kk * 64 + (l >> 4) * 16;
            bf16x8 a[2], b[4];
            #pragma unroll
            for (int m = 0; m < 2; ++m) {
                int r = wr * 32 + m * 16 + (l & 15);
                a[m] = *(const bf16x8*)(Asm[cur] + r * 128 + (cb ^ ((r & 7) << 4)));
            }
            #pragma unroll
            for (int n = 0; n < 4; ++n) {
                int r = wc * 64 + n * 16 + (l & 15);
                b[n] = *(const bf16x8*)(Bsm[cur] + r * 128 + (cb ^ ((r & 7) << 4)));
            }
            #pragma unroll
            for (int m = 0; m < 2; ++m)
                #pragma unroll
                for (int n = 0; n < 4; ++n)
                    acc[m][n] = __builtin_amdgcn_mfma_f32_16x16x32_bf16(a[m], b[n], acc[m][n], 0, 0, 0);
        }
        __builtin_amdgcn_s_barrier();
        __builtin_amdgcn_sched_barrier(0);
    }
#undef WSTAGE

    #pragma unroll
    for (int m = 0; m < 2; ++m)
        #pragma unroll
        for (int n = 0; n < 4; ++n)
            #pragma unroll
            for (int r = 0; r < 4; ++r) {
                int row = rowBase + wr * 32 + m * 16 + (l >> 4) * 4 + r;
                int col = colBase + wc * 64 + n * 16 + (l & 15);
                float f = acc[m][n][r];
                if (!isfinite(f)) f = 0.f;  // tripwire
                C[(size_t)row * E_ + col] = f;
            }
}

// ---------------------------------------------------------------------------
// theta_shift for q AND k in one dispatch.  [R13 verbatim]
// ---------------------------------------------------------------------------
__global__ __launch_bounds__(256) void theta2_kernel(
    unsigned short* __restrict__ qb,
    unsigned short* __restrict__ kb,
    const float* __restrict__ sinp, const float* __restrict__ cosp)
{
    unsigned short* qk = blockIdx.y ? kb : qb;
    const float scale = blockIdx.y ? 0.088388347648318447f : 1.0f;
    const int i = blockIdx.x * 256 + threadIdx.x;
    const int pe = i & (E_ / 2 - 1);
    const int bt = i >> 9;
    const int t = bt & (T_ - 1);
    const int e0 = pe << 1;
    const int d0 = e0 & (KD_ - 1);
    const size_t base = (size_t)bt * E_ + e0;
    const float q0 = u2f(qk[base]);
    const float q1 = u2f(qk[base + 1]);
    const int sb = t * KD_ + d0;
    const float s0 = sinp[sb], s1 = sinp[sb + 1];
    const float c0 = cosp[sb], c1 = cosp[sb + 1];
    qk[base]     = f2bu((q0 * c0 - q1 * s0) * scale);
    qk[base + 1] = f2bu((q1 * c1 + q0 * s1) * scale);
}

// ---------------------------------------------------------------------------
// Retention v6 (swapped operands): S^T = mfma(K, Q), Q in regs qf[qb][kk]
// (all 64 q, loaded once). QK split along t: wave w computes S^T for its 16 t
// x 64 q (K reads 4/tile). P stored Pq[64 q][64 t] via ds_write_b64 (t lane-
// local). PV: O^T = V^T @ P^T (A=vf from Vs, B=pf from Pq along t).
// Rowsum: 2 shuffles + cross-wave rsum_p[4][64]. Fused rms_silu epilogue with
// ushort4-packed stores. Same R12-proven vmcnt/barrier ladder; LDS 74 KB.
// ---------------------------------------------------------------------------
#define STAGE_K(BUF, T0)                                                       \
    {                                                                          \
        _Pragma("unroll")                                                      \
        for (int i = 0; i < 4; ++i) {                                          \
            int r = i * 16 + (tid >> 4);                                       \
            int cb = ((tid & 15) * 16) ^ ((r & 7) << 4);                       \
            gl_lds16((const char*)(kb + (size_t)(b * T_ + (T0) + r) * E_ + h * KD_) + cb, \
                     Ks[BUF] + i * 4096 + w * 1024);                           \
        }                                                                      \
    }

#define STAGE_V(T0)                                                            \
    {                                                                          \
        _Pragma("unroll")                                                      \
        for (int i = 0; i < 8; ++i) {                                          \
            int r = i * 32 + (tid >> 3);                                       \
            int cb = ((tid & 7) * 16) ^ ((r & 7) << 4);                        \
            gl_lds16((const char*)(vt + (size_t)((b * H_ + h) * HD_ + r) * T_ + (T0)) + cb, \
                     Vs + i * 4096 + w * 1024);                                \
        }                                                                      \
    }

__global__ __launch_bounds__(256, 2) void retention_mfma_kernel(
    const unsigned short* __restrict__ qb,
    const unsigned short* __restrict__ kb,
    const unsigned short* __restrict__ vt,
    const unsigned short* __restrict__ g,
    unsigned short* __restrict__ ao)
{
    __shared__ __align__(16) char Ks[2][64 * 128 * 2];   // 2 x 16 KB
    __shared__ __align__(16) char Vs[256 * 64 * 2];      //     32 KB
    __shared__ __align__(16) char Pq[64 * 64 * 2];       //      8 KB [q][t]
    __shared__ float rsum_p[4][64];
    __shared__ float rsq_p[4][64];
    const int tid = threadIdx.x;
    const int l = tid & 63;
    const int w = tid >> 6;
    const int g_ = l >> 4;               // 0..3
    const int q15 = l & 15;
    const int orig = (int)blockIdx.x;
    const int xcd  = orig & 7;
    const int pos  = orig >> 3;          // 0..63
    const int slot = pos >> 5;           // 0: big half, 1: small half
    const int cu   = pos & 31;
    const int half = cu >> 4;
    const int c15  = cu & 15;
    const int bh   = xcd * 2 + half;     // 2 bh per XCD (L2-resident K/V)
    const int chunk = slot ? c15 : (31 - c15);
    const int b = bh >> 3, h = bh & 7;
    const int s0 = chunk * 64;
    const float ld = logf(1.f - exp2f(-5.f - (float)h));

    // decay factorization: mask(q,t) = D^q * D^-t
    float es[4];                         // D^(s0 + qb2*16 + q15)
    #pragma unroll
    for (int qb2 = 0; qb2 < 4; ++qb2)
        es[qb2] = __expf((float)(s0 + qb2 * 16 + q15) * ld);
    float etl[4];                        // D^-(w*16 + 4g + r)
    #pragma unroll
    for (int r = 0; r < 4; ++r)
        etl[r] = __expf(-(float)(w * 16 + 4 * g_ + r) * ld);
    const float Dm64 = __expf(-64.f * ld);
    float etb = 1.f;                     // D^-t0

    // Q in registers: B-operand frags for all 4 q-blocks x 4 kd-slices.
    bf16x8 qf[4][4];
    #pragma unroll
    for (int qb2 = 0; qb2 < 4; ++qb2) {
        const char* qp = (const char*)(qb + (size_t)(b * T_ + s0 + qb2 * 16 + q15) * E_ + h * KD_);
        #pragma unroll
        for (int kk = 0; kk < 4; ++kk)
            qf[qb2][kk] = *(const bf16x8*)(qp + kk * 64 + g_ * 16);
    }

    f32x4 oaccT[4][4] = {};   // [q-block][vcol frag]; col=q15, row=vcol 4g+r
    float rs[4] = {0.f, 0.f, 0.f, 0.f};   // per q-block, this wave's t partial

    const int nt = chunk + 1;
    STAGE_K(0, 0)

    for (int t = 0; t < nt; ++t) {
        const int cur = t & 1;
        const int t0 = t * 64;
        STAGE_V(t0)
        if (t + 1 < nt) {
            STAGE_K(1 - cur, t0 + 64)
            asm volatile("s_waitcnt vmcnt(12)" ::: "memory");
        } else {
            asm volatile("s_waitcnt vmcnt(8)" ::: "memory");
        }
        __builtin_amdgcn_s_barrier();
        __builtin_amdgcn_sched_barrier(0);

        // QK^T swapped: this wave's 16 t-rows x all 64 q.
        // kf: A-operand, row = t_local = w*16 + q15, k = kd slice kk.
        f32x4 sacc[4] = {};
        {
            const int krow = w * 16 + q15;
            const int swz = (krow & 7) << 4;
            #pragma unroll
            for (int kk = 0; kk < 4; ++kk) {
                bf16x8 kf = *(const bf16x8*)(Ks[cur] + krow * 256 + ((kk * 64 + g_ * 16) ^ swz));
                #pragma unroll
                for (int qb2 = 0; qb2 < 4; ++qb2)
                    sacc[qb2] = __builtin_amdgcn_mfma_f32_16x16x32_bf16(kf, qf[qb2][kk], sacc[qb2], 0, 0, 0);
            }
        }
        // mask + P write (b64, t lane-local) + rowsum partial
        {
            const float etw = etb;  // D^-t0
            #pragma unroll
            for (int qb2 = 0; qb2 < 4; ++qb2) {
                const int qg = s0 + qb2 * 16 + q15;       // global q
                const int q_local = qb2 * 16 + q15;
                float rsp = 0.f;
                unsigned short pk[4];
                #pragma unroll
                for (int r = 0; r < 4; ++r) {
                    int tg = t0 + w * 16 + 4 * g_ + r;     // global t
                    float pm = (qg >= tg) ? sacc[qb2][r] * (es[qb2] * etw * etl[r]) : 0.f;
                    rsp += pm;
                    pk[r] = f2bu(pm);
                }
                *(ushort4*)(Pq + q_local * 128 + (((w * 16 + 4 * g_) * 2) ^ ((q_local & 7) << 4))) =
                    make_ushort4(pk[0], pk[1], pk[2], pk[3]);
                rsp += __shfl_xor(rsp, 16);
                rsp += __shfl_xor(rsp, 32);
                rs[qb2] += rsp;
            }
            etb *= Dm64;
        }
        // V(t) staged (all waves) AND all waves' P writes visible before PV.
        if (t + 1 < nt) {
            asm volatile("s_waitcnt vmcnt(4) lgkmcnt(0)" ::: "memory");
        } else {
            asm volatile("s_waitcnt vmcnt(0) lgkmcnt(0)" ::: "memory");
        }
        __builtin_amdgcn_s_barrier();
        __builtin_amdgcn_sched_barrier(0);
        // PV swapped: O^T[vcol][q] += V^T[vcol][t] @ P^T[t][q].
        // A = vf (rows = wave's 64 vcols), B = pf (cols = 16 q of block qb2).
        #pragma unroll
        for (int kk = 0; kk < 2; ++kk) {
            const int cb = kk * 64 + g_ * 16;
            bf16x8 pf[4], vf[4];
            #pragma unroll
            for (int qb2 = 0; qb2 < 4; ++qb2) {
                int pr = qb2 * 16 + q15;
                pf[qb2] = *(const bf16x8*)(Pq + pr * 128 + (cb ^ ((pr & 7) << 4)));
            }
            #pragma unroll
            for (int m = 0; m < 4; ++m) {
                int vr = w * 64 + m * 16 + q15;
                vf[m] = *(const bf16x8*)(Vs + vr * 128 + (cb ^ ((vr & 7) << 4)));
            }
            #pragma unroll
            for (int qb2 = 0; qb2 < 4; ++qb2)
                #pragma unroll
                for (int m = 0; m < 4; ++m)
                    oaccT[qb2][m] = __builtin_amdgcn_mfma_f32_16x16x32_bf16(vf[m], pf[qb2], oaccT[qb2][m], 0, 0, 0);
        }
        __builtin_amdgcn_s_barrier();
        __builtin_amdgcn_sched_barrier(0);
    }

    // --- fused epilogue: denom -> rms -> silu(g) -> packed store ---
    // cross-wave rowsum: wave w holds partial over its t-slices for all 64 q.
    if (l < 16) {
        #pragma unroll
        for (int qb2 = 0; qb2 < 4; ++qb2)
            rsum_p[w][qb2 * 16 + q15] = rs[qb2];
    }
    __syncthreads();

    float inv[4];
    #pragma unroll
    for (int qb2 = 0; qb2 < 4; ++qb2) {
        const int q_local = qb2 * 16 + q15;
        const float tot = rsum_p[0][q_local] + rsum_p[1][q_local] +
                          rsum_p[2][q_local] + rsum_p[3][q_local];
        inv[qb2] = 1.f / fmaxf(fabsf(tot), 1.f);
    }

    // per-q sumsq over this wave's 64-vcol slice
    #pragma unroll
    for (int qb2 = 0; qb2 < 4; ++qb2) {
        float ps = 0.f;
        #pragma unroll
        for (int m = 0; m < 4; ++m)
            #pragma unroll
            for (int r = 0; r < 4; ++r) {
                float o = oaccT[qb2][m][r] * inv[qb2];
                ps += o * o;
            }
        ps += __shfl_xor(ps, 16);
        ps += __shfl_xor(ps, 32);
        if (l < 16) rsq_p[w][qb2 * 16 + q15] = ps;
    }
    __syncthreads();

    #pragma unroll
    for (int qb2 = 0; qb2 < 4; ++qb2) {
        const int q_local = qb2 * 16 + q15;
        const float tot = rsq_p[0][q_local] + rsq_p[1][q_local] +
                          rsq_p[2][q_local] + rsq_p[3][q_local];
        const float scale = rsqrtf(tot * (1.0f / HD_) + 1e-6f) * inv[qb2];
        const size_t rowb = (size_t)(b * T_ + s0 + q_local) * V_ + h * HD_;
        #pragma unroll
        for (int m = 0; m < 4; ++m) {
            const int vc0 = w * 64 + m * 16 + 4 * g_;
            ushort4 gv4 = *(const ushort4*)(g + rowb + vc0);
            const unsigned short* gv = (const unsigned short*)&gv4;
            unsigned short outp[4];
            #pragma unroll
            for (int r = 0; r < 4; ++r) {
                const float gvf = u2f(gv[r]);
                const float silu = gvf / (1.f + __expf(-gvf));
                float f = oaccT[qb2][m][r] * scale * silu;
                if (!isfinite(f)) f = 0.f;
                outp[r] = f2bu(f);
            }
            *(ushort4*)(ao + rowb + vc0) = make_ushort4(outp[0], outp[1], outp[2], outp[3]);
        }
    }
}

extern "C" void kernel_launch(void* const* d_in, const int* in_sizes, int n_in,
                              void* d_out, int out_size, void* d_ws, size_t ws_size,
                              hipStream_t stream)
{
    const float* x    = (const float*)d_in[0];
    const float* sinp = (const float*)d_in[1];
    const float* cosp = (const float*)d_in[2];
    // d_in[3] = mask: decay computed analytically in-kernel
    const float* Wq   = (const float*)d_in[4];
    const float* Wk   = (const float*)d_in[5];
    const float* Wv   = (const float*)d_in[6];
    const float* Wg   = (const float*)d_in[7];
    const float* Wo   = (const float*)d_in[8];
    float* out = (float*)d_out;

    // d_out doubles as scratch (R4-proven): xb [0,8.39M) | qb [8.39M,16.78M).
    unsigned short* xb = (unsigned short*)d_out;
    unsigned short* qb = xb + (size_t)M_ * E_;

    // ws: DISJOINT layout (~92 MB of 512 MiB).
    char* ws = (char*)d_ws;
    unsigned short* kb  = (unsigned short*)(ws + 0);         //  8.39 MB
    unsigned short* vb  = (unsigned short*)(ws + 8388608);   // 16.78 MB
    unsigned short* gb  = (unsigned short*)(ws + 25165824);  // 16.78 MB
    unsigned short* wt  = (unsigned short*)(ws + 41943040);  // 12.58 MB [6144][1024]
    unsigned short* vt  = (unsigned short*)(ws + 54525952);  // 16.78 MB
    unsigned short* aob = (unsigned short*)(ws + 71303168);  // 16.78 MB
    unsigned short* wot = (unsigned short*)(ws + 88080384);  //  4.19 MB

    dim3 blk(256);
    conv_x_kernel<<<M_ * E_ / 8 / 256, blk, 0, stream>>>(x, xb);

    transW4_kernel<<<dim3(32, 16, 4), blk, 0, stream>>>(Wq, Wk, Wv, Wg, wt);

    gemm_qkvg_kernel<<<dim3(48, 32), blk, 0, stream>>>(xb, wt, qb, kb, vb, gb);

    theta2_kernel<<<dim3(M_ * E_ / 2 / 256, 2), blk, 0, stream>>>(qb, kb, sinp, cosp);

    transV_kernel<<<dim3(32, 32, B_), blk, 0, stream>>>(vb, vt);

    retention_mfma_kernel<<<dim3(512), blk, 0, stream>>>(qb, kb, vt, gb, aob);

    transW_kernel<<<dim3(16, 32), blk, 0, stream>>>(Wo, wot, V_, E_);
    gemm_wo_kernel<<<dim3(8, 64), blk, 0, stream>>>(aob, wot, out);
}